// Round 1
// baseline (319.623 us; speedup 1.0000x reference)
//
#include <hip/hip_runtime.h>
#include <hip/hip_bf16.h>

// Problem constants (fixed by setup_inputs in the reference)
#define H        768
#define LMAX     128
#define CONV_NUM 8
#define CONV_SIZE 96
#define T_CONV   673            // H - CONV_SIZE + 1
#define FC_IN    5384           // CONV_NUM * T_CONV
#define N_WAY    10
#define K_SHOT   5
#define TOTAL_Q  150
#define SPLITK   4
#define KSPLIT   1348           // 4-aligned split of 5384 (last split = 1340)

// ---------------------------------------------------------------------------
// 1) entity gather: mean of x[b, s:max(e,s+1)] over span rows -> [.,768]
//    grid = 2*(Bs+Bq); bid < M -> head entity, else tail entity.
// ---------------------------------------------------------------------------
__global__ __launch_bounds__(256) void entity_kernel(
    const float* __restrict__ all_support, const float* __restrict__ all_query,
    const int* __restrict__ s_h, const int* __restrict__ s_h_end,
    const int* __restrict__ s_t, const int* __restrict__ s_t_end,
    const int* __restrict__ q_h, const int* __restrict__ q_h_end,
    const int* __restrict__ q_t, const int* __restrict__ q_t_end,
    float* __restrict__ ent_h, float* __restrict__ ent_t, int Bs, int Bq)
{
    int M = Bs + Bq;
    int bid = blockIdx.x;
    int tail = (bid >= M) ? 1 : 0;
    int b = tail ? bid - M : bid;
    const float* src;
    int s, e;
    if (b < Bs) {
        src = all_support + (size_t)b * LMAX * H;
        s = tail ? s_t[b] : s_h[b];
        e = tail ? s_t_end[b] : s_h_end[b];
    } else {
        int m = b - Bs;
        src = all_query + (size_t)m * LMAX * H;
        s = tail ? q_t[m] : q_h[m];
        e = tail ? q_t_end[m] : q_h_end[m];
    }
    if (e < s + 1) e = s + 1;
    int tid = threadIdx.x;
    float a0 = 0.f, a1 = 0.f, a2 = 0.f;
    for (int r = s; r < e; ++r) {
        const float* row = src + (size_t)r * H;
        a0 += row[tid];
        a1 += row[tid + 256];
        a2 += row[tid + 512];
    }
    float rc = 1.0f / (float)(e - s);
    float* dst = (tail ? ent_t : ent_h) + (size_t)b * H;
    dst[tid]       = a0 * rc;
    dst[tid + 256] = a1 * rc;
    dst[tid + 512] = a2 * rc;
}

// ---------------------------------------------------------------------------
// 2) per-sample conv(96) + ReLU + concat + avgpool(2) fused, all in LDS.
//    grid = M samples. 16 "combos" = 8 head filters + 8 tail filters.
//    Each wave takes 4 combos; each lane computes 11 consecutive positions
//    with an 11-register rolling window (2 LDS reads per 11 FMAs).
// ---------------------------------------------------------------------------
#define HT_STRIDE 676
__global__ __launch_bounds__(256) void conv_kernel(
    const float* __restrict__ support_emb, const float* __restrict__ query_emb,
    const float* __restrict__ ent_h, const float* __restrict__ ent_t,
    float* __restrict__ flat, int Bs)
{
    __shared__ float xs[800];            // 768 + zero pad (lanes beyond 673 read junk-safe zeros)
    __shared__ float filt[16 * 96];      // [combo][k]: 0..7 head, 8..15 tail
    __shared__ float ht[16 * HT_STRIDE]; // relu'd conv outputs per combo

    int b = blockIdx.x;
    int tid = threadIdx.x;
    const float* xsrc = (b < Bs) ? (support_emb + (size_t)b * H)
                                 : (query_emb + (size_t)(b - Bs) * H);
    if (tid < 192)
        *(float4*)&xs[tid * 4] = *(const float4*)&xsrc[tid * 4];
    if (tid >= 192 && tid < 200) {
        int o = 768 + (tid - 192) * 4;
        xs[o] = 0.f; xs[o + 1] = 0.f; xs[o + 2] = 0.f; xs[o + 3] = 0.f;
    }
    {
        const float* hrow = ent_h + (size_t)b * H;
        const float* trow = ent_t + (size_t)b * H;
        if (tid < 192) *(float4*)&filt[tid * 4] = *(const float4*)&hrow[tid * 4];
        else           *(float4*)&filt[tid * 4] = *(const float4*)&trow[(tid - 192) * 4];
        if (tid < 128) *(float4*)&filt[(256 + tid) * 4] = *(const float4*)&trow[(64 + tid) * 4];
    }
    __syncthreads();

    int wave = tid >> 6, lane = tid & 63;
    int p0 = lane * 11;                  // base output position for this lane
    #pragma unroll 1
    for (int cc = 0; cc < 4; ++cc) {
        int c = wave * 4 + cc;
        const float* fp = &filt[c * 96];
        float w[11], acc[11];
        #pragma unroll
        for (int i = 0; i < 11; ++i) { w[i] = xs[p0 + i]; acc[i] = 0.f; }
        #pragma unroll
        for (int k = 0; k < 96; ++k) {
            float f = fp[k];             // wave-uniform broadcast
            #pragma unroll
            for (int i = 0; i < 11; ++i)
                acc[i] = fmaf(f, w[(k + i) % 11], acc[i]);
            w[k % 11] = xs[p0 + k + 11]; // slide window (max index 799)
        }
        #pragma unroll
        for (int i = 0; i < 11; ++i) {
            int p = p0 + i;
            if (p < T_CONV) ht[c * HT_STRIDE + p] = fmaxf(acc[i], 0.f);
        }
    }
    __syncthreads();

    // avgpool(k=2,s=2) over concat(h_f, t_f) per filter; straddles h/t boundary at j=336
    float* out = flat + (size_t)b * FC_IN;
    for (int f = 0; f < CONV_NUM; ++f) {
        for (int j = tid; j < T_CONV; j += 256) {
            int i0 = 2 * j, i1 = 2 * j + 1;
            float v0 = (i0 < T_CONV) ? ht[f * HT_STRIDE + i0]
                                     : ht[(8 + f) * HT_STRIDE + (i0 - T_CONV)];
            float v1 = (i1 < T_CONV) ? ht[f * HT_STRIDE + i1]
                                     : ht[(8 + f) * HT_STRIDE + (i1 - T_CONV)];
            out[f * T_CONV + j] = 0.5f * (v0 + v1);
        }
    }
}

// ---------------------------------------------------------------------------
// 3) fp32 GEMM: C[m,n] = sum_k flat[m,k] * W[n,k]   (A row-major, B row-major-K)
//    BM=128 BN=64 BK=32, 256 threads, 8x4 micro-tile, split-K=4 -> parts[]
// ---------------------------------------------------------------------------
#define BM 128
#define BN 64
#define BK 32
#define APAD 132
#define BPAD 68
__global__ __launch_bounds__(256) void gemm_kernel(
    const float* __restrict__ A, const float* __restrict__ W,
    float* __restrict__ parts, int M)
{
    __shared__ float As[BK * APAD];   // [k][m], padded
    __shared__ float Bs[BK * BPAD];   // [k][n], padded

    int tid = threadIdx.x;
    int m0 = blockIdx.x * BM;
    int n0 = blockIdx.y * BN;
    int split = blockIdx.z;
    int kstart = split * KSPLIT;
    int kend = min(kstart + KSPLIT, FC_IN);

    int tr = tid >> 4;   // 0..15 -> rows tr*8..tr*8+7
    int tc = tid & 15;   // 0..15 -> cols tc*4..tc*4+3

    float acc[8][4];
    #pragma unroll
    for (int i = 0; i < 8; ++i)
        #pragma unroll
        for (int j = 0; j < 4; ++j) acc[i][j] = 0.f;

    for (int kb = kstart; kb < kend; kb += BK) {
        // stage A (128x32): 4 float4 per thread, transpose into [k][m]
        #pragma unroll
        for (int it = 0; it < 4; ++it) {
            int q = it * 256 + tid;
            int m = q >> 3, k4 = q & 7;
            int row = m0 + m;
            int kg = kb + k4 * 4;
            float4 v = make_float4(0.f, 0.f, 0.f, 0.f);
            if (row < M) {
                const float* p = A + (size_t)row * FC_IN + kg;
                if (kg + 3 < kend) v = *(const float4*)p;
                else {
                    if (kg + 0 < kend) v.x = p[0];
                    if (kg + 1 < kend) v.y = p[1];
                    if (kg + 2 < kend) v.z = p[2];
                    if (kg + 3 < kend) v.w = p[3];
                }
            }
            As[(k4 * 4 + 0) * APAD + m] = v.x;
            As[(k4 * 4 + 1) * APAD + m] = v.y;
            As[(k4 * 4 + 2) * APAD + m] = v.z;
            As[(k4 * 4 + 3) * APAD + m] = v.w;
        }
        // stage B (64x32): 2 float4 per thread
        #pragma unroll
        for (int it = 0; it < 2; ++it) {
            int q = it * 256 + tid;
            int n = q >> 3, k4 = q & 7;
            int kg = kb + k4 * 4;
            const float* p = W + (size_t)(n0 + n) * FC_IN + kg;
            float4 v = make_float4(0.f, 0.f, 0.f, 0.f);
            if (kg + 3 < kend) v = *(const float4*)p;
            else {
                if (kg + 0 < kend) v.x = p[0];
                if (kg + 1 < kend) v.y = p[1];
                if (kg + 2 < kend) v.z = p[2];
                if (kg + 3 < kend) v.w = p[3];
            }
            Bs[(k4 * 4 + 0) * BPAD + n] = v.x;
            Bs[(k4 * 4 + 1) * BPAD + n] = v.y;
            Bs[(k4 * 4 + 2) * BPAD + n] = v.z;
            Bs[(k4 * 4 + 3) * BPAD + n] = v.w;
        }
        __syncthreads();
        #pragma unroll
        for (int kk = 0; kk < BK; ++kk) {
            float4 a0 = *(float4*)&As[kk * APAD + tr * 8];
            float4 a1 = *(float4*)&As[kk * APAD + tr * 8 + 4];
            float4 b0 = *(float4*)&Bs[kk * BPAD + tc * 4];
            float av[8] = {a0.x, a0.y, a0.z, a0.w, a1.x, a1.y, a1.z, a1.w};
            float bv[4] = {b0.x, b0.y, b0.z, b0.w};
            #pragma unroll
            for (int i = 0; i < 8; ++i)
                #pragma unroll
                for (int j = 0; j < 4; ++j)
                    acc[i][j] = fmaf(av[i], bv[j], acc[i][j]);
        }
        __syncthreads();
    }
    #pragma unroll
    for (int i = 0; i < 8; ++i) {
        int row = m0 + tr * 8 + i;
        if (row < M) {
            float4 v = make_float4(acc[i][0], acc[i][1], acc[i][2], acc[i][3]);
            *(float4*)(parts + ((size_t)split * M + row) * H + n0 + tc * 4) = v;
        }
    }
}

// ---------------------------------------------------------------------------
// 4) proto = mean over K_SHOT of (sum_split parts + bias); grid = Bs/K_SHOT
// ---------------------------------------------------------------------------
__global__ __launch_bounds__(256) void proto_kernel(
    const float* __restrict__ parts, const float* __restrict__ bias,
    float* __restrict__ proto, int M)
{
    int bid = blockIdx.x;            // e*N_WAY + n
    int tid = threadIdx.x;
    int base_row = bid * K_SHOT;
    #pragma unroll
    for (int i = 0; i < 3; ++i) {
        int d = tid + i * 256;
        float s = 0.f;
        for (int k = 0; k < K_SHOT; ++k) {
            size_t row = (size_t)(base_row + k);
            #pragma unroll
            for (int sp = 0; sp < SPLITK; ++sp)
                s += parts[((size_t)sp * M + row) * H + d];
        }
        proto[(size_t)bid * H + d] = s * (1.0f / K_SHOT) + bias[d];
    }
}

// ---------------------------------------------------------------------------
// 5) distances + logits + pred; grid = Bq blocks (one per query)
// ---------------------------------------------------------------------------
__global__ __launch_bounds__(256) void dist_kernel(
    const float* __restrict__ parts, const float* __restrict__ bias,
    const float* __restrict__ proto, float* __restrict__ outp, int M, int Bs, int Bq)
{
    int bid = blockIdx.x;            // e*TOTAL_Q + q == query index
    int e = bid / TOTAL_Q;
    int tid = threadIdx.x;
    int m = Bs + bid;                // row in GEMM output

    float qv[3];
    #pragma unroll
    for (int i = 0; i < 3; ++i) {
        int d = tid + i * 256;
        float s = bias[d];
        #pragma unroll
        for (int sp = 0; sp < SPLITK; ++sp)
            s += parts[((size_t)sp * M + m) * H + d];
        qv[i] = s;
    }

    __shared__ float red[N_WAY][4];
    __shared__ float lvals[N_WAY];
    int wave = tid >> 6, lane = tid & 63;
    for (int n = 0; n < N_WAY; ++n) {
        const float* pr = proto + (size_t)(e * N_WAY + n) * H;
        float p = 0.f;
        #pragma unroll
        for (int i = 0; i < 3; ++i) {
            int d = tid + i * 256;
            float df = pr[d] - qv[i];
            p = fmaf(df, df, p);
        }
        #pragma unroll
        for (int off = 32; off > 0; off >>= 1)
            p += __shfl_down(p, off);
        if (lane == 0) red[n][wave] = p;
    }
    __syncthreads();
    if (tid < N_WAY) {
        float v = red[tid][0] + red[tid][1] + red[tid][2] + red[tid][3];
        lvals[tid] = -v;
        outp[(size_t)bid * (N_WAY + 1) + tid] = -v;
    }
    __syncthreads();
    if (tid == 0) {
        float mn = lvals[0];
        #pragma unroll
        for (int n = 1; n < N_WAY; ++n) mn = fminf(mn, lvals[n]);
        float last = mn - 1.0f;
        outp[(size_t)bid * (N_WAY + 1) + N_WAY] = last;
        float best = lvals[0];
        int bi = 0;
        for (int n = 1; n < N_WAY; ++n)
            if (lvals[n] > best) { best = lvals[n]; bi = n; }
        if (last > best) bi = N_WAY;   // can never trigger; parity with reference
        outp[(size_t)Bq * (N_WAY + 1) + bid] = (float)bi;
    }
}

// ---------------------------------------------------------------------------
extern "C" void kernel_launch(void* const* d_in, const int* in_sizes, int n_in,
                              void* d_out, int out_size, void* d_ws, size_t ws_size,
                              hipStream_t stream)
{
    const float* all_support = (const float*)d_in[0];
    const float* support_emb = (const float*)d_in[1];
    const float* all_query   = (const float*)d_in[2];
    const float* query_emb   = (const float*)d_in[3];
    const float* fc_W        = (const float*)d_in[4];
    const float* fc_b        = (const float*)d_in[5];
    const int* s_eh     = (const int*)d_in[6];
    const int* s_eh_end = (const int*)d_in[7];
    const int* s_et     = (const int*)d_in[8];
    const int* s_et_end = (const int*)d_in[9];
    const int* q_eh     = (const int*)d_in[10];
    const int* q_eh_end = (const int*)d_in[11];
    const int* q_et     = (const int*)d_in[12];
    const int* q_et_end = (const int*)d_in[13];

    int Bs = in_sizes[1] / H;   // 400
    int Bq = in_sizes[3] / H;   // 1200
    int M = Bs + Bq;            // 1600

    float* ws    = (float*)d_ws;
    float* ent_h = ws;                                   // M*H
    float* ent_t = ent_h + (size_t)M * H;                // M*H
    float* flat  = ent_t + (size_t)M * H;                // M*FC_IN
    float* parts = flat + (size_t)M * FC_IN;             // SPLITK*M*H
    float* proto = parts + (size_t)SPLITK * M * H;       // (Bs/K_SHOT)*H

    entity_kernel<<<2 * M, 256, 0, stream>>>(
        all_support, all_query, s_eh, s_eh_end, s_et, s_et_end,
        q_eh, q_eh_end, q_et, q_et_end, ent_h, ent_t, Bs, Bq);

    conv_kernel<<<M, 256, 0, stream>>>(support_emb, query_emb, ent_h, ent_t, flat, Bs);

    dim3 gg((M + BM - 1) / BM, H / BN, SPLITK);
    gemm_kernel<<<gg, 256, 0, stream>>>(flat, fc_W, parts, M);

    proto_kernel<<<Bs / K_SHOT, 256, 0, stream>>>(parts, fc_b, proto, M);

    dist_kernel<<<Bq, 256, 0, stream>>>(parts, fc_b, proto, (float*)d_out, M, Bs, Bq);
}

// Round 2
// 198.059 us; speedup vs baseline: 1.6138x; 1.6138x over previous
//
#include <hip/hip_runtime.h>

// Problem constants (fixed by setup_inputs in the reference)
#define H        768
#define LMAX     128
#define CONV_NUM 8
#define CONV_SIZE 96
#define T_CONV   673            // H - CONV_SIZE + 1
#define FC_IN    5384           // CONV_NUM * T_CONV
#define KP       5408           // K padded to multiple of 32 (169 steps)
#define KSTEPS   (KP / 32)      // 169
#define N_WAY    10
#define K_SHOT   5
#define TOTAL_Q  150
#define SPLITK   8

using s16x8 = __attribute__((ext_vector_type(8))) short;   // 8 bf16 (4 VGPRs)
using f32x4 = __attribute__((ext_vector_type(4))) float;   // MFMA acc
typedef unsigned short u16;

__device__ __forceinline__ u16 f2bf(float x) {              // RNE float->bf16 bits
    unsigned u = __float_as_uint(x);
    u += 0x7FFFu + ((u >> 16) & 1u);
    return (u16)(u >> 16);
}
__device__ __forceinline__ float bf2f(u16 b) { return __uint_as_float(((unsigned)b) << 16); }

__device__ __forceinline__ void gl16(const u16* g, u16* l) { // global->LDS 16B async
    __builtin_amdgcn_global_load_lds(
        (const __attribute__((address_space(1))) unsigned int*)g,
        (__attribute__((address_space(3))) unsigned int*)l, 16, 0, 0);
}

// ---------------------------------------------------------------------------
// 1) entity gather: mean of x[b, s:max(e,s+1)] -> [.,768]
// ---------------------------------------------------------------------------
__global__ __launch_bounds__(256) void entity_kernel(
    const float* __restrict__ all_support, const float* __restrict__ all_query,
    const int* __restrict__ s_h, const int* __restrict__ s_h_end,
    const int* __restrict__ s_t, const int* __restrict__ s_t_end,
    const int* __restrict__ q_h, const int* __restrict__ q_h_end,
    const int* __restrict__ q_t, const int* __restrict__ q_t_end,
    float* __restrict__ ent_h, float* __restrict__ ent_t, int Bs, int Bq)
{
    int M = Bs + Bq;
    int bid = blockIdx.x;
    int tail = (bid >= M) ? 1 : 0;
    int b = tail ? bid - M : bid;
    const float* src;
    int s, e;
    if (b < Bs) {
        src = all_support + (size_t)b * LMAX * H;
        s = tail ? s_t[b] : s_h[b];
        e = tail ? s_t_end[b] : s_h_end[b];
    } else {
        int m = b - Bs;
        src = all_query + (size_t)m * LMAX * H;
        s = tail ? q_t[m] : q_h[m];
        e = tail ? q_t_end[m] : q_h_end[m];
    }
    if (e < s + 1) e = s + 1;
    int tid = threadIdx.x;
    float a0 = 0.f, a1 = 0.f, a2 = 0.f;
    for (int r = s; r < e; ++r) {
        const float* row = src + (size_t)r * H;
        a0 += row[tid];
        a1 += row[tid + 256];
        a2 += row[tid + 512];
    }
    float rc = 1.0f / (float)(e - s);
    float* dst = (tail ? ent_t : ent_h) + (size_t)b * H;
    dst[tid]       = a0 * rc;
    dst[tid + 256] = a1 * rc;
    dst[tid + 512] = a2 * rc;
}

// ---------------------------------------------------------------------------
// 2) per-sample conv(96)+ReLU+concat+avgpool(2); emits flat as bf16 hi/lo pair
// ---------------------------------------------------------------------------
#define HT_STRIDE 676
__global__ __launch_bounds__(256) void conv_kernel(
    const float* __restrict__ support_emb, const float* __restrict__ query_emb,
    const float* __restrict__ ent_h, const float* __restrict__ ent_t,
    u16* __restrict__ flat_hi, u16* __restrict__ flat_lo, int Bs)
{
    __shared__ float xs[800];
    __shared__ float filt[16 * 96];
    __shared__ float ht[16 * HT_STRIDE];

    int b = blockIdx.x;
    int tid = threadIdx.x;
    const float* xsrc = (b < Bs) ? (support_emb + (size_t)b * H)
                                 : (query_emb + (size_t)(b - Bs) * H);
    if (tid < 192)
        *(float4*)&xs[tid * 4] = *(const float4*)&xsrc[tid * 4];
    if (tid >= 192 && tid < 200) {
        int o = 768 + (tid - 192) * 4;
        xs[o] = 0.f; xs[o + 1] = 0.f; xs[o + 2] = 0.f; xs[o + 3] = 0.f;
    }
    {
        const float* hrow = ent_h + (size_t)b * H;
        const float* trow = ent_t + (size_t)b * H;
        if (tid < 192) *(float4*)&filt[tid * 4] = *(const float4*)&hrow[tid * 4];
        else           *(float4*)&filt[tid * 4] = *(const float4*)&trow[(tid - 192) * 4];
        if (tid < 128) *(float4*)&filt[(256 + tid) * 4] = *(const float4*)&trow[(64 + tid) * 4];
    }
    __syncthreads();

    int wave = tid >> 6, lane = tid & 63;
    int p0 = lane * 11;
    #pragma unroll 1
    for (int cc = 0; cc < 4; ++cc) {
        int c = wave * 4 + cc;
        const float* fp = &filt[c * 96];
        float w[11], acc[11];
        #pragma unroll
        for (int i = 0; i < 11; ++i) { w[i] = xs[p0 + i]; acc[i] = 0.f; }
        #pragma unroll
        for (int k = 0; k < 96; ++k) {
            float f = fp[k];
            #pragma unroll
            for (int i = 0; i < 11; ++i)
                acc[i] = fmaf(f, w[(k + i) % 11], acc[i]);
            w[k % 11] = xs[p0 + k + 11];
        }
        #pragma unroll
        for (int i = 0; i < 11; ++i) {
            int p = p0 + i;
            if (p < T_CONV) ht[c * HT_STRIDE + p] = fmaxf(acc[i], 0.f);
        }
    }
    __syncthreads();

    u16* oh = flat_hi + (size_t)b * KP;
    u16* ol = flat_lo + (size_t)b * KP;
    for (int f = 0; f < CONV_NUM; ++f) {
        for (int j = tid; j < T_CONV; j += 256) {
            int i0 = 2 * j, i1 = 2 * j + 1;
            float v0 = (i0 < T_CONV) ? ht[f * HT_STRIDE + i0]
                                     : ht[(8 + f) * HT_STRIDE + (i0 - T_CONV)];
            float v1 = (i1 < T_CONV) ? ht[f * HT_STRIDE + i1]
                                     : ht[(8 + f) * HT_STRIDE + (i1 - T_CONV)];
            float val = 0.5f * (v0 + v1);
            u16 hb = f2bf(val);
            oh[f * T_CONV + j] = hb;
            ol[f * T_CONV + j] = f2bf(val - bf2f(hb));
        }
    }
    for (int j = FC_IN + tid; j < KP; j += 256) { oh[j] = 0; ol[j] = 0; }  // zero K-pad
}

// ---------------------------------------------------------------------------
// 2b) split fc_W -> bf16 hi/lo, padded to KP with zeros
// ---------------------------------------------------------------------------
__global__ __launch_bounds__(256) void wsplit_kernel(
    const float* __restrict__ W, u16* __restrict__ Wh, u16* __restrict__ Wl)
{
    int r = blockIdx.x;
    for (int j = threadIdx.x; j < KP; j += 256) {
        float v = (j < FC_IN) ? W[(size_t)r * FC_IN + j] : 0.f;
        u16 hb = f2bf(v);
        Wh[(size_t)r * KP + j] = hb;
        Wl[(size_t)r * KP + j] = f2bf(v - bf2f(hb));
    }
}

// ---------------------------------------------------------------------------
// 3) split-bf16 MFMA GEMM: C = Ahi*Whi + Ahi*Wlo + Alo*Whi  (fp32 acc)
//    128x128 tile, BK=32, 4 waves x (64x64), frag-native LDS layout
//    [frag(8)][kgroup(4)][row(16)][8 bf16] per 8KB segment -> lane-linear reads.
//    global_load_lds w=16, double-buffered 2-phase loop. split-K=8.
// ---------------------------------------------------------------------------
#define SEG 4096   // ushorts per segment (8KB)
__global__ __launch_bounds__(256) void gemm_mfma(
    const u16* __restrict__ Ah_g, const u16* __restrict__ Al_g,
    const u16* __restrict__ Bh_g, const u16* __restrict__ Bl_g,
    float* __restrict__ parts, int M)
{
    __shared__ u16 lds[2][4 * SEG];   // 64 KB: {Ah, Al, Bh, Bl} x dbuf

    int tid = threadIdx.x;
    int m0 = blockIdx.x * 128;
    int n0 = blockIdx.y * 128;
    int split = blockIdx.z;
    int ks0 = (KSTEPS * split) / SPLITK;
    int ks1 = (KSTEPS * (split + 1)) / SPLITK;

    // staging: 512 chunks of 16B per segment = 2 issues/thread.
    // chunk c: frag=c>>6, kg=(c>>4)&3, row=c&15 ; LDS dest = seg + c*8 (lane-linear)
    int c0 = tid, c1 = 256 + tid;
    int f0 = c0 >> 6, kg0 = (c0 >> 4) & 3, r0 = c0 & 15;
    int f1 = c1 >> 6, kg1 = (c1 >> 4) & 3, r1 = c1 & 15;
    size_t aoff0 = (size_t)(m0 + f0 * 16 + r0) * KP + kg0 * 8;
    size_t aoff1 = (size_t)(m0 + f1 * 16 + r1) * KP + kg1 * 8;
    size_t boff0 = (size_t)(n0 + f0 * 16 + r0) * KP + kg0 * 8;
    size_t boff1 = (size_t)(n0 + f1 * 16 + r1) * KP + kg1 * 8;

    int w = tid >> 6, lane = tid & 63;
    int wm = w >> 1, wn = w & 1;              // wave -> 64x64 quadrant
    int lfr = ((lane >> 4) * 16 + (lane & 15)) * 8;  // within-frag ushort offset

    f32x4 acc[4][4];
    #pragma unroll
    for (int i = 0; i < 4; ++i)
        #pragma unroll
        for (int j = 0; j < 4; ++j) acc[i][j] = (f32x4){0.f, 0.f, 0.f, 0.f};

    // prologue: stage first K-step into buf 0
    {
        int kb = ks0 * 32;
        u16* L = &lds[0][0];
        gl16(Ah_g + aoff0 + kb, L + 0 * SEG + c0 * 8);
        gl16(Ah_g + aoff1 + kb, L + 0 * SEG + c1 * 8);
        gl16(Al_g + aoff0 + kb, L + 1 * SEG + c0 * 8);
        gl16(Al_g + aoff1 + kb, L + 1 * SEG + c1 * 8);
        gl16(Bh_g + boff0 + kb, L + 2 * SEG + c0 * 8);
        gl16(Bh_g + boff1 + kb, L + 2 * SEG + c1 * 8);
        gl16(Bl_g + boff0 + kb, L + 3 * SEG + c0 * 8);
        gl16(Bl_g + boff1 + kb, L + 3 * SEG + c1 * 8);
    }
    asm volatile("s_waitcnt vmcnt(0)" ::: "memory");
    __syncthreads();

    int cur = 0;
    for (int ks = ks0; ks < ks1; ++ks) {
        if (ks + 1 < ks1) {                   // prefetch next K-step into other buf
            int kb = (ks + 1) * 32;
            u16* L = &lds[cur ^ 1][0];
            gl16(Ah_g + aoff0 + kb, L + 0 * SEG + c0 * 8);
            gl16(Ah_g + aoff1 + kb, L + 0 * SEG + c1 * 8);
            gl16(Al_g + aoff0 + kb, L + 1 * SEG + c0 * 8);
            gl16(Al_g + aoff1 + kb, L + 1 * SEG + c1 * 8);
            gl16(Bh_g + boff0 + kb, L + 2 * SEG + c0 * 8);
            gl16(Bh_g + boff1 + kb, L + 2 * SEG + c1 * 8);
            gl16(Bl_g + boff0 + kb, L + 3 * SEG + c0 * 8);
            gl16(Bl_g + boff1 + kb, L + 3 * SEG + c1 * 8);
        }
        const u16* L = &lds[cur][0];
        s16x8 ah[4], al[4], bh[4], bl[4];
        #pragma unroll
        for (int f = 0; f < 4; ++f) {
            ah[f] = *(const s16x8*)(L + 0 * SEG + (wm * 4 + f) * 512 + lfr);
            al[f] = *(const s16x8*)(L + 1 * SEG + (wm * 4 + f) * 512 + lfr);
            bh[f] = *(const s16x8*)(L + 2 * SEG + (wn * 4 + f) * 512 + lfr);
            bl[f] = *(const s16x8*)(L + 3 * SEG + (wn * 4 + f) * 512 + lfr);
        }
        #pragma unroll
        for (int i = 0; i < 4; ++i)
            #pragma unroll
            for (int j = 0; j < 4; ++j) {
                acc[i][j] = __builtin_amdgcn_mfma_f32_16x16x32_bf16(ah[i], bh[j], acc[i][j], 0, 0, 0);
                acc[i][j] = __builtin_amdgcn_mfma_f32_16x16x32_bf16(ah[i], bl[j], acc[i][j], 0, 0, 0);
                acc[i][j] = __builtin_amdgcn_mfma_f32_16x16x32_bf16(al[i], bh[j], acc[i][j], 0, 0, 0);
            }
        asm volatile("s_waitcnt vmcnt(0)" ::: "memory");
        __syncthreads();
        cur ^= 1;
    }

    // epilogue: C/D layout col=lane&15, row=(lane>>4)*4+reg  [m91-verified]
    int rbase = m0 + wm * 64 + (lane >> 4) * 4;
    int cbase = n0 + wn * 64 + (lane & 15);
    #pragma unroll
    for (int i = 0; i < 4; ++i) {
        int row0 = rbase + i * 16;
        #pragma unroll
        for (int j = 0; j < 4; ++j) {
            int col = cbase + j * 16;
            float* dst = parts + ((size_t)split * M + row0) * H + col;
            #pragma unroll
            for (int r = 0; r < 4; ++r)
                if (row0 + r < M) dst[(size_t)r * H] = acc[i][j][r];
        }
    }
}

// ---------------------------------------------------------------------------
// 4) proto = mean over K_SHOT of (sum_split parts + bias)
// ---------------------------------------------------------------------------
__global__ __launch_bounds__(256) void proto_kernel(
    const float* __restrict__ parts, const float* __restrict__ bias,
    float* __restrict__ proto, int M)
{
    int bid = blockIdx.x;
    int tid = threadIdx.x;
    int base_row = bid * K_SHOT;
    #pragma unroll
    for (int i = 0; i < 3; ++i) {
        int d = tid + i * 256;
        float s = 0.f;
        for (int k = 0; k < K_SHOT; ++k) {
            size_t row = (size_t)(base_row + k);
            #pragma unroll
            for (int sp = 0; sp < SPLITK; ++sp)
                s += parts[((size_t)sp * M + row) * H + d];
        }
        proto[(size_t)bid * H + d] = s * (1.0f / K_SHOT) + bias[d];
    }
}

// ---------------------------------------------------------------------------
// 5) distances + logits + pred
// ---------------------------------------------------------------------------
__global__ __launch_bounds__(256) void dist_kernel(
    const float* __restrict__ parts, const float* __restrict__ bias,
    const float* __restrict__ proto, float* __restrict__ outp, int M, int Bs, int Bq)
{
    int bid = blockIdx.x;
    int e = bid / TOTAL_Q;
    int tid = threadIdx.x;
    int m = Bs + bid;

    float qv[3];
    #pragma unroll
    for (int i = 0; i < 3; ++i) {
        int d = tid + i * 256;
        float s = bias[d];
        #pragma unroll
        for (int sp = 0; sp < SPLITK; ++sp)
            s += parts[((size_t)sp * M + m) * H + d];
        qv[i] = s;
    }

    __shared__ float red[N_WAY][4];
    __shared__ float lvals[N_WAY];
    int wave = tid >> 6, lane = tid & 63;
    for (int n = 0; n < N_WAY; ++n) {
        const float* pr = proto + (size_t)(e * N_WAY + n) * H;
        float p = 0.f;
        #pragma unroll
        for (int i = 0; i < 3; ++i) {
            int d = tid + i * 256;
            float df = pr[d] - qv[i];
            p = fmaf(df, df, p);
        }
        #pragma unroll
        for (int off = 32; off > 0; off >>= 1)
            p += __shfl_down(p, off);
        if (lane == 0) red[n][wave] = p;
    }
    __syncthreads();
    if (tid < N_WAY) {
        float v = red[tid][0] + red[tid][1] + red[tid][2] + red[tid][3];
        lvals[tid] = -v;
        outp[(size_t)bid * (N_WAY + 1) + tid] = -v;
    }
    __syncthreads();
    if (tid == 0) {
        float mn = lvals[0];
        #pragma unroll
        for (int n = 1; n < N_WAY; ++n) mn = fminf(mn, lvals[n]);
        float last = mn - 1.0f;
        outp[(size_t)bid * (N_WAY + 1) + N_WAY] = last;
        float best = lvals[0];
        int bi = 0;
        for (int n = 1; n < N_WAY; ++n)
            if (lvals[n] > best) { best = lvals[n]; bi = n; }
        if (last > best) bi = N_WAY;
        outp[(size_t)Bq * (N_WAY + 1) + bid] = (float)bi;
    }
}

// ---------------------------------------------------------------------------
extern "C" void kernel_launch(void* const* d_in, const int* in_sizes, int n_in,
                              void* d_out, int out_size, void* d_ws, size_t ws_size,
                              hipStream_t stream)
{
    const float* all_support = (const float*)d_in[0];
    const float* support_emb = (const float*)d_in[1];
    const float* all_query   = (const float*)d_in[2];
    const float* query_emb   = (const float*)d_in[3];
    const float* fc_W        = (const float*)d_in[4];
    const float* fc_b        = (const float*)d_in[5];
    const int* s_eh     = (const int*)d_in[6];
    const int* s_eh_end = (const int*)d_in[7];
    const int* s_et     = (const int*)d_in[8];
    const int* s_et_end = (const int*)d_in[9];
    const int* q_eh     = (const int*)d_in[10];
    const int* q_eh_end = (const int*)d_in[11];
    const int* q_et     = (const int*)d_in[12];
    const int* q_et_end = (const int*)d_in[13];

    int Bs = in_sizes[1] / H;   // 400
    int Bq = in_sizes[3] / H;   // 1200
    int M = Bs + Bq;            // 1600

    // workspace layout (all segment sizes are multiples of 16B)
    float* ent_h = (float*)d_ws;                          // M*H
    float* ent_t = ent_h + (size_t)M * H;                 // M*H
    float* proto = ent_t + (size_t)M * H;                 // (Bs/K_SHOT)*H
    float* parts = proto + (size_t)(Bs / K_SHOT) * H;     // SPLITK*M*H
    u16* Wh      = (u16*)(parts + (size_t)SPLITK * M * H);// H*KP
    u16* Wl      = Wh + (size_t)H * KP;                   // H*KP
    u16* flat_hi = Wl + (size_t)H * KP;                   // M*KP
    u16* flat_lo = flat_hi + (size_t)M * KP;              // M*KP (last: GEMM A-OOB
                                                          //  rows read harmless ws slack)

    wsplit_kernel<<<H, 256, 0, stream>>>(fc_W, Wh, Wl);

    entity_kernel<<<2 * M, 256, 0, stream>>>(
        all_support, all_query, s_eh, s_eh_end, s_et, s_et_end,
        q_eh, q_eh_end, q_et, q_et_end, ent_h, ent_t, Bs, Bq);

    conv_kernel<<<M, 256, 0, stream>>>(support_emb, query_emb, ent_h, ent_t,
                                       flat_hi, flat_lo, Bs);

    dim3 gg((M + 127) / 128, H / 128, SPLITK);
    gemm_mfma<<<gg, 256, 0, stream>>>(flat_hi, flat_lo, Wh, Wl, parts, M);

    proto_kernel<<<Bs / K_SHOT, 256, 0, stream>>>(parts, fc_b, proto, M);

    dist_kernel<<<Bq, 256, 0, stream>>>(parts, fc_b, proto, (float*)d_out, M, Bs, Bq);
}

// Round 3
// 158.691 us; speedup vs baseline: 2.0141x; 1.2481x over previous
//
#include <hip/hip_runtime.h>

// Problem constants (fixed by setup_inputs in the reference)
#define H        768
#define LMAX     128
#define CONV_NUM 8
#define CONV_SIZE 96
#define T_CONV   673            // H - CONV_SIZE + 1
#define FC_IN    5384           // CONV_NUM * T_CONV
#define KP       5408           // K padded to multiple of 32 (169 steps)
#define KSTEPS   (KP / 32)      // 169
#define N_WAY    10
#define K_SHOT   5
#define TOTAL_Q  150
#define SPLITK   8
#define BS       400
#define BQ       1200
#define MTOT     1600           // BS + BQ
#define NPROTO   80             // BS / K_SHOT
#define MA       1280           // NPROTO + BQ  (GEMM row count, = 10*128 exact)

using s16x8 = __attribute__((ext_vector_type(8))) short;   // 8 bf16 (4 VGPRs)
using f32x4 = __attribute__((ext_vector_type(4))) float;   // MFMA acc
typedef unsigned short u16;

__device__ __forceinline__ u16 f2bf(float x) {              // RNE float->bf16 bits
    unsigned u = __float_as_uint(x);
    u += 0x7FFFu + ((u >> 16) & 1u);
    return (u16)(u >> 16);
}
__device__ __forceinline__ float bf2f(u16 b) { return __uint_as_float(((unsigned)b) << 16); }

__device__ __forceinline__ void gl16(const u16* g, u16* l) { // global->LDS 16B async
    __builtin_amdgcn_global_load_lds(
        (const __attribute__((address_space(1))) unsigned int*)g,
        (__attribute__((address_space(3))) unsigned int*)l, 16, 0, 0);
}

// ---------------------------------------------------------------------------
// 1) fused: [blocks 0..MTOT): entity-gather + conv(96) + ReLU + concat +
//    avgpool(2) -> bf16 hi/lo rows.  Support rows -> flatS (pre-average
//    staging), query rows -> A rows [80..1280).
//    [blocks MTOT..MTOT+H): split fc_W row -> bf16 hi/lo (independent work,
//    interleaves with conv blocks to hide its HBM traffic).
// ---------------------------------------------------------------------------
#define HT_STRIDE 676
__global__ __launch_bounds__(256) void pre_kernel(
    const float* __restrict__ all_support, const float* __restrict__ all_query,
    const float* __restrict__ support_emb, const float* __restrict__ query_emb,
    const float* __restrict__ fc_W,
    const int* __restrict__ s_eh, const int* __restrict__ s_eh_end,
    const int* __restrict__ s_et, const int* __restrict__ s_et_end,
    const int* __restrict__ q_eh, const int* __restrict__ q_eh_end,
    const int* __restrict__ q_et, const int* __restrict__ q_et_end,
    u16* __restrict__ flatS_hi, u16* __restrict__ flatS_lo,
    u16* __restrict__ A_hi, u16* __restrict__ A_lo,
    u16* __restrict__ Wh, u16* __restrict__ Wl)
{
    int bid = blockIdx.x;
    int tid = threadIdx.x;

    if (bid >= MTOT) {                      // ---- W-split path ----
        int r = bid - MTOT;
        for (int j = tid; j < KP; j += 256) {
            float v = (j < FC_IN) ? fc_W[(size_t)r * FC_IN + j] : 0.f;
            u16 hb = f2bf(v);
            Wh[(size_t)r * KP + j] = hb;
            Wl[(size_t)r * KP + j] = f2bf(v - bf2f(hb));
        }
        return;
    }

    // ---- conv path ----
    __shared__ float xs[800];
    __shared__ float filt[16 * 96];         // [0..767]=head ent, [768..1535]=tail ent
    __shared__ float ht[16 * HT_STRIDE];

    int b = bid;
    const float* src;
    int sh, eh, st, et;
    if (b < BS) {
        src = all_support + (size_t)b * LMAX * H;
        sh = s_eh[b]; eh = s_eh_end[b]; st = s_et[b]; et = s_et_end[b];
    } else {
        int m = b - BS;
        src = all_query + (size_t)m * LMAX * H;
        sh = q_eh[m]; eh = q_eh_end[m]; st = q_et[m]; et = q_et_end[m];
    }
    if (eh < sh + 1) eh = sh + 1;
    if (et < st + 1) et = st + 1;

    {   // entity gather -> filt (head then tail), coalesced row reads
        float a0 = 0.f, a1 = 0.f, a2 = 0.f;
        for (int r = sh; r < eh; ++r) {
            const float* row = src + (size_t)r * H;
            a0 += row[tid]; a1 += row[tid + 256]; a2 += row[tid + 512];
        }
        float rc = 1.0f / (float)(eh - sh);
        filt[tid] = a0 * rc; filt[tid + 256] = a1 * rc; filt[tid + 512] = a2 * rc;
        a0 = a1 = a2 = 0.f;
        for (int r = st; r < et; ++r) {
            const float* row = src + (size_t)r * H;
            a0 += row[tid]; a1 += row[tid + 256]; a2 += row[tid + 512];
        }
        rc = 1.0f / (float)(et - st);
        filt[768 + tid] = a0 * rc; filt[1024 + tid] = a1 * rc; filt[1280 + tid] = a2 * rc;
    }
    const float* xsrc = (b < BS) ? (support_emb + (size_t)b * H)
                                 : (query_emb + (size_t)(b - BS) * H);
    if (tid < 192)
        *(float4*)&xs[tid * 4] = *(const float4*)&xsrc[tid * 4];
    if (tid >= 192 && tid < 200) {
        int o = 768 + (tid - 192) * 4;
        xs[o] = 0.f; xs[o + 1] = 0.f; xs[o + 2] = 0.f; xs[o + 3] = 0.f;
    }
    __syncthreads();

    int wave = tid >> 6, lane = tid & 63;
    int p0 = lane * 11;
    #pragma unroll 1
    for (int cc = 0; cc < 4; ++cc) {
        int c = wave * 4 + cc;
        const float* fp = &filt[c * 96];
        float w[11], acc[11];
        #pragma unroll
        for (int i = 0; i < 11; ++i) { w[i] = xs[p0 + i]; acc[i] = 0.f; }
        #pragma unroll
        for (int k = 0; k < 96; ++k) {
            float f = fp[k];
            #pragma unroll
            for (int i = 0; i < 11; ++i)
                acc[i] = fmaf(f, w[(k + i) % 11], acc[i]);
            w[k % 11] = xs[p0 + k + 11];
        }
        #pragma unroll
        for (int i = 0; i < 11; ++i) {
            int p = p0 + i;
            if (p < T_CONV) ht[c * HT_STRIDE + p] = fmaxf(acc[i], 0.f);
        }
    }
    __syncthreads();

    u16* oh; u16* ol;
    if (b < BS) { oh = flatS_hi + (size_t)b * KP;            ol = flatS_lo + (size_t)b * KP; }
    else        { oh = A_hi + (size_t)(NPROTO + b - BS) * KP; ol = A_lo + (size_t)(NPROTO + b - BS) * KP; }
    for (int f = 0; f < CONV_NUM; ++f) {
        for (int j = tid; j < T_CONV; j += 256) {
            int i0 = 2 * j, i1 = 2 * j + 1;
            float v0 = (i0 < T_CONV) ? ht[f * HT_STRIDE + i0]
                                     : ht[(8 + f) * HT_STRIDE + (i0 - T_CONV)];
            float v1 = (i1 < T_CONV) ? ht[f * HT_STRIDE + i1]
                                     : ht[(8 + f) * HT_STRIDE + (i1 - T_CONV)];
            float val = 0.5f * (v0 + v1);
            u16 hb = f2bf(val);
            oh[f * T_CONV + j] = hb;
            ol[f * T_CONV + j] = f2bf(val - bf2f(hb));
        }
    }
    for (int j = FC_IN + tid; j < KP; j += 256) { oh[j] = 0; ol[j] = 0; }
}

// ---------------------------------------------------------------------------
// 2) support pre-average: A rows [0..80) = mean over K_SHOT of flatS rows.
//    fc is linear, so mean-before-GEMM == mean-after-GEMM (proto).
// ---------------------------------------------------------------------------
__global__ __launch_bounds__(256) void avg_kernel(
    const u16* __restrict__ flatS_hi, const u16* __restrict__ flatS_lo,
    u16* __restrict__ A_hi, u16* __restrict__ A_lo)
{
    int i = blockIdx.x;                   // proto row 0..79
    size_t base = (size_t)i * K_SHOT * KP;
    for (int j = threadIdx.x; j < KP; j += 256) {
        float s = 0.f;
        #pragma unroll
        for (int k = 0; k < K_SHOT; ++k) {
            size_t idx = base + (size_t)k * KP + j;
            s += bf2f(flatS_hi[idx]) + bf2f(flatS_lo[idx]);
        }
        float v = s * (1.0f / K_SHOT);
        u16 hb = f2bf(v);
        A_hi[(size_t)i * KP + j] = hb;
        A_lo[(size_t)i * KP + j] = f2bf(v - bf2f(hb));
    }
}

// ---------------------------------------------------------------------------
// 3) split-bf16 MFMA GEMM: C = Ahi*Whi + Ahi*Wlo + Alo*Whi  (fp32 acc)
//    128x128 tile, BK=32, 4 waves x (64x64). frag-native LDS layout
//    [frag(8)][kgroup(4)][row(16)][8 bf16] per 8KB segment, lane-linear.
//    2-ahead prefetch with counted vmcnt(8) + raw s_barrier (T3/T4-lite).
//    grid = (MA/128=10, H/128=6, SPLITK=8) = 480 blocks = exactly 2/CU.
// ---------------------------------------------------------------------------
#define SEG 4096   // ushorts per segment (8KB)

#define STAGE(ks, buf) do {                                   \
    int kb_ = (ks) * 32;                                      \
    u16* L_ = &lds[buf][0];                                   \
    gl16(Ah_g + aoff0 + kb_, L_ + 0 * SEG + c0 * 8);          \
    gl16(Ah_g + aoff1 + kb_, L_ + 0 * SEG + c1 * 8);          \
    gl16(Al_g + aoff0 + kb_, L_ + 1 * SEG + c0 * 8);          \
    gl16(Al_g + aoff1 + kb_, L_ + 1 * SEG + c1 * 8);          \
    gl16(Bh_g + boff0 + kb_, L_ + 2 * SEG + c0 * 8);          \
    gl16(Bh_g + boff1 + kb_, L_ + 2 * SEG + c1 * 8);          \
    gl16(Bl_g + boff0 + kb_, L_ + 3 * SEG + c0 * 8);          \
    gl16(Bl_g + boff1 + kb_, L_ + 3 * SEG + c1 * 8);          \
} while (0)

__global__ __launch_bounds__(256, 2) void gemm_mfma(
    const u16* __restrict__ Ah_g, const u16* __restrict__ Al_g,
    const u16* __restrict__ Bh_g, const u16* __restrict__ Bl_g,
    float* __restrict__ parts)
{
    __shared__ u16 lds[2][4 * SEG];   // 64 KB: {Ah, Al, Bh, Bl} x dbuf

    int tid = threadIdx.x;
    int m0 = blockIdx.x * 128;
    int n0 = blockIdx.y * 128;
    int split = blockIdx.z;
    int ks0 = (KSTEPS * split) / SPLITK;
    int nk = (KSTEPS * (split + 1)) / SPLITK - ks0;   // 21 or 22

    // staging: 512 chunks of 16B per segment = 2 issues/thread per segment.
    // chunk c: frag=c>>6, kg=(c>>4)&3, row=c&15 ; LDS dest = seg + c*8 (lane-linear)
    int c0 = tid, c1 = 256 + tid;
    int f0 = c0 >> 6, kg0 = (c0 >> 4) & 3, r0 = c0 & 15;
    int f1 = c1 >> 6, kg1 = (c1 >> 4) & 3, r1 = c1 & 15;
    size_t aoff0 = (size_t)(m0 + f0 * 16 + r0) * KP + kg0 * 8;
    size_t aoff1 = (size_t)(m0 + f1 * 16 + r1) * KP + kg1 * 8;
    size_t boff0 = (size_t)(n0 + f0 * 16 + r0) * KP + kg0 * 8;
    size_t boff1 = (size_t)(n0 + f1 * 16 + r1) * KP + kg1 * 8;

    int w = tid >> 6, lane = tid & 63;
    int wm = w >> 1, wn = w & 1;              // wave -> 64x64 quadrant
    int lfr = ((lane >> 4) * 16 + (lane & 15)) * 8;  // within-frag ushort offset

    f32x4 acc[4][4];
    #pragma unroll
    for (int i = 0; i < 4; ++i)
        #pragma unroll
        for (int j = 0; j < 4; ++j) acc[i][j] = (f32x4){0.f, 0.f, 0.f, 0.f};

    STAGE(ks0, 0);          // 8 loads in flight
    STAGE(ks0 + 1, 1);      // 16 in flight (nk >= 21 always)

    int cur = 0;
    for (int k = 0; k < nk; ++k) {
        // wait for step k's 8 loads (oldest); keep step k+1's flying
        if (k + 1 < nk) asm volatile("s_waitcnt vmcnt(8)" ::: "memory");
        else            asm volatile("s_waitcnt vmcnt(0)" ::: "memory");
        __builtin_amdgcn_s_barrier();

        const u16* L = &lds[cur][0];
        s16x8 ah[4], al[4], bh[4], bl[4];
        #pragma unroll
        for (int f = 0; f < 4; ++f) {
            ah[f] = *(const s16x8*)(L + 0 * SEG + (wm * 4 + f) * 512 + lfr);
            al[f] = *(const s16x8*)(L + 1 * SEG + (wm * 4 + f) * 512 + lfr);
            bh[f] = *(const s16x8*)(L + 2 * SEG + (wn * 4 + f) * 512 + lfr);
            bl[f] = *(const s16x8*)(L + 3 * SEG + (wn * 4 + f) * 512 + lfr);
        }
        asm volatile("s_waitcnt lgkmcnt(0)" ::: "memory");
        __builtin_amdgcn_s_barrier();       // all waves done reading buf(cur)

        if (k + 2 < nk) STAGE(ks0 + k + 2, cur);   // overwrite-safe; flies under MFMA

        #pragma unroll
        for (int i = 0; i < 4; ++i)
            #pragma unroll
            for (int j = 0; j < 4; ++j) {
                acc[i][j] = __builtin_amdgcn_mfma_f32_16x16x32_bf16(ah[i], bh[j], acc[i][j], 0, 0, 0);
                acc[i][j] = __builtin_amdgcn_mfma_f32_16x16x32_bf16(ah[i], bl[j], acc[i][j], 0, 0, 0);
                acc[i][j] = __builtin_amdgcn_mfma_f32_16x16x32_bf16(al[i], bh[j], acc[i][j], 0, 0, 0);
            }
        cur ^= 1;
    }

    // epilogue: C/D layout col=lane&15, row=(lane>>4)*4+reg  [m91-verified]
    int rbase = m0 + wm * 64 + (lane >> 4) * 4;
    int cbase = n0 + wn * 64 + (lane & 15);
    #pragma unroll
    for (int i = 0; i < 4; ++i) {
        int row0 = rbase + i * 16;
        #pragma unroll
        for (int j = 0; j < 4; ++j) {
            int col = cbase + j * 16;
            float* dst = parts + ((size_t)split * MA + row0) * H + col;
            #pragma unroll
            for (int r = 0; r < 4; ++r)
                dst[(size_t)r * H] = acc[i][j][r];
        }
    }
}

// ---------------------------------------------------------------------------
// 4) proto finalize: proto[i] = sum_split parts[sp][i] + bias   (i < 80)
// ---------------------------------------------------------------------------
__global__ __launch_bounds__(256) void protofin_kernel(
    const float* __restrict__ parts, const float* __restrict__ bias,
    float* __restrict__ proto)
{
    int i = blockIdx.x;
    int tid = threadIdx.x;
    #pragma unroll
    for (int q = 0; q < 3; ++q) {
        int d = tid + q * 256;
        float s = bias[d];
        #pragma unroll
        for (int sp = 0; sp < SPLITK; ++sp)
            s += parts[((size_t)sp * MA + i) * H + d];
        proto[(size_t)i * H + d] = s;
    }
}

// ---------------------------------------------------------------------------
// 5) distances + logits + pred; grid = BQ blocks (one per query)
// ---------------------------------------------------------------------------
__global__ __launch_bounds__(256) void dist_kernel(
    const float* __restrict__ parts, const float* __restrict__ bias,
    const float* __restrict__ proto, float* __restrict__ outp)
{
    int bid = blockIdx.x;            // e*TOTAL_Q + q
    int e = bid / TOTAL_Q;
    int tid = threadIdx.x;
    int m = NPROTO + bid;            // GEMM row of this query

    float qv[3];
    #pragma unroll
    for (int q = 0; q < 3; ++q) {
        int d = tid + q * 256;
        float s = bias[d];
        #pragma unroll
        for (int sp = 0; sp < SPLITK; ++sp)
            s += parts[((size_t)sp * MA + m) * H + d];
        qv[q] = s;
    }

    __shared__ float red[N_WAY][4];
    __shared__ float lvals[N_WAY];
    int wave = tid >> 6, lane = tid & 63;
    for (int n = 0; n < N_WAY; ++n) {
        const float* pr = proto + (size_t)(e * N_WAY + n) * H;
        float p = 0.f;
        #pragma unroll
        for (int q = 0; q < 3; ++q) {
            int d = tid + q * 256;
            float df = pr[d] - qv[q];
            p = fmaf(df, df, p);
        }
        #pragma unroll
        for (int off = 32; off > 0; off >>= 1)
            p += __shfl_down(p, off);
        if (lane == 0) red[n][wave] = p;
    }
    __syncthreads();
    if (tid < N_WAY) {
        float v = red[tid][0] + red[tid][1] + red[tid][2] + red[tid][3];
        lvals[tid] = -v;
        outp[(size_t)bid * (N_WAY + 1) + tid] = -v;
    }
    __syncthreads();
    if (tid == 0) {
        float mn = lvals[0];
        #pragma unroll
        for (int n = 1; n < N_WAY; ++n) mn = fminf(mn, lvals[n]);
        float last = mn - 1.0f;
        outp[(size_t)bid * (N_WAY + 1) + N_WAY] = last;
        float best = lvals[0];
        int bi = 0;
        for (int n = 1; n < N_WAY; ++n)
            if (lvals[n] > best) { best = lvals[n]; bi = n; }
        if (last > best) bi = N_WAY;   // parity with reference; cannot trigger
        outp[(size_t)BQ * (N_WAY + 1) + bid] = (float)bi;
    }
}

// ---------------------------------------------------------------------------
extern "C" void kernel_launch(void* const* d_in, const int* in_sizes, int n_in,
                              void* d_out, int out_size, void* d_ws, size_t ws_size,
                              hipStream_t stream)
{
    const float* all_support = (const float*)d_in[0];
    const float* support_emb = (const float*)d_in[1];
    const float* all_query   = (const float*)d_in[2];
    const float* query_emb   = (const float*)d_in[3];
    const float* fc_W        = (const float*)d_in[4];
    const float* fc_b        = (const float*)d_in[5];
    const int* s_eh     = (const int*)d_in[6];
    const int* s_eh_end = (const int*)d_in[7];
    const int* s_et     = (const int*)d_in[8];
    const int* s_et_end = (const int*)d_in[9];
    const int* q_eh     = (const int*)d_in[10];
    const int* q_eh_end = (const int*)d_in[11];
    const int* q_et     = (const int*)d_in[12];
    const int* q_et_end = (const int*)d_in[13];

    // workspace layout (fp32 first, then u16; all 16B-aligned)
    float* parts = (float*)d_ws;                           // SPLITK*MA*H
    float* proto = parts + (size_t)SPLITK * MA * H;        // NPROTO*H
    u16* Wh      = (u16*)(proto + (size_t)NPROTO * H);     // H*KP
    u16* Wl      = Wh + (size_t)H * KP;                    // H*KP
    u16* A_hi    = Wl + (size_t)H * KP;                    // MA*KP
    u16* A_lo    = A_hi + (size_t)MA * KP;                 // MA*KP
    u16* flatS_hi= A_lo + (size_t)MA * KP;                 // BS*KP
    u16* flatS_lo= flatS_hi + (size_t)BS * KP;             // BS*KP

    pre_kernel<<<MTOT + H, 256, 0, stream>>>(
        all_support, all_query, support_emb, query_emb, fc_W,
        s_eh, s_eh_end, s_et, s_et_end, q_eh, q_eh_end, q_et, q_et_end,
        flatS_hi, flatS_lo, A_hi, A_lo, Wh, Wl);

    avg_kernel<<<NPROTO, 256, 0, stream>>>(flatS_hi, flatS_lo, A_hi, A_lo);

    dim3 gg(MA / 128, H / 128, SPLITK);
    gemm_mfma<<<gg, 256, 0, stream>>>(A_hi, A_lo, Wh, Wl, parts);

    protofin_kernel<<<NPROTO, 256, 0, stream>>>(parts, fc_b, proto);

    dist_kernel<<<BQ, 256, 0, stream>>>(parts, fc_b, proto, (float*)d_out);
}

// Round 4
// 145.762 us; speedup vs baseline: 2.1928x; 1.0887x over previous
//
#include <hip/hip_runtime.h>

// Problem constants (fixed by setup_inputs in the reference)
#define H        768
#define LMAX     128
#define CONV_NUM 8
#define CONV_SIZE 96
#define T_CONV   673            // H - CONV_SIZE + 1
#define FC_IN    5384           // CONV_NUM * T_CONV
#define KP       5408           // K padded to multiple of 32 (169 steps)
#define KSTEPS   (KP / 32)      // 169
#define N_WAY    10
#define K_SHOT   5
#define TOTAL_Q  150
#define SPLITK   8
#define BS       400
#define BQ       1200
#define MTOT     1600           // BS + BQ
#define NPROTO   80             // BS / K_SHOT
#define MA       1280           // NPROTO + BQ  (GEMM rows; 5 tiles of 256)

using s16x8 = __attribute__((ext_vector_type(8))) short;   // 8 bf16 (4 VGPRs)
using f32x4 = __attribute__((ext_vector_type(4))) float;   // MFMA acc
typedef unsigned short u16;

__device__ __forceinline__ u16 f2bf(float x) {              // RNE float->bf16 bits
    unsigned u = __float_as_uint(x);
    u += 0x7FFFu + ((u >> 16) & 1u);
    return (u16)(u >> 16);
}
__device__ __forceinline__ float bf2f(u16 b) { return __uint_as_float(((unsigned)b) << 16); }

__device__ __forceinline__ void gl16(const u16* g, u16* l) { // global->LDS 16B async
    __builtin_amdgcn_global_load_lds(
        (const __attribute__((address_space(1))) unsigned int*)g,
        (__attribute__((address_space(3))) unsigned int*)l, 16, 0, 0);
}

// ---------------------------------------------------------------------------
// 1) fused: [blocks 0..MTOT): entity-gather + conv(96) + ReLU + concat +
//    avgpool(2) -> bf16 hi/lo rows.  Support rows -> flatS, query rows -> A.
//    [blocks MTOT..MTOT+H): split fc_W row -> bf16 hi/lo.
// ---------------------------------------------------------------------------
#define HT_STRIDE 676
__global__ __launch_bounds__(256) void pre_kernel(
    const float* __restrict__ all_support, const float* __restrict__ all_query,
    const float* __restrict__ support_emb, const float* __restrict__ query_emb,
    const float* __restrict__ fc_W,
    const int* __restrict__ s_eh, const int* __restrict__ s_eh_end,
    const int* __restrict__ s_et, const int* __restrict__ s_et_end,
    const int* __restrict__ q_eh, const int* __restrict__ q_eh_end,
    const int* __restrict__ q_et, const int* __restrict__ q_et_end,
    u16* __restrict__ flatS_hi, u16* __restrict__ flatS_lo,
    u16* __restrict__ A_hi, u16* __restrict__ A_lo,
    u16* __restrict__ Wh, u16* __restrict__ Wl)
{
    int bid = blockIdx.x;
    int tid = threadIdx.x;

    if (bid >= MTOT) {                      // ---- W-split path ----
        int r = bid - MTOT;
        for (int j = tid; j < KP; j += 256) {
            float v = (j < FC_IN) ? fc_W[(size_t)r * FC_IN + j] : 0.f;
            u16 hb = f2bf(v);
            Wh[(size_t)r * KP + j] = hb;
            Wl[(size_t)r * KP + j] = f2bf(v - bf2f(hb));
        }
        return;
    }

    // ---- conv path ----
    __shared__ float xs[800];
    __shared__ float filt[16 * 96];         // [0..767]=head ent, [768..1535]=tail ent
    __shared__ float ht[16 * HT_STRIDE];

    int b = bid;
    const float* src;
    int sh, eh, st, et;
    if (b < BS) {
        src = all_support + (size_t)b * LMAX * H;
        sh = s_eh[b]; eh = s_eh_end[b]; st = s_et[b]; et = s_et_end[b];
    } else {
        int m = b - BS;
        src = all_query + (size_t)m * LMAX * H;
        sh = q_eh[m]; eh = q_eh_end[m]; st = q_et[m]; et = q_et_end[m];
    }
    if (eh < sh + 1) eh = sh + 1;
    if (et < st + 1) et = st + 1;

    {   // entity gather -> filt (head then tail), coalesced row reads
        float a0 = 0.f, a1 = 0.f, a2 = 0.f;
        for (int r = sh; r < eh; ++r) {
            const float* row = src + (size_t)r * H;
            a0 += row[tid]; a1 += row[tid + 256]; a2 += row[tid + 512];
        }
        float rc = 1.0f / (float)(eh - sh);
        filt[tid] = a0 * rc; filt[tid + 256] = a1 * rc; filt[tid + 512] = a2 * rc;
        a0 = a1 = a2 = 0.f;
        for (int r = st; r < et; ++r) {
            const float* row = src + (size_t)r * H;
            a0 += row[tid]; a1 += row[tid + 256]; a2 += row[tid + 512];
        }
        rc = 1.0f / (float)(et - st);
        filt[768 + tid] = a0 * rc; filt[1024 + tid] = a1 * rc; filt[1280 + tid] = a2 * rc;
    }
    const float* xsrc = (b < BS) ? (support_emb + (size_t)b * H)
                                 : (query_emb + (size_t)(b - BS) * H);
    if (tid < 192)
        *(float4*)&xs[tid * 4] = *(const float4*)&xsrc[tid * 4];
    if (tid >= 192 && tid < 200) {
        int o = 768 + (tid - 192) * 4;
        xs[o] = 0.f; xs[o + 1] = 0.f; xs[o + 2] = 0.f; xs[o + 3] = 0.f;
    }
    __syncthreads();

    int wave = tid >> 6, lane = tid & 63;
    int p0 = lane * 11;
    #pragma unroll 1
    for (int cc = 0; cc < 4; ++cc) {
        int c = wave * 4 + cc;
        const float* fp = &filt[c * 96];
        float w[11], acc[11];
        #pragma unroll
        for (int i = 0; i < 11; ++i) { w[i] = xs[p0 + i]; acc[i] = 0.f; }
        #pragma unroll
        for (int k = 0; k < 96; ++k) {
            float f = fp[k];
            #pragma unroll
            for (int i = 0; i < 11; ++i)
                acc[i] = fmaf(f, w[(k + i) % 11], acc[i]);
            w[k % 11] = xs[p0 + k + 11];
        }
        #pragma unroll
        for (int i = 0; i < 11; ++i) {
            int p = p0 + i;
            if (p < T_CONV) ht[c * HT_STRIDE + p] = fmaxf(acc[i], 0.f);
        }
    }
    __syncthreads();

    u16* oh; u16* ol;
    if (b < BS) { oh = flatS_hi + (size_t)b * KP;             ol = flatS_lo + (size_t)b * KP; }
    else        { oh = A_hi + (size_t)(NPROTO + b - BS) * KP; ol = A_lo + (size_t)(NPROTO + b - BS) * KP; }
    for (int f = 0; f < CONV_NUM; ++f) {
        for (int j = tid; j < T_CONV; j += 256) {
            int i0 = 2 * j, i1 = 2 * j + 1;
            float v0 = (i0 < T_CONV) ? ht[f * HT_STRIDE + i0]
                                     : ht[(8 + f) * HT_STRIDE + (i0 - T_CONV)];
            float v1 = (i1 < T_CONV) ? ht[f * HT_STRIDE + i1]
                                     : ht[(8 + f) * HT_STRIDE + (i1 - T_CONV)];
            float val = 0.5f * (v0 + v1);
            u16 hb = f2bf(val);
            oh[f * T_CONV + j] = hb;
            ol[f * T_CONV + j] = f2bf(val - bf2f(hb));
        }
    }
    for (int j = FC_IN + tid; j < KP; j += 256) { oh[j] = 0; ol[j] = 0; }
}

// ---------------------------------------------------------------------------
// 2) support pre-average (fc linear => mean-before == mean-after).
//    Vectorized: 16B s16x8 loads/stores (G13).
// ---------------------------------------------------------------------------
__global__ __launch_bounds__(256) void avg_kernel(
    const u16* __restrict__ flatS_hi, const u16* __restrict__ flatS_lo,
    u16* __restrict__ A_hi, u16* __restrict__ A_lo)
{
    int i = blockIdx.x;                   // proto row 0..79
    size_t base = (size_t)i * K_SHOT * KP;
    for (int t = threadIdx.x; t < KP / 8; t += 256) {
        int j = t * 8;
        float s[8] = {0.f, 0.f, 0.f, 0.f, 0.f, 0.f, 0.f, 0.f};
        #pragma unroll
        for (int k = 0; k < K_SHOT; ++k) {
            s16x8 vh = *(const s16x8*)(flatS_hi + base + (size_t)k * KP + j);
            s16x8 vl = *(const s16x8*)(flatS_lo + base + (size_t)k * KP + j);
            #pragma unroll
            for (int u = 0; u < 8; ++u)
                s[u] += bf2f((u16)vh[u]) + bf2f((u16)vl[u]);
        }
        s16x8 oh, ol;
        #pragma unroll
        for (int u = 0; u < 8; ++u) {
            float v = s[u] * (1.0f / K_SHOT);
            u16 hb = f2bf(v);
            oh[u] = (short)hb;
            ol[u] = (short)f2bf(v - bf2f(hb));
        }
        *(s16x8*)(A_hi + (size_t)i * KP + j) = oh;
        *(s16x8*)(A_lo + (size_t)i * KP + j) = ol;
    }
}

// ---------------------------------------------------------------------------
// 3) split-bf16 MFMA GEMM: C = Ahi*Whi + Ahi*Wlo + Alo*Whi  (fp32 acc)
//    256x128 tile, BK=32, 512 thr / 8 waves x (64x64). Frag-native LDS:
//    A-seg [frag(16)][kg(4)][row(16)][8], B-seg [frag(8)][kg(4)][row(16)][8].
//    2-ahead counted vmcnt(6). Grid 240 = 5m x 6n x 8sk, XCD-chunked swizzle
//    (each XCD owns one full split slice -> B/A panels L2-resident).
// ---------------------------------------------------------------------------
#define ASEG 8192   // 256*32 u16 (16KB)
#define BSEG 4096   // 128*32 u16 (8KB)
#define BUFU (2 * ASEG + 2 * BSEG)   // 24576 u16 = 48KB per buffer

#define STAGE(ks, buf) do {                                     \
    int kb_ = (ks) * 32;                                        \
    u16* L_ = &lds[buf][0];                                     \
    gl16(Ah_g + aoff0 + kb_, L_ + cA0 * 8);                     \
    gl16(Ah_g + aoff1 + kb_, L_ + cA1 * 8);                     \
    gl16(Al_g + aoff0 + kb_, L_ + ASEG + cA0 * 8);              \
    gl16(Al_g + aoff1 + kb_, L_ + ASEG + cA1 * 8);              \
    gl16(Bh_g + boff  + kb_, L_ + 2 * ASEG + cB * 8);           \
    gl16(Bl_g + boff  + kb_, L_ + 2 * ASEG + BSEG + cB * 8);    \
} while (0)

__global__ __launch_bounds__(512, 2) void gemm_mfma(
    const u16* __restrict__ Ah_g, const u16* __restrict__ Al_g,
    const u16* __restrict__ Bh_g, const u16* __restrict__ Bl_g,
    float* __restrict__ parts)
{
    __shared__ u16 lds[2][BUFU];   // 96 KB -> 1 block/CU

    int tid = threadIdx.x;
    // XCD-chunked bijective swizzle: 240 blocks = 8 XCDs x 30
    int wg = (blockIdx.x & 7) * 30 + (blockIdx.x >> 3);
    int sk = wg / 30;
    int rem = wg % 30;
    int n0 = (rem / 5) * 128;
    int m0 = (rem % 5) * 256;

    int ks0 = (KSTEPS * sk) / SPLITK;
    int nk = (KSTEPS * (sk + 1)) / SPLITK - ks0;   // 21 or 22

    // A chunks (1024 of 16B per seg): c: frag=c>>6, kg=(c>>4)&3, row=c&15
    int cA0 = tid, cA1 = tid + 512;
    int cB = tid;                                  // B chunks (512 per seg)
    size_t aoff0 = (size_t)(m0 + (cA0 >> 6) * 16 + (cA0 & 15)) * KP + ((cA0 >> 4) & 3) * 8;
    size_t aoff1 = (size_t)(m0 + (cA1 >> 6) * 16 + (cA1 & 15)) * KP + ((cA1 >> 4) & 3) * 8;
    size_t boff  = (size_t)(n0 + (cB >> 6) * 16 + (cB & 15)) * KP + ((cB >> 4) & 3) * 8;

    int w = tid >> 6, lane = tid & 63;
    int wm = w >> 1, wn = w & 1;                   // 4x2 waves of 64x64
    int lfr = ((lane >> 4) * 16 + (lane & 15)) * 8;

    f32x4 acc[4][4];
    #pragma unroll
    for (int i = 0; i < 4; ++i)
        #pragma unroll
        for (int j = 0; j < 4; ++j) acc[i][j] = (f32x4){0.f, 0.f, 0.f, 0.f};

    STAGE(ks0, 0);          // 6 loads/thread in flight
    STAGE(ks0 + 1, 1);      // 12 in flight (nk >= 21 always)

    int cur = 0;
    for (int k = 0; k < nk; ++k) {
        if (k + 1 < nk) asm volatile("s_waitcnt vmcnt(6)" ::: "memory");
        else            asm volatile("s_waitcnt vmcnt(0)" ::: "memory");
        __builtin_amdgcn_s_barrier();

        const u16* L = &lds[cur][0];
        s16x8 ah[4], al[4], bh[4], bl[4];
        #pragma unroll
        for (int f = 0; f < 4; ++f) {
            ah[f] = *(const s16x8*)(L + (wm * 4 + f) * 512 + lfr);
            al[f] = *(const s16x8*)(L + ASEG + (wm * 4 + f) * 512 + lfr);
            bh[f] = *(const s16x8*)(L + 2 * ASEG + (wn * 4 + f) * 512 + lfr);
            bl[f] = *(const s16x8*)(L + 2 * ASEG + BSEG + (wn * 4 + f) * 512 + lfr);
        }
        asm volatile("s_waitcnt lgkmcnt(0)" ::: "memory");
        __builtin_amdgcn_s_barrier();       // all waves done reading buf(cur)

        if (k + 2 < nk) STAGE(ks0 + k + 2, cur);   // flies under MFMA

        #pragma unroll
        for (int i = 0; i < 4; ++i)
            #pragma unroll
            for (int j = 0; j < 4; ++j) {
                acc[i][j] = __builtin_amdgcn_mfma_f32_16x16x32_bf16(ah[i], bh[j], acc[i][j], 0, 0, 0);
                acc[i][j] = __builtin_amdgcn_mfma_f32_16x16x32_bf16(ah[i], bl[j], acc[i][j], 0, 0, 0);
                acc[i][j] = __builtin_amdgcn_mfma_f32_16x16x32_bf16(al[i], bh[j], acc[i][j], 0, 0, 0);
            }
        cur ^= 1;
    }

    // epilogue: C/D layout col=lane&15, row=(lane>>4)*4+reg  [m91-verified]
    int rbase = m0 + wm * 64 + (lane >> 4) * 4;
    int cbase = n0 + wn * 64 + (lane & 15);
    #pragma unroll
    for (int i = 0; i < 4; ++i) {
        int row0 = rbase + i * 16;
        #pragma unroll
        for (int j = 0; j < 4; ++j) {
            int col = cbase + j * 16;
            float* dst = parts + ((size_t)sk * MA + row0) * H + col;
            #pragma unroll
            for (int r = 0; r < 4; ++r)
                dst[(size_t)r * H] = acc[i][j][r];
        }
    }
}

// ---------------------------------------------------------------------------
// 4) proto finalize: proto[i] = sum_split parts[sp][i] + bias   (i < 80)
// ---------------------------------------------------------------------------
__global__ __launch_bounds__(256) void protofin_kernel(
    const float* __restrict__ parts, const float* __restrict__ bias,
    float* __restrict__ proto)
{
    int i = blockIdx.x;
    int tid = threadIdx.x;
    #pragma unroll
    for (int q = 0; q < 3; ++q) {
        int d = tid + q * 256;
        float s = bias[d];
        #pragma unroll
        for (int sp = 0; sp < SPLITK; ++sp)
            s += parts[((size_t)sp * MA + i) * H + d];
        proto[(size_t)i * H + d] = s;
    }
}

// ---------------------------------------------------------------------------
// 5) distances + logits + pred; grid = BQ blocks (one per query)
// ---------------------------------------------------------------------------
__global__ __launch_bounds__(256) void dist_kernel(
    const float* __restrict__ parts, const float* __restrict__ bias,
    const float* __restrict__ proto, float* __restrict__ outp)
{
    int bid = blockIdx.x;            // e*TOTAL_Q + q
    int e = bid / TOTAL_Q;
    int tid = threadIdx.x;
    int m = NPROTO + bid;            // GEMM row of this query

    float qv[3];
    #pragma unroll
    for (int q = 0; q < 3; ++q) {
        int d = tid + q * 256;
        float s = bias[d];
        #pragma unroll
        for (int sp = 0; sp < SPLITK; ++sp)
            s += parts[((size_t)sp * MA + m) * H + d];
        qv[q] = s;
    }

    __shared__ float red[N_WAY][4];
    __shared__ float lvals[N_WAY];
    int wave = tid >> 6, lane = tid & 63;
    for (int n = 0; n < N_WAY; ++n) {
        const float* pr = proto + (size_t)(e * N_WAY + n) * H;
        float p = 0.f;
        #pragma unroll
        for (int q = 0; q < 3; ++q) {
            int d = tid + q * 256;
            float df = pr[d] - qv[q];
            p = fmaf(df, df, p);
        }
        #pragma unroll
        for (int off = 32; off > 0; off >>= 1)
            p += __shfl_down(p, off);
        if (lane == 0) red[n][wave] = p;
    }
    __syncthreads();
    if (tid < N_WAY) {
        float v = red[tid][0] + red[tid][1] + red[tid][2] + red[tid][3];
        lvals[tid] = -v;
        outp[(size_t)bid * (N_WAY + 1) + tid] = -v;
    }
    __syncthreads();
    if (tid == 0) {
        float mn = lvals[0];
        #pragma unroll
        for (int n = 1; n < N_WAY; ++n) mn = fminf(mn, lvals[n]);
        float last = mn - 1.0f;
        outp[(size_t)bid * (N_WAY + 1) + N_WAY] = last;
        float best = lvals[0];
        int bi = 0;
        for (int n = 1; n < N_WAY; ++n)
            if (lvals[n] > best) { best = lvals[n]; bi = n; }
        if (last > best) bi = N_WAY;   // parity with reference; cannot trigger
        outp[(size_t)BQ * (N_WAY + 1) + bid] = (float)bi;
    }
}

// ---------------------------------------------------------------------------
extern "C" void kernel_launch(void* const* d_in, const int* in_sizes, int n_in,
                              void* d_out, int out_size, void* d_ws, size_t ws_size,
                              hipStream_t stream)
{
    const float* all_support = (const float*)d_in[0];
    const float* support_emb = (const float*)d_in[1];
    const float* all_query   = (const float*)d_in[2];
    const float* query_emb   = (const float*)d_in[3];
    const float* fc_W        = (const float*)d_in[4];
    const float* fc_b        = (const float*)d_in[5];
    const int* s_eh     = (const int*)d_in[6];
    const int* s_eh_end = (const int*)d_in[7];
    const int* s_et     = (const int*)d_in[8];
    const int* s_et_end = (const int*)d_in[9];
    const int* q_eh     = (const int*)d_in[10];
    const int* q_eh_end = (const int*)d_in[11];
    const int* q_et     = (const int*)d_in[12];
    const int* q_et_end = (const int*)d_in[13];

    // workspace layout (fp32 first, then u16; all 16B-aligned)
    float* parts = (float*)d_ws;                           // SPLITK*MA*H
    float* proto = parts + (size_t)SPLITK * MA * H;        // NPROTO*H
    u16* Wh      = (u16*)(proto + (size_t)NPROTO * H);     // H*KP
    u16* Wl      = Wh + (size_t)H * KP;                    // H*KP
    u16* A_hi    = Wl + (size_t)H * KP;                    // MA*KP
    u16* A_lo    = A_hi + (size_t)MA * KP;                 // MA*KP
    u16* flatS_hi= A_lo + (size_t)MA * KP;                 // BS*KP
    u16* flatS_lo= flatS_hi + (size_t)BS * KP;             // BS*KP

    pre_kernel<<<MTOT + H, 256, 0, stream>>>(
        all_support, all_query, support_emb, query_emb, fc_W,
        s_eh, s_eh_end, s_et, s_et_end, q_eh, q_eh_end, q_et, q_et_end,
        flatS_hi, flatS_lo, A_hi, A_lo, Wh, Wl);

    avg_kernel<<<NPROTO, 256, 0, stream>>>(flatS_hi, flatS_lo, A_hi, A_lo);

    gemm_mfma<<<240, 512, 0, stream>>>(A_hi, A_lo, Wh, Wl, parts);

    protofin_kernel<<<NPROTO, 256, 0, stream>>>(parts, fc_b, proto);

    dist_kernel<<<BQ, 256, 0, stream>>>(parts, fc_b, proto, (float*)d_out);
}

// Round 5
// 118.169 us; speedup vs baseline: 2.7048x; 1.2335x over previous
//
#include <hip/hip_runtime.h>

// Problem constants (fixed by setup_inputs in the reference)
#define H        768
#define LMAX     128
#define CONV_NUM 8
#define CONV_SIZE 96
#define T_CONV   673            // H - CONV_SIZE + 1
#define FC_IN    5384           // CONV_NUM * T_CONV
#define KP       5408           // K padded to multiple of 32 (169 steps)
#define KSTEPS   (KP / 32)      // 169
#define N_WAY    10
#define K_SHOT   5
#define TOTAL_Q  150
#define SPLITK   8
#define BS       400
#define BQ       1200
#define MTOT     1600           // BS + BQ
#define NPROTO   80             // BS / K_SHOT
#define MA       1280           // NPROTO + BQ  (GEMM rows; 5 tiles of 256)

using s16x8 = __attribute__((ext_vector_type(8))) short;   // 8 bf16 (4 VGPRs)
using f32x4 = __attribute__((ext_vector_type(4))) float;   // MFMA acc
typedef unsigned short u16;

__device__ __forceinline__ u16 f2bf(float x) {              // RNE float->bf16 bits
    unsigned u = __float_as_uint(x);
    u += 0x7FFFu + ((u >> 16) & 1u);
    return (u16)(u >> 16);
}
__device__ __forceinline__ float bf2f(u16 b) { return __uint_as_float(((unsigned)b) << 16); }

__device__ __forceinline__ void gl16(const u16* g, u16* l) { // global->LDS 16B async
    __builtin_amdgcn_global_load_lds(
        (const __attribute__((address_space(1))) unsigned int*)g,
        (__attribute__((address_space(3))) unsigned int*)l, 16, 0, 0);
}

// ---------------------------------------------------------------------------
// 1) fused: [blocks 0..MTOT): entity-gather + conv(96) + ReLU + concat +
//    avgpool(2) -> bf16 rows.  Support rows -> flatS, query rows -> A[80..).
//    [blocks MTOT..MTOT+H): fc_W row -> bf16.
// ---------------------------------------------------------------------------
#define HT_STRIDE 676
__global__ __launch_bounds__(256) void pre_kernel(
    const float* __restrict__ all_support, const float* __restrict__ all_query,
    const float* __restrict__ support_emb, const float* __restrict__ query_emb,
    const float* __restrict__ fc_W,
    const int* __restrict__ s_eh, const int* __restrict__ s_eh_end,
    const int* __restrict__ s_et, const int* __restrict__ s_et_end,
    const int* __restrict__ q_eh, const int* __restrict__ q_eh_end,
    const int* __restrict__ q_et, const int* __restrict__ q_et_end,
    u16* __restrict__ flatS, u16* __restrict__ A_bf,
    u16* __restrict__ Wh)
{
    int bid = blockIdx.x;
    int tid = threadIdx.x;

    if (bid >= MTOT) {                      // ---- W-split path ----
        int r = bid - MTOT;
        for (int j = tid; j < KP; j += 256) {
            float v = (j < FC_IN) ? fc_W[(size_t)r * FC_IN + j] : 0.f;
            Wh[(size_t)r * KP + j] = f2bf(v);
        }
        return;
    }

    // ---- conv path ----
    __shared__ float xs[800];
    __shared__ float filt[16 * 96];         // [0..767]=head ent, [768..1535]=tail ent
    __shared__ float ht[16 * HT_STRIDE];

    int b = bid;
    const float* src;
    int sh, eh, st, et;
    if (b < BS) {
        src = all_support + (size_t)b * LMAX * H;
        sh = s_eh[b]; eh = s_eh_end[b]; st = s_et[b]; et = s_et_end[b];
    } else {
        int m = b - BS;
        src = all_query + (size_t)m * LMAX * H;
        sh = q_eh[m]; eh = q_eh_end[m]; st = q_et[m]; et = q_et_end[m];
    }
    if (eh < sh + 1) eh = sh + 1;
    if (et < st + 1) et = st + 1;

    {   // entity gather -> filt (head then tail), coalesced row reads
        float a0 = 0.f, a1 = 0.f, a2 = 0.f;
        for (int r = sh; r < eh; ++r) {
            const float* row = src + (size_t)r * H;
            a0 += row[tid]; a1 += row[tid + 256]; a2 += row[tid + 512];
        }
        float rc = 1.0f / (float)(eh - sh);
        filt[tid] = a0 * rc; filt[tid + 256] = a1 * rc; filt[tid + 512] = a2 * rc;
        a0 = a1 = a2 = 0.f;
        for (int r = st; r < et; ++r) {
            const float* row = src + (size_t)r * H;
            a0 += row[tid]; a1 += row[tid + 256]; a2 += row[tid + 512];
        }
        rc = 1.0f / (float)(et - st);
        filt[768 + tid] = a0 * rc; filt[1024 + tid] = a1 * rc; filt[1280 + tid] = a2 * rc;
    }
    const float* xsrc = (b < BS) ? (support_emb + (size_t)b * H)
                                 : (query_emb + (size_t)(b - BS) * H);
    if (tid < 192)
        *(float4*)&xs[tid * 4] = *(const float4*)&xsrc[tid * 4];
    if (tid >= 192 && tid < 200) {
        int o = 768 + (tid - 192) * 4;
        xs[o] = 0.f; xs[o + 1] = 0.f; xs[o + 2] = 0.f; xs[o + 3] = 0.f;
    }
    __syncthreads();

    int wave = tid >> 6, lane = tid & 63;
    int p0 = lane * 11;
    #pragma unroll 1
    for (int cc = 0; cc < 4; ++cc) {
        int c = wave * 4 + cc;
        const float* fp = &filt[c * 96];
        float w[11], acc[11];
        #pragma unroll
        for (int i = 0; i < 11; ++i) { w[i] = xs[p0 + i]; acc[i] = 0.f; }
        #pragma unroll
        for (int k = 0; k < 96; ++k) {
            float f = fp[k];
            #pragma unroll
            for (int i = 0; i < 11; ++i)
                acc[i] = fmaf(f, w[(k + i) % 11], acc[i]);
            w[k % 11] = xs[p0 + k + 11];
        }
        #pragma unroll
        for (int i = 0; i < 11; ++i) {
            int p = p0 + i;
            if (p < T_CONV) ht[c * HT_STRIDE + p] = fmaxf(acc[i], 0.f);
        }
    }
    __syncthreads();

    u16* oh = (b < BS) ? (flatS + (size_t)b * KP)
                       : (A_bf + (size_t)(NPROTO + b - BS) * KP);
    for (int f = 0; f < CONV_NUM; ++f) {
        for (int j = tid; j < T_CONV; j += 256) {
            int i0 = 2 * j, i1 = 2 * j + 1;
            float v0 = (i0 < T_CONV) ? ht[f * HT_STRIDE + i0]
                                     : ht[(8 + f) * HT_STRIDE + (i0 - T_CONV)];
            float v1 = (i1 < T_CONV) ? ht[f * HT_STRIDE + i1]
                                     : ht[(8 + f) * HT_STRIDE + (i1 - T_CONV)];
            oh[f * T_CONV + j] = f2bf(0.5f * (v0 + v1));
        }
    }
    for (int j = FC_IN + tid; j < KP; j += 256) oh[j] = 0;
}

// ---------------------------------------------------------------------------
// 2) support pre-average (fc linear => mean-before == mean-after), 16B vec.
// ---------------------------------------------------------------------------
__global__ __launch_bounds__(256) void avg_kernel(
    const u16* __restrict__ flatS, u16* __restrict__ A_bf)
{
    int i = blockIdx.x;                   // proto row 0..79
    size_t base = (size_t)i * K_SHOT * KP;
    for (int t = threadIdx.x; t < KP / 8; t += 256) {
        int j = t * 8;
        float s[8] = {0.f, 0.f, 0.f, 0.f, 0.f, 0.f, 0.f, 0.f};
        #pragma unroll
        for (int k = 0; k < K_SHOT; ++k) {
            s16x8 vh = *(const s16x8*)(flatS + base + (size_t)k * KP + j);
            #pragma unroll
            for (int u = 0; u < 8; ++u)
                s[u] += bf2f((u16)vh[u]);
        }
        s16x8 oh;
        #pragma unroll
        for (int u = 0; u < 8; ++u)
            oh[u] = (short)f2bf(s[u] * (1.0f / K_SHOT));
        *(s16x8*)(A_bf + (size_t)i * KP + j) = oh;
    }
}

// ---------------------------------------------------------------------------
// 3) bf16 MFMA GEMM: C = A * W^T  (fp32 acc; bf16 rounding error << threshold)
//    256x128 tile, BK=32, 512 thr / 8 waves x (64x64). Frag-native LDS:
//    A-seg [frag(16)][kg(4)][row(16)][8], B-seg [frag(8)][kg(4)][row(16)][8].
//    2-ahead counted vmcnt(3). Grid 240 = 5m x 6n x 8sk, XCD-chunked swizzle.
// ---------------------------------------------------------------------------
#define ASEG 8192   // 256*32 u16 (16KB)
#define BSEG 4096   // 128*32 u16 (8KB)
#define BUFU (ASEG + BSEG)   // 12288 u16 = 24KB per buffer

#define STAGE(ks, buf) do {                                     \
    int kb_ = (ks) * 32;                                        \
    u16* L_ = &lds[buf][0];                                     \
    gl16(Ah_g + aoff0 + kb_, L_ + cA0 * 8);                     \
    gl16(Ah_g + aoff1 + kb_, L_ + cA1 * 8);                     \
    gl16(Bh_g + boff  + kb_, L_ + ASEG + cB * 8);               \
} while (0)

__global__ __launch_bounds__(512, 2) void gemm_mfma(
    const u16* __restrict__ Ah_g, const u16* __restrict__ Bh_g,
    float* __restrict__ parts)
{
    __shared__ u16 lds[2][BUFU];   // 48 KB

    int tid = threadIdx.x;
    // XCD-chunked bijective swizzle: 240 blocks = 8 XCDs x 30
    int wg = (blockIdx.x & 7) * 30 + (blockIdx.x >> 3);
    int sk = wg / 30;
    int rem = wg % 30;
    int n0 = (rem / 5) * 128;
    int m0 = (rem % 5) * 256;

    int ks0 = (KSTEPS * sk) / SPLITK;
    int nk = (KSTEPS * (sk + 1)) / SPLITK - ks0;   // 21 or 22

    // A chunks (1024 of 16B): c: frag=c>>6, kg=(c>>4)&3, row=c&15
    int cA0 = tid, cA1 = tid + 512;
    int cB = tid;                                  // B chunks (512)
    size_t aoff0 = (size_t)(m0 + (cA0 >> 6) * 16 + (cA0 & 15)) * KP + ((cA0 >> 4) & 3) * 8;
    size_t aoff1 = (size_t)(m0 + (cA1 >> 6) * 16 + (cA1 & 15)) * KP + ((cA1 >> 4) & 3) * 8;
    size_t boff  = (size_t)(n0 + (cB >> 6) * 16 + (cB & 15)) * KP + ((cB >> 4) & 3) * 8;

    int w = tid >> 6, lane = tid & 63;
    int wm = w >> 1, wn = w & 1;                   // 4x2 waves of 64x64
    int lfr = ((lane >> 4) * 16 + (lane & 15)) * 8;

    f32x4 acc[4][4];
    #pragma unroll
    for (int i = 0; i < 4; ++i)
        #pragma unroll
        for (int j = 0; j < 4; ++j) acc[i][j] = (f32x4){0.f, 0.f, 0.f, 0.f};

    STAGE(ks0, 0);          // 3 loads/thread in flight
    STAGE(ks0 + 1, 1);      // 6 in flight (nk >= 21 always)

    int cur = 0;
    for (int k = 0; k < nk; ++k) {
        if (k + 1 < nk) asm volatile("s_waitcnt vmcnt(3)" ::: "memory");
        else            asm volatile("s_waitcnt vmcnt(0)" ::: "memory");
        __builtin_amdgcn_s_barrier();

        const u16* L = &lds[cur][0];
        s16x8 ah[4], bh[4];
        #pragma unroll
        for (int f = 0; f < 4; ++f) {
            ah[f] = *(const s16x8*)(L + (wm * 4 + f) * 512 + lfr);
            bh[f] = *(const s16x8*)(L + ASEG + (wn * 4 + f) * 512 + lfr);
        }
        asm volatile("s_waitcnt lgkmcnt(0)" ::: "memory");
        __builtin_amdgcn_s_barrier();       // all waves done reading buf(cur)

        if (k + 2 < nk) STAGE(ks0 + k + 2, cur);   // flies under MFMA

        #pragma unroll
        for (int i = 0; i < 4; ++i)
            #pragma unroll
            for (int j = 0; j < 4; ++j)
                acc[i][j] = __builtin_amdgcn_mfma_f32_16x16x32_bf16(ah[i], bh[j], acc[i][j], 0, 0, 0);
        cur ^= 1;
    }

    // epilogue: C/D layout col=lane&15, row=(lane>>4)*4+reg  [m91-verified]
    int rbase = m0 + wm * 64 + (lane >> 4) * 4;
    int cbase = n0 + wn * 64 + (lane & 15);
    #pragma unroll
    for (int i = 0; i < 4; ++i) {
        int row0 = rbase + i * 16;
        #pragma unroll
        for (int j = 0; j < 4; ++j) {
            int col = cbase + j * 16;
            float* dst = parts + ((size_t)sk * MA + row0) * H + col;
            #pragma unroll
            for (int r = 0; r < 4; ++r)
                dst[(size_t)r * H] = acc[i][j][r];
        }
    }
}

// ---------------------------------------------------------------------------
// 4) proto finalize: proto[i] = sum_split parts[sp][i] + bias   (i < 80)
// ---------------------------------------------------------------------------
__global__ __launch_bounds__(256) void protofin_kernel(
    const float* __restrict__ parts, const float* __restrict__ bias,
    float* __restrict__ proto)
{
    int i = blockIdx.x;
    int tid = threadIdx.x;
    #pragma unroll
    for (int q = 0; q < 3; ++q) {
        int d = tid + q * 256;
        float s = bias[d];
        #pragma unroll
        for (int sp = 0; sp < SPLITK; ++sp)
            s += parts[((size_t)sp * MA + i) * H + d];
        proto[(size_t)i * H + d] = s;
    }
}

// ---------------------------------------------------------------------------
// 5) distances + logits + pred; grid = BQ blocks (one per query)
// ---------------------------------------------------------------------------
__global__ __launch_bounds__(256) void dist_kernel(
    const float* __restrict__ parts, const float* __restrict__ bias,
    const float* __restrict__ proto, float* __restrict__ outp)
{
    int bid = blockIdx.x;            // e*TOTAL_Q + q
    int e = bid / TOTAL_Q;
    int tid = threadIdx.x;
    int m = NPROTO + bid;            // GEMM row of this query

    float qv[3];
    #pragma unroll
    for (int q = 0; q < 3; ++q) {
        int d = tid + q * 256;
        float s = bias[d];
        #pragma unroll
        for (int sp = 0; sp < SPLITK; ++sp)
            s += parts[((size_t)sp * MA + m) * H + d];
        qv[q] = s;
    }

    __shared__ float red[N_WAY][4];
    __shared__ float lvals[N_WAY];
    int wave = tid >> 6, lane = tid & 63;
    for (int n = 0; n < N_WAY; ++n) {
        const float* pr = proto + (size_t)(e * N_WAY + n) * H;
        float p = 0.f;
        #pragma unroll
        for (int q = 0; q < 3; ++q) {
            int d = tid + q * 256;
            float df = pr[d] - qv[q];
            p = fmaf(df, df, p);
        }
        #pragma unroll
        for (int off = 32; off > 0; off >>= 1)
            p += __shfl_down(p, off);
        if (lane == 0) red[n][wave] = p;
    }
    __syncthreads();
    if (tid < N_WAY) {
        float v = red[tid][0] + red[tid][1] + red[tid][2] + red[tid][3];
        lvals[tid] = -v;
        outp[(size_t)bid * (N_WAY + 1) + tid] = -v;
    }
    __syncthreads();
    if (tid == 0) {
        float mn = lvals[0];
        #pragma unroll
        for (int n = 1; n < N_WAY; ++n) mn = fminf(mn, lvals[n]);
        float last = mn - 1.0f;
        outp[(size_t)bid * (N_WAY + 1) + N_WAY] = last;
        float best = lvals[0];
        int bi = 0;
        for (int n = 1; n < N_WAY; ++n)
            if (lvals[n] > best) { best = lvals[n]; bi = n; }
        if (last > best) bi = N_WAY;   // parity with reference; cannot trigger
        outp[(size_t)BQ * (N_WAY + 1) + bid] = (float)bi;
    }
}

// ---------------------------------------------------------------------------
extern "C" void kernel_launch(void* const* d_in, const int* in_sizes, int n_in,
                              void* d_out, int out_size, void* d_ws, size_t ws_size,
                              hipStream_t stream)
{
    const float* all_support = (const float*)d_in[0];
    const float* support_emb = (const float*)d_in[1];
    const float* all_query   = (const float*)d_in[2];
    const float* query_emb   = (const float*)d_in[3];
    const float* fc_W        = (const float*)d_in[4];
    const float* fc_b        = (const float*)d_in[5];
    const int* s_eh     = (const int*)d_in[6];
    const int* s_eh_end = (const int*)d_in[7];
    const int* s_et     = (const int*)d_in[8];
    const int* s_et_end = (const int*)d_in[9];
    const int* q_eh     = (const int*)d_in[10];
    const int* q_eh_end = (const int*)d_in[11];
    const int* q_et     = (const int*)d_in[12];
    const int* q_et_end = (const int*)d_in[13];

    // workspace layout (fp32 first, then u16; all 16B-aligned)
    float* parts = (float*)d_ws;                           // SPLITK*MA*H
    float* proto = parts + (size_t)SPLITK * MA * H;        // NPROTO*H
    u16* Wh      = (u16*)(proto + (size_t)NPROTO * H);     // H*KP
    u16* A_bf    = Wh + (size_t)H * KP;                    // MA*KP
    u16* flatS   = A_bf + (size_t)MA * KP;                 // BS*KP

    pre_kernel<<<MTOT + H, 256, 0, stream>>>(
        all_support, all_query, support_emb, query_emb, fc_W,
        s_eh, s_eh_end, s_et, s_et_end, q_eh, q_eh_end, q_et, q_et_end,
        flatS, A_bf, Wh);

    avg_kernel<<<NPROTO, 256, 0, stream>>>(flatS, A_bf);

    gemm_mfma<<<240, 512, 0, stream>>>(A_bf, Wh, parts);

    protofin_kernel<<<NPROTO, 256, 0, stream>>>(parts, fc_b, proto);

    dist_kernel<<<BQ, 256, 0, stream>>>(parts, fc_b, proto, (float*)d_out);
}

// Round 6
// 76.669 us; speedup vs baseline: 4.1689x; 1.5413x over previous
//
#include <hip/hip_runtime.h>

// Problem constants (fixed by setup_inputs in the reference)
#define H        768
#define LMAX     128
#define CONV_NUM 8
#define CONV_SIZE 96
#define T_CONV   673            // H - CONV_SIZE + 1
#define FC_IN    5384           // CONV_NUM * T_CONV
#define KP       5408           // K padded to multiple of 32 (169 steps)
#define KSTEPS   (KP / 32)      // 169
#define N_WAY    10
#define K_SHOT   5
#define TOTAL_Q  150
#define SPLITK   8
#define BS       400
#define BQ       1200
#define MTOT     1600           // BS + BQ
#define NPROTO   80             // BS / K_SHOT
#define MA       1280           // NPROTO + BQ  (GEMM rows; 5 tiles of 256)

using s16x8 = __attribute__((ext_vector_type(8))) short;   // 8 bf16 (4 VGPRs)
using f32x4 = __attribute__((ext_vector_type(4))) float;   // MFMA acc
typedef unsigned short u16;

__device__ __forceinline__ u16 f2bf(float x) {              // RNE float->bf16 bits
    unsigned u = __float_as_uint(x);
    u += 0x7FFFu + ((u >> 16) & 1u);
    return (u16)(u >> 16);
}
__device__ __forceinline__ float bf2f(u16 b) { return __uint_as_float(((unsigned)b) << 16); }

__device__ __forceinline__ void gl16(const u16* g, u16* l) { // global->LDS 16B async
    __builtin_amdgcn_global_load_lds(
        (const __attribute__((address_space(1))) unsigned int*)g,
        (__attribute__((address_space(3))) unsigned int*)l, 16, 0, 0);
}

// ---------------------------------------------------------------------------
// 1) fused: [blocks 0..MTOT): entity-gather + MFMA conv(96) + ReLU + concat +
//    avgpool(2) -> bf16 rows.  Support rows -> flatS, query rows -> A[80..).
//    [blocks MTOT..MTOT+H): fc_W row -> bf16.
//    Conv as per-sample GEMM: A = filt(16x96, hi/lo 2-term in regs),
//    B = Hankel(x) built via 8 shifted bf16 LDS copies -> 1 aligned
//    ds_read_b128 per B-fragment. D[combo][pos] accumulated fp32, 6 MFMA/tile.
// ---------------------------------------------------------------------------
#define HTS 678                 // ht bf16 stride
#define XCS 784                 // xcs stride (16B-aligned rows, <=4-way banks)
__global__ __launch_bounds__(256, 4) void pre_kernel(
    const float* __restrict__ all_support, const float* __restrict__ all_query,
    const float* __restrict__ support_emb, const float* __restrict__ query_emb,
    const float* __restrict__ fc_W,
    const int* __restrict__ s_eh, const int* __restrict__ s_eh_end,
    const int* __restrict__ s_et, const int* __restrict__ s_et_end,
    const int* __restrict__ q_eh, const int* __restrict__ q_eh_end,
    const int* __restrict__ q_et, const int* __restrict__ q_et_end,
    u16* __restrict__ flatS, u16* __restrict__ A_bf,
    u16* __restrict__ Wh)
{
    int bid = blockIdx.x;
    int tid = threadIdx.x;

    if (bid >= MTOT) {                      // ---- W-split path ----
        int r = bid - MTOT;
        for (int j = tid; j < KP; j += 256) {
            float v = (j < FC_IN) ? fc_W[(size_t)r * FC_IN + j] : 0.f;
            Wh[(size_t)r * KP + j] = f2bf(v);
        }
        return;
    }

    // ---- conv path ----
    __shared__ u16 htb[16 * HTS];           // 21696 B; first 3200 B alias xs
    __shared__ u16 filt_h[16 * 96];         // combo-major: 0..7 head, 8..15 tail
    __shared__ u16 filt_l[16 * 96];
    __shared__ u16 xcs[8][XCS];             // xcs[c][i] = x[i+c], 16B rows
    float* xs = (float*)htb;                // dead before htb is written

    int b = bid;
    const float* src;
    int sh, eh, st, et;
    if (b < BS) {
        src = all_support + (size_t)b * LMAX * H;
        sh = s_eh[b]; eh = s_eh_end[b]; st = s_et[b]; et = s_et_end[b];
    } else {
        int m = b - BS;
        src = all_query + (size_t)m * LMAX * H;
        sh = q_eh[m]; eh = q_eh_end[m]; st = q_et[m]; et = q_et_end[m];
    }
    if (eh < sh + 1) eh = sh + 1;
    if (et < st + 1) et = st + 1;

    {   // entity gather -> filt hi/lo (head then tail), coalesced row reads
        float a0 = 0.f, a1 = 0.f, a2 = 0.f;
        for (int r = sh; r < eh; ++r) {
            const float* row = src + (size_t)r * H;
            a0 += row[tid]; a1 += row[tid + 256]; a2 += row[tid + 512];
        }
        float rc = 1.0f / (float)(eh - sh);
        float m0 = a0 * rc, m1 = a1 * rc, m2 = a2 * rc;
        u16 h0 = f2bf(m0), h1 = f2bf(m1), h2 = f2bf(m2);
        filt_h[tid] = h0;       filt_l[tid] = f2bf(m0 - bf2f(h0));
        filt_h[tid + 256] = h1; filt_l[tid + 256] = f2bf(m1 - bf2f(h1));
        filt_h[tid + 512] = h2; filt_l[tid + 512] = f2bf(m2 - bf2f(h2));
        a0 = a1 = a2 = 0.f;
        for (int r = st; r < et; ++r) {
            const float* row = src + (size_t)r * H;
            a0 += row[tid]; a1 += row[tid + 256]; a2 += row[tid + 512];
        }
        rc = 1.0f / (float)(et - st);
        m0 = a0 * rc; m1 = a1 * rc; m2 = a2 * rc;
        h0 = f2bf(m0); h1 = f2bf(m1); h2 = f2bf(m2);
        filt_h[tid + 768] = h0;  filt_l[tid + 768] = f2bf(m0 - bf2f(h0));
        filt_h[tid + 1024] = h1; filt_l[tid + 1024] = f2bf(m1 - bf2f(h1));
        filt_h[tid + 1280] = h2; filt_l[tid + 1280] = f2bf(m2 - bf2f(h2));
    }
    const float* xsrc = (b < BS) ? (support_emb + (size_t)b * H)
                                 : (query_emb + (size_t)(b - BS) * H);
    if (tid < 192)
        *(float4*)&xs[tid * 4] = *(const float4*)&xsrc[tid * 4];
    if (tid >= 192 && tid < 200) {
        int o = 768 + (tid - 192) * 4;
        xs[o] = 0.f; xs[o + 1] = 0.f; xs[o + 2] = 0.f; xs[o + 3] = 0.f;
    }
    __syncthreads();

    // build shifted bf16 copies of x (reads xs, which aliases htb — still live)
    #pragma unroll 1
    for (int c = 0; c < 8; ++c)
        for (int i = tid; i < XCS; i += 256)
            xcs[c][i] = f2bf(xs[i + c]);
    __syncthreads();                        // after this, htb may be written

    // ---- MFMA conv: D[combo(16)][pos(673)] = filt(16x96) @ HankelB(96x673)
    {
        int lane = tid & 63, wv = tid >> 6;
        int n = lane & 15, g = lane >> 4;
        int afo = n * 96 + g * 8;           // A-frag: combo = n, k = g*8+j
        s16x8 fh0 = *(const s16x8*)&filt_h[afo];
        s16x8 fh1 = *(const s16x8*)&filt_h[afo + 32];
        s16x8 fh2 = *(const s16x8*)&filt_h[afo + 64];
        s16x8 fl0 = *(const s16x8*)&filt_l[afo];
        s16x8 fl1 = *(const s16x8*)&filt_l[afo + 32];
        s16x8 fl2 = *(const s16x8*)&filt_l[afo + 64];
        // B-frag base: x[nt*16 + n + k], k = ks*32 + g*8 + j ->
        // xcs[n&7][nt*16 + (n&8) + ks*32 + g*8 + j]  (16B-aligned)
        const u16* xrow = &xcs[n & 7][g * 8 + (n & 8)];
        #pragma unroll 1
        for (int nt = wv; nt < 43; nt += 4) {
            const u16* xp = xrow + nt * 16;
            s16x8 x0 = *(const s16x8*)(xp);
            s16x8 x1 = *(const s16x8*)(xp + 32);
            s16x8 x2 = *(const s16x8*)(xp + 64);
            f32x4 a = (f32x4){0.f, 0.f, 0.f, 0.f};
            a = __builtin_amdgcn_mfma_f32_16x16x32_bf16(fh0, x0, a, 0, 0, 0);
            a = __builtin_amdgcn_mfma_f32_16x16x32_bf16(fl0, x0, a, 0, 0, 0);
            a = __builtin_amdgcn_mfma_f32_16x16x32_bf16(fh1, x1, a, 0, 0, 0);
            a = __builtin_amdgcn_mfma_f32_16x16x32_bf16(fl1, x1, a, 0, 0, 0);
            a = __builtin_amdgcn_mfma_f32_16x16x32_bf16(fh2, x2, a, 0, 0, 0);
            a = __builtin_amdgcn_mfma_f32_16x16x32_bf16(fl2, x2, a, 0, 0, 0);
            int pcol = nt * 16 + n;         // D: col=lane&15 -> position
            if (pcol < T_CONV) {
                #pragma unroll
                for (int r = 0; r < 4; ++r) // D: row=(lane>>4)*4+r -> combo
                    htb[(g * 4 + r) * HTS + pcol] = f2bf(fmaxf(a[r], 0.f));
            }
        }
    }
    __syncthreads();

    // avgpool(2) over concat(h_f, t_f); straddles h/t boundary at j=336
    u16* oh = (b < BS) ? (flatS + (size_t)b * KP)
                       : (A_bf + (size_t)(NPROTO + b - BS) * KP);
    for (int f = 0; f < CONV_NUM; ++f) {
        for (int j = tid; j < T_CONV; j += 256) {
            int i0 = 2 * j, i1 = 2 * j + 1;
            float v0 = bf2f((i0 < T_CONV) ? htb[f * HTS + i0]
                                          : htb[(8 + f) * HTS + (i0 - T_CONV)]);
            float v1 = bf2f((i1 < T_CONV) ? htb[f * HTS + i1]
                                          : htb[(8 + f) * HTS + (i1 - T_CONV)]);
            oh[f * T_CONV + j] = f2bf(0.5f * (v0 + v1));
        }
    }
    for (int j = FC_IN + tid; j < KP; j += 256) oh[j] = 0;
}

// ---------------------------------------------------------------------------
// 2) support pre-average (fc linear => mean-before == mean-after), 16B vec.
// ---------------------------------------------------------------------------
__global__ __launch_bounds__(256) void avg_kernel(
    const u16* __restrict__ flatS, u16* __restrict__ A_bf)
{
    int i = blockIdx.x;                   // proto row 0..79
    size_t base = (size_t)i * K_SHOT * KP;
    for (int t = threadIdx.x; t < KP / 8; t += 256) {
        int j = t * 8;
        float s[8] = {0.f, 0.f, 0.f, 0.f, 0.f, 0.f, 0.f, 0.f};
        #pragma unroll
        for (int k = 0; k < K_SHOT; ++k) {
            s16x8 vh = *(const s16x8*)(flatS + base + (size_t)k * KP + j);
            #pragma unroll
            for (int u = 0; u < 8; ++u)
                s[u] += bf2f((u16)vh[u]);
        }
        s16x8 oh;
        #pragma unroll
        for (int u = 0; u < 8; ++u)
            oh[u] = (short)f2bf(s[u] * (1.0f / K_SHOT));
        *(s16x8*)(A_bf + (size_t)i * KP + j) = oh;
    }
}

// ---------------------------------------------------------------------------
// 3) bf16 MFMA GEMM: C = A * W^T  (fp32 acc)
//    256x128 tile, BK=32, 512 thr / 8 waves x (64x64). Frag-native LDS.
//    2-ahead counted vmcnt(3). Grid 240 = 5m x 6n x 8sk, XCD-chunked swizzle.
// ---------------------------------------------------------------------------
#define ASEG 8192   // 256*32 u16 (16KB)
#define BSEG 4096   // 128*32 u16 (8KB)
#define BUFU (ASEG + BSEG)   // 12288 u16 = 24KB per buffer

#define STAGE(ks, buf) do {                                     \
    int kb_ = (ks) * 32;                                        \
    u16* L_ = &lds[buf][0];                                     \
    gl16(Ah_g + aoff0 + kb_, L_ + cA0 * 8);                     \
    gl16(Ah_g + aoff1 + kb_, L_ + cA1 * 8);                     \
    gl16(Bh_g + boff  + kb_, L_ + ASEG + cB * 8);               \
} while (0)

__global__ __launch_bounds__(512, 2) void gemm_mfma(
    const u16* __restrict__ Ah_g, const u16* __restrict__ Bh_g,
    float* __restrict__ parts)
{
    __shared__ u16 lds[2][BUFU];   // 48 KB

    int tid = threadIdx.x;
    // XCD-chunked bijective swizzle: 240 blocks = 8 XCDs x 30
    int wg = (blockIdx.x & 7) * 30 + (blockIdx.x >> 3);
    int sk = wg / 30;
    int rem = wg % 30;
    int n0 = (rem / 5) * 128;
    int m0 = (rem % 5) * 256;

    int ks0 = (KSTEPS * sk) / SPLITK;
    int nk = (KSTEPS * (sk + 1)) / SPLITK - ks0;   // 21 or 22

    // A chunks (1024 of 16B): c: frag=c>>6, kg=(c>>4)&3, row=c&15
    int cA0 = tid, cA1 = tid + 512;
    int cB = tid;                                  // B chunks (512)
    size_t aoff0 = (size_t)(m0 + (cA0 >> 6) * 16 + (cA0 & 15)) * KP + ((cA0 >> 4) & 3) * 8;
    size_t aoff1 = (size_t)(m0 + (cA1 >> 6) * 16 + (cA1 & 15)) * KP + ((cA1 >> 4) & 3) * 8;
    size_t boff  = (size_t)(n0 + (cB >> 6) * 16 + (cB & 15)) * KP + ((cB >> 4) & 3) * 8;

    int w = tid >> 6, lane = tid & 63;
    int wm = w >> 1, wn = w & 1;                   // 4x2 waves of 64x64
    int lfr = ((lane >> 4) * 16 + (lane & 15)) * 8;

    f32x4 acc[4][4];
    #pragma unroll
    for (int i = 0; i < 4; ++i)
        #pragma unroll
        for (int j = 0; j < 4; ++j) acc[i][j] = (f32x4){0.f, 0.f, 0.f, 0.f};

    STAGE(ks0, 0);          // 3 loads/thread in flight
    STAGE(ks0 + 1, 1);      // 6 in flight (nk >= 21 always)

    int cur = 0;
    for (int k = 0; k < nk; ++k) {
        if (k + 1 < nk) asm volatile("s_waitcnt vmcnt(3)" ::: "memory");
        else            asm volatile("s_waitcnt vmcnt(0)" ::: "memory");
        __builtin_amdgcn_s_barrier();

        const u16* L = &lds[cur][0];
        s16x8 ah[4], bh[4];
        #pragma unroll
        for (int f = 0; f < 4; ++f) {
            ah[f] = *(const s16x8*)(L + (wm * 4 + f) * 512 + lfr);
            bh[f] = *(const s16x8*)(L + ASEG + (wn * 4 + f) * 512 + lfr);
        }
        asm volatile("s_waitcnt lgkmcnt(0)" ::: "memory");
        __builtin_amdgcn_s_barrier();       // all waves done reading buf(cur)

        if (k + 2 < nk) STAGE(ks0 + k + 2, cur);   // flies under MFMA

        #pragma unroll
        for (int i = 0; i < 4; ++i)
            #pragma unroll
            for (int j = 0; j < 4; ++j)
                acc[i][j] = __builtin_amdgcn_mfma_f32_16x16x32_bf16(ah[i], bh[j], acc[i][j], 0, 0, 0);
        cur ^= 1;
    }

    // epilogue: C/D layout col=lane&15, row=(lane>>4)*4+reg  [m91-verified]
    int rbase = m0 + wm * 64 + (lane >> 4) * 4;
    int cbase = n0 + wn * 64 + (lane & 15);
    #pragma unroll
    for (int i = 0; i < 4; ++i) {
        int row0 = rbase + i * 16;
        #pragma unroll
        for (int j = 0; j < 4; ++j) {
            int col = cbase + j * 16;
            float* dst = parts + ((size_t)sk * MA + row0) * H + col;
            #pragma unroll
            for (int r = 0; r < 4; ++r)
                dst[(size_t)r * H] = acc[i][j][r];
        }
    }
}

// ---------------------------------------------------------------------------
// 4) proto finalize: proto[i] = sum_split parts[sp][i] + bias   (i < 80)
// ---------------------------------------------------------------------------
__global__ __launch_bounds__(256) void protofin_kernel(
    const float* __restrict__ parts, const float* __restrict__ bias,
    float* __restrict__ proto)
{
    int i = blockIdx.x;
    int tid = threadIdx.x;
    #pragma unroll
    for (int q = 0; q < 3; ++q) {
        int d = tid + q * 256;
        float s = bias[d];
        #pragma unroll
        for (int sp = 0; sp < SPLITK; ++sp)
            s += parts[((size_t)sp * MA + i) * H + d];
        proto[(size_t)i * H + d] = s;
    }
}

// ---------------------------------------------------------------------------
// 5) distances + logits + pred; grid = BQ blocks (one per query)
// ---------------------------------------------------------------------------
__global__ __launch_bounds__(256) void dist_kernel(
    const float* __restrict__ parts, const float* __restrict__ bias,
    const float* __restrict__ proto, float* __restrict__ outp)
{
    int bid = blockIdx.x;            // e*TOTAL_Q + q
    int e = bid / TOTAL_Q;
    int tid = threadIdx.x;
    int m = NPROTO + bid;            // GEMM row of this query

    float qv[3];
    #pragma unroll
    for (int q = 0; q < 3; ++q) {
        int d = tid + q * 256;
        float s = bias[d];
        #pragma unroll
        for (int sp = 0; sp < SPLITK; ++sp)
            s += parts[((size_t)sp * MA + m) * H + d];
        qv[q] = s;
    }

    __shared__ float red[N_WAY][4];
    __shared__ float lvals[N_WAY];
    int wave = tid >> 6, lane = tid & 63;
    for (int n = 0; n < N_WAY; ++n) {
        const float* pr = proto + (size_t)(e * N_WAY + n) * H;
        float p = 0.f;
        #pragma unroll
        for (int q = 0; q < 3; ++q) {
            int d = tid + q * 256;
            float df = pr[d] - qv[q];
            p = fmaf(df, df, p);
        }
        #pragma unroll
        for (int off = 32; off > 0; off >>= 1)
            p += __shfl_down(p, off);
        if (lane == 0) red[n][wave] = p;
    }
    __syncthreads();
    if (tid < N_WAY) {
        float v = red[tid][0] + red[tid][1] + red[tid][2] + red[tid][3];
        lvals[tid] = -v;
        outp[(size_t)bid * (N_WAY + 1) + tid] = -v;
    }
    __syncthreads();
    if (tid == 0) {
        float mn = lvals[0];
        #pragma unroll
        for (int n = 1; n < N_WAY; ++n) mn = fminf(mn, lvals[n]);
        float last = mn - 1.0f;
        outp[(size_t)bid * (N_WAY + 1) + N_WAY] = last;
        float best = lvals[0];
        int bi = 0;
        for (int n = 1; n < N_WAY; ++n)
            if (lvals[n] > best) { best = lvals[n]; bi = n; }
        if (last > best) bi = N_WAY;   // parity with reference; cannot trigger
        outp[(size_t)BQ * (N_WAY + 1) + bid] = (float)bi;
    }
}

// ---------------------------------------------------------------------------
extern "C" void kernel_launch(void* const* d_in, const int* in_sizes, int n_in,
                              void* d_out, int out_size, void* d_ws, size_t ws_size,
                              hipStream_t stream)
{
    const float* all_support = (const float*)d_in[0];
    const float* support_emb = (const float*)d_in[1];
    const float* all_query   = (const float*)d_in[2];
    const float* query_emb   = (const float*)d_in[3];
    const float* fc_W        = (const float*)d_in[4];
    const float* fc_b        = (const float*)d_in[5];
    const int* s_eh     = (const int*)d_in[6];
    const int* s_eh_end = (const int*)d_in[7];
    const int* s_et     = (const int*)d_in[8];
    const int* s_et_end = (const int*)d_in[9];
    const int* q_eh     = (const int*)d_in[10];
    const int* q_eh_end = (const int*)d_in[11];
    const int* q_et     = (const int*)d_in[12];
    const int* q_et_end = (const int*)d_in[13];

    // workspace layout (fp32 first, then u16; all 16B-aligned)
    float* parts = (float*)d_ws;                           // SPLITK*MA*H
    float* proto = parts + (size_t)SPLITK * MA * H;        // NPROTO*H
    u16* Wh      = (u16*)(proto + (size_t)NPROTO * H);     // H*KP
    u16* A_bf    = Wh + (size_t)H * KP;                    // MA*KP
    u16* flatS   = A_bf + (size_t)MA * KP;                 // BS*KP

    pre_kernel<<<MTOT + H, 256, 0, stream>>>(
        all_support, all_query, support_emb, query_emb, fc_W,
        s_eh, s_eh_end, s_et, s_et_end, q_eh, q_eh_end, q_et, q_et_end,
        flatS, A_bf, Wh);

    avg_kernel<<<NPROTO, 256, 0, stream>>>(flatS, A_bf);

    gemm_mfma<<<240, 512, 0, stream>>>(A_bf, Wh, parts);

    protofin_kernel<<<NPROTO, 256, 0, stream>>>(parts, fc_b, proto);

    dist_kernel<<<BQ, 256, 0, stream>>>(parts, fc_b, proto, (float*)d_out);
}

// Round 7
// 74.754 us; speedup vs baseline: 4.2757x; 1.0256x over previous
//
#include <hip/hip_runtime.h>

// Problem constants (fixed by setup_inputs in the reference)
#define H        768
#define LMAX     128
#define CONV_NUM 8
#define CONV_SIZE 96
#define T_CONV   673            // H - CONV_SIZE + 1
#define FC_IN    5384           // CONV_NUM * T_CONV
#define KP       5408           // K padded to multiple of 32 (169 steps)
#define KSTEPS   (KP / 32)      // 169
#define N_WAY    10
#define K_SHOT   5
#define TOTAL_Q  150
#define SPLITK   8
#define BS       400
#define BQ       1200
#define MTOT     1600           // BS + BQ
#define NPROTO   80             // BS / K_SHOT
#define MA       1280           // NPROTO + BQ  (GEMM rows; 5 tiles of 256)

using s16x8 = __attribute__((ext_vector_type(8))) short;   // 8 bf16 (4 VGPRs)
using f32x4 = __attribute__((ext_vector_type(4))) float;   // MFMA acc
typedef unsigned short u16;

__device__ __forceinline__ u16 f2bf(float x) {              // RNE float->bf16 bits
    unsigned u = __float_as_uint(x);
    u += 0x7FFFu + ((u >> 16) & 1u);
    return (u16)(u >> 16);
}
__device__ __forceinline__ float bf2f(u16 b) { return __uint_as_float(((unsigned)b) << 16); }

__device__ __forceinline__ void gl16(const u16* g, u16* l) { // global->LDS 16B async
    __builtin_amdgcn_global_load_lds(
        (const __attribute__((address_space(1))) unsigned int*)g,
        (__attribute__((address_space(3))) unsigned int*)l, 16, 0, 0);
}

// ---------------------------------------------------------------------------
// 1) fused: [blocks 0..MTOT): entity-gather + MFMA conv(96) + ReLU + concat +
//    avgpool(2) -> bf16 rows.  Support rows -> flatS, query rows -> A[80..).
//    [blocks MTOT..MTOT+H): fc_W row -> bf16.
//    Conv as per-sample GEMM: A = filt(16x96, hi/lo 2-term in regs),
//    B = Hankel(x) built via 8 shifted bf16 LDS copies -> 1 aligned
//    ds_read_b128 per B-fragment. D[combo][pos] accumulated fp32, 6 MFMA/tile.
// ---------------------------------------------------------------------------
#define HTS 678                 // ht bf16 stride
#define XCS 784                 // xcs stride (16B-aligned rows, <=4-way banks)
__global__ __launch_bounds__(256, 4) void pre_kernel(
    const float* __restrict__ all_support, const float* __restrict__ all_query,
    const float* __restrict__ support_emb, const float* __restrict__ query_emb,
    const float* __restrict__ fc_W,
    const int* __restrict__ s_eh, const int* __restrict__ s_eh_end,
    const int* __restrict__ s_et, const int* __restrict__ s_et_end,
    const int* __restrict__ q_eh, const int* __restrict__ q_eh_end,
    const int* __restrict__ q_et, const int* __restrict__ q_et_end,
    u16* __restrict__ flatS, u16* __restrict__ A_bf,
    u16* __restrict__ Wh)
{
    int bid = blockIdx.x;
    int tid = threadIdx.x;

    if (bid >= MTOT) {                      // ---- W-split path ----
        int r = bid - MTOT;
        for (int j = tid; j < KP; j += 256) {
            float v = (j < FC_IN) ? fc_W[(size_t)r * FC_IN + j] : 0.f;
            Wh[(size_t)r * KP + j] = f2bf(v);
        }
        return;
    }

    // ---- conv path ----
    __shared__ u16 htb[16 * HTS];           // 21696 B; first 3200 B alias xs
    __shared__ u16 filt_h[16 * 96];         // combo-major: 0..7 head, 8..15 tail
    __shared__ u16 filt_l[16 * 96];
    __shared__ u16 xcs[8][XCS];             // xcs[c][i] = x[i+c], 16B rows
    float* xs = (float*)htb;                // dead before htb is written

    int b = bid;
    const float* src;
    int sh, eh, st, et;
    if (b < BS) {
        src = all_support + (size_t)b * LMAX * H;
        sh = s_eh[b]; eh = s_eh_end[b]; st = s_et[b]; et = s_et_end[b];
    } else {
        int m = b - BS;
        src = all_query + (size_t)m * LMAX * H;
        sh = q_eh[m]; eh = q_eh_end[m]; st = q_et[m]; et = q_et_end[m];
    }
    if (eh < sh + 1) eh = sh + 1;
    if (et < st + 1) et = st + 1;

    {   // entity gather -> filt hi/lo (head then tail), coalesced row reads
        float a0 = 0.f, a1 = 0.f, a2 = 0.f;
        for (int r = sh; r < eh; ++r) {
            const float* row = src + (size_t)r * H;
            a0 += row[tid]; a1 += row[tid + 256]; a2 += row[tid + 512];
        }
        float rc = 1.0f / (float)(eh - sh);
        float m0 = a0 * rc, m1 = a1 * rc, m2 = a2 * rc;
        u16 h0 = f2bf(m0), h1 = f2bf(m1), h2 = f2bf(m2);
        filt_h[tid] = h0;       filt_l[tid] = f2bf(m0 - bf2f(h0));
        filt_h[tid + 256] = h1; filt_l[tid + 256] = f2bf(m1 - bf2f(h1));
        filt_h[tid + 512] = h2; filt_l[tid + 512] = f2bf(m2 - bf2f(h2));
        a0 = a1 = a2 = 0.f;
        for (int r = st; r < et; ++r) {
            const float* row = src + (size_t)r * H;
            a0 += row[tid]; a1 += row[tid + 256]; a2 += row[tid + 512];
        }
        rc = 1.0f / (float)(et - st);
        m0 = a0 * rc; m1 = a1 * rc; m2 = a2 * rc;
        h0 = f2bf(m0); h1 = f2bf(m1); h2 = f2bf(m2);
        filt_h[tid + 768] = h0;  filt_l[tid + 768] = f2bf(m0 - bf2f(h0));
        filt_h[tid + 1024] = h1; filt_l[tid + 1024] = f2bf(m1 - bf2f(h1));
        filt_h[tid + 1280] = h2; filt_l[tid + 1280] = f2bf(m2 - bf2f(h2));
    }
    const float* xsrc = (b < BS) ? (support_emb + (size_t)b * H)
                                 : (query_emb + (size_t)(b - BS) * H);
    if (tid < 192)
        *(float4*)&xs[tid * 4] = *(const float4*)&xsrc[tid * 4];
    if (tid >= 192 && tid < 200) {
        int o = 768 + (tid - 192) * 4;
        xs[o] = 0.f; xs[o + 1] = 0.f; xs[o + 2] = 0.f; xs[o + 3] = 0.f;
    }
    __syncthreads();

    // build shifted bf16 copies of x (reads xs, which aliases htb — still live)
    #pragma unroll 1
    for (int c = 0; c < 8; ++c)
        for (int i = tid; i < XCS; i += 256)
            xcs[c][i] = f2bf(xs[i + c]);
    __syncthreads();                        // after this, htb may be written

    // ---- MFMA conv: D[combo(16)][pos(673)] = filt(16x96) @ HankelB(96x673)
    {
        int lane = tid & 63, wv = tid >> 6;
        int n = lane & 15, g = lane >> 4;
        int afo = n * 96 + g * 8;           // A-frag: combo = n, k = g*8+j
        s16x8 fh0 = *(const s16x8*)&filt_h[afo];
        s16x8 fh1 = *(const s16x8*)&filt_h[afo + 32];
        s16x8 fh2 = *(const s16x8*)&filt_h[afo + 64];
        s16x8 fl0 = *(const s16x8*)&filt_l[afo];
        s16x8 fl1 = *(const s16x8*)&filt_l[afo + 32];
        s16x8 fl2 = *(const s16x8*)&filt_l[afo + 64];
        // B-frag base: x[nt*16 + n + k], k = ks*32 + g*8 + j ->
        // xcs[n&7][nt*16 + (n&8) + ks*32 + g*8 + j]  (16B-aligned)
        const u16* xrow = &xcs[n & 7][g * 8 + (n & 8)];
        #pragma unroll 1
        for (int nt = wv; nt < 43; nt += 4) {
            const u16* xp = xrow + nt * 16;
            s16x8 x0 = *(const s16x8*)(xp);
            s16x8 x1 = *(const s16x8*)(xp + 32);
            s16x8 x2 = *(const s16x8*)(xp + 64);
            f32x4 a = (f32x4){0.f, 0.f, 0.f, 0.f};
            a = __builtin_amdgcn_mfma_f32_16x16x32_bf16(fh0, x0, a, 0, 0, 0);
            a = __builtin_amdgcn_mfma_f32_16x16x32_bf16(fl0, x0, a, 0, 0, 0);
            a = __builtin_amdgcn_mfma_f32_16x16x32_bf16(fh1, x1, a, 0, 0, 0);
            a = __builtin_amdgcn_mfma_f32_16x16x32_bf16(fl1, x1, a, 0, 0, 0);
            a = __builtin_amdgcn_mfma_f32_16x16x32_bf16(fh2, x2, a, 0, 0, 0);
            a = __builtin_amdgcn_mfma_f32_16x16x32_bf16(fl2, x2, a, 0, 0, 0);
            int pcol = nt * 16 + n;         // D: col=lane&15 -> position
            if (pcol < T_CONV) {
                #pragma unroll
                for (int r = 0; r < 4; ++r) // D: row=(lane>>4)*4+r -> combo
                    htb[(g * 4 + r) * HTS + pcol] = f2bf(fmaxf(a[r], 0.f));
            }
        }
    }
    __syncthreads();

    // avgpool(2) over concat(h_f, t_f); straddles h/t boundary at j=336
    u16* oh = (b < BS) ? (flatS + (size_t)b * KP)
                       : (A_bf + (size_t)(NPROTO + b - BS) * KP);
    for (int f = 0; f < CONV_NUM; ++f) {
        for (int j = tid; j < T_CONV; j += 256) {
            int i0 = 2 * j, i1 = 2 * j + 1;
            float v0 = bf2f((i0 < T_CONV) ? htb[f * HTS + i0]
                                          : htb[(8 + f) * HTS + (i0 - T_CONV)]);
            float v1 = bf2f((i1 < T_CONV) ? htb[f * HTS + i1]
                                          : htb[(8 + f) * HTS + (i1 - T_CONV)]);
            oh[f * T_CONV + j] = f2bf(0.5f * (v0 + v1));
        }
    }
    for (int j = FC_IN + tid; j < KP; j += 256) oh[j] = 0;
}

// ---------------------------------------------------------------------------
// 2) support pre-average (fc linear => mean-before == mean-after), 16B vec.
// ---------------------------------------------------------------------------
__global__ __launch_bounds__(256) void avg_kernel(
    const u16* __restrict__ flatS, u16* __restrict__ A_bf)
{
    int i = blockIdx.x;                   // proto row 0..79
    size_t base = (size_t)i * K_SHOT * KP;
    for (int t = threadIdx.x; t < KP / 8; t += 256) {
        int j = t * 8;
        float s[8] = {0.f, 0.f, 0.f, 0.f, 0.f, 0.f, 0.f, 0.f};
        #pragma unroll
        for (int k = 0; k < K_SHOT; ++k) {
            s16x8 vh = *(const s16x8*)(flatS + base + (size_t)k * KP + j);
            #pragma unroll
            for (int u = 0; u < 8; ++u)
                s[u] += bf2f((u16)vh[u]);
        }
        s16x8 oh;
        #pragma unroll
        for (int u = 0; u < 8; ++u)
            oh[u] = (short)f2bf(s[u] * (1.0f / K_SHOT));
        *(s16x8*)(A_bf + (size_t)i * KP + j) = oh;
    }
}

// ---------------------------------------------------------------------------
// 3) bf16 MFMA GEMM: C = A * W^T  (fp32 acc, bf16 C-store; bias dropped —
//    it cancels in proto-query differences).
//    256x128 tile, BK=32, 256 thr / 4 waves x (64x128): 32 MFMA : 12 ds_read
//    per K-step (ratio 2.67). Frag-native LDS. 2-ahead counted vmcnt(6).
//    Grid 240 = 5m x 6n x 8sk, XCD-chunked bijective swizzle.
// ---------------------------------------------------------------------------
#define ASEG 8192   // 256*32 u16 (16KB)
#define BSEG 4096   // 128*32 u16 (8KB)
#define BUFU (ASEG + BSEG)   // 12288 u16 = 24KB per buffer

#define STAGE(ks, buf) do {                                     \
    int kb_ = (ks) * 32;                                        \
    u16* L_ = &lds[buf][0];                                     \
    gl16(Ah_g + aoff0 + kb_, L_ + cA0 * 8);                     \
    gl16(Ah_g + aoff1 + kb_, L_ + cA1 * 8);                     \
    gl16(Ah_g + aoff2 + kb_, L_ + cA2 * 8);                     \
    gl16(Ah_g + aoff3 + kb_, L_ + cA3 * 8);                     \
    gl16(Bh_g + boff0 + kb_, L_ + ASEG + cB0 * 8);              \
    gl16(Bh_g + boff1 + kb_, L_ + ASEG + cB1 * 8);              \
} while (0)

__global__ __launch_bounds__(256, 2) void gemm_mfma(
    const u16* __restrict__ Ah_g, const u16* __restrict__ Bh_g,
    u16* __restrict__ partsB)
{
    __shared__ u16 lds[2][BUFU];   // 48 KB

    int tid = threadIdx.x;
    // XCD-chunked bijective swizzle: 240 blocks = 8 XCDs x 30
    int wg = (blockIdx.x & 7) * 30 + (blockIdx.x >> 3);
    int sk = wg / 30;
    int rem = wg % 30;
    int n0 = (rem / 5) * 128;
    int m0 = (rem % 5) * 256;

    int ks0 = (KSTEPS * sk) / SPLITK;
    int nk = (KSTEPS * (sk + 1)) / SPLITK - ks0;   // 21 or 22

    // A chunks (1024 of 16B): c: frag=c>>6, kg=(c>>4)&3, row=c&15
    int cA0 = tid, cA1 = tid + 256, cA2 = tid + 512, cA3 = tid + 768;
    int cB0 = tid, cB1 = tid + 256;               // B chunks (512)
    size_t aoff0 = (size_t)(m0 + (cA0 >> 6) * 16 + (cA0 & 15)) * KP + ((cA0 >> 4) & 3) * 8;
    size_t aoff1 = (size_t)(m0 + (cA1 >> 6) * 16 + (cA1 & 15)) * KP + ((cA1 >> 4) & 3) * 8;
    size_t aoff2 = (size_t)(m0 + (cA2 >> 6) * 16 + (cA2 & 15)) * KP + ((cA2 >> 4) & 3) * 8;
    size_t aoff3 = (size_t)(m0 + (cA3 >> 6) * 16 + (cA3 & 15)) * KP + ((cA3 >> 4) & 3) * 8;
    size_t boff0 = (size_t)(n0 + (cB0 >> 6) * 16 + (cB0 & 15)) * KP + ((cB0 >> 4) & 3) * 8;
    size_t boff1 = (size_t)(n0 + (cB1 >> 6) * 16 + (cB1 & 15)) * KP + ((cB1 >> 4) & 3) * 8;

    int w = tid >> 6, lane = tid & 63;            // wave w owns rows w*64..w*64+63
    int lfr = ((lane >> 4) * 16 + (lane & 15)) * 8;

    f32x4 acc[4][8];
    #pragma unroll
    for (int i = 0; i < 4; ++i)
        #pragma unroll
        for (int j = 0; j < 8; ++j) acc[i][j] = (f32x4){0.f, 0.f, 0.f, 0.f};

    STAGE(ks0, 0);          // 6 loads/thread in flight
    STAGE(ks0 + 1, 1);      // 12 in flight (nk >= 21 always)

    int cur = 0;
    for (int k = 0; k < nk; ++k) {
        if (k + 1 < nk) asm volatile("s_waitcnt vmcnt(6)" ::: "memory");
        else            asm volatile("s_waitcnt vmcnt(0)" ::: "memory");
        __builtin_amdgcn_s_barrier();

        const u16* L = &lds[cur][0];
        s16x8 ah[4], bh[8];
        #pragma unroll
        for (int f = 0; f < 4; ++f)
            ah[f] = *(const s16x8*)(L + (w * 4 + f) * 512 + lfr);
        #pragma unroll
        for (int j = 0; j < 8; ++j)
            bh[j] = *(const s16x8*)(L + ASEG + j * 512 + lfr);
        asm volatile("s_waitcnt lgkmcnt(0)" ::: "memory");
        __builtin_amdgcn_s_barrier();       // all waves done reading buf(cur)

        if (k + 2 < nk) STAGE(ks0 + k + 2, cur);   // flies under MFMA

        #pragma unroll
        for (int i = 0; i < 4; ++i)
            #pragma unroll
            for (int j = 0; j < 8; ++j)
                acc[i][j] = __builtin_amdgcn_mfma_f32_16x16x32_bf16(ah[i], bh[j], acc[i][j], 0, 0, 0);
        cur ^= 1;
    }

    // epilogue: C/D layout col=lane&15, row=(lane>>4)*4+reg  [m91-verified]
    int rbase = m0 + w * 64 + (lane >> 4) * 4;
    int cbase = n0 + (lane & 15);
    #pragma unroll
    for (int i = 0; i < 4; ++i) {
        int row0 = rbase + i * 16;
        #pragma unroll
        for (int j = 0; j < 8; ++j) {
            int col = cbase + j * 16;
            u16* dst = partsB + ((size_t)sk * MA + row0) * H + col;
            #pragma unroll
            for (int r = 0; r < 4; ++r)
                dst[(size_t)r * H] = f2bf(acc[i][j][r]);
        }
    }
}

// ---------------------------------------------------------------------------
// 4) proto finalize: proto[i] = sum_split partsB[sp][i]   (i < 80; no bias —
//    bias cancels in proto-query distance)
// ---------------------------------------------------------------------------
__global__ __launch_bounds__(256) void protofin_kernel(
    const u16* __restrict__ partsB, float* __restrict__ proto)
{
    int i = blockIdx.x;
    int tid = threadIdx.x;
    #pragma unroll
    for (int q = 0; q < 3; ++q) {
        int d = tid + q * 256;
        float s = 0.f;
        #pragma unroll
        for (int sp = 0; sp < SPLITK; ++sp)
            s += bf2f(partsB[((size_t)sp * MA + i) * H + d]);
        proto[(size_t)i * H + d] = s;
    }
}

// ---------------------------------------------------------------------------
// 5) distances + logits + pred; grid = BQ blocks (one per query)
// ---------------------------------------------------------------------------
__global__ __launch_bounds__(256) void dist_kernel(
    const u16* __restrict__ partsB, const float* __restrict__ proto,
    float* __restrict__ outp)
{
    int bid = blockIdx.x;            // e*TOTAL_Q + q
    int e = bid / TOTAL_Q;
    int tid = threadIdx.x;
    int m = NPROTO + bid;            // GEMM row of this query

    float qv[3];
    #pragma unroll
    for (int q = 0; q < 3; ++q) {
        int d = tid + q * 256;
        float s = 0.f;
        #pragma unroll
        for (int sp = 0; sp < SPLITK; ++sp)
            s += bf2f(partsB[((size_t)sp * MA + m) * H + d]);
        qv[q] = s;
    }

    __shared__ float red[N_WAY][4];
    __shared__ float lvals[N_WAY];
    int wave = tid >> 6, lane = tid & 63;
    for (int n = 0; n < N_WAY; ++n) {
        const float* pr = proto + (size_t)(e * N_WAY + n) * H;
        float p = 0.f;
        #pragma unroll
        for (int q = 0; q < 3; ++q) {
            int d = tid + q * 256;
            float df = pr[d] - qv[q];
            p = fmaf(df, df, p);
        }
        #pragma unroll
        for (int off = 32; off > 0; off >>= 1)
            p += __shfl_down(p, off);
        if (lane == 0) red[n][wave] = p;
    }
    __syncthreads();
    if (tid < N_WAY) {
        float v = red[tid][0] + red[tid][1] + red[tid][2] + red[tid][3];
        lvals[tid] = -v;
        outp[(size_t)bid * (N_WAY + 1) + tid] = -v;
    }
    __syncthreads();
    if (tid == 0) {
        float mn = lvals[0];
        #pragma unroll
        for (int n = 1; n < N_WAY; ++n) mn = fminf(mn, lvals[n]);
        float last = mn - 1.0f;
        outp[(size_t)bid * (N_WAY + 1) + N_WAY] = last;
        float best = lvals[0];
        int bi = 0;
        for (int n = 1; n < N_WAY; ++n)
            if (lvals[n] > best) { best = lvals[n]; bi = n; }
        if (last > best) bi = N_WAY;   // parity with reference; cannot trigger
        outp[(size_t)BQ * (N_WAY + 1) + bid] = (float)bi;
    }
}

// ---------------------------------------------------------------------------
extern "C" void kernel_launch(void* const* d_in, const int* in_sizes, int n_in,
                              void* d_out, int out_size, void* d_ws, size_t ws_size,
                              hipStream_t stream)
{
    const float* all_support = (const float*)d_in[0];
    const float* support_emb = (const float*)d_in[1];
    const float* all_query   = (const float*)d_in[2];
    const float* query_emb   = (const float*)d_in[3];
    const float* fc_W        = (const float*)d_in[4];
    const int* s_eh     = (const int*)d_in[6];
    const int* s_eh_end = (const int*)d_in[7];
    const int* s_et     = (const int*)d_in[8];
    const int* s_et_end = (const int*)d_in[9];
    const int* q_eh     = (const int*)d_in[10];
    const int* q_eh_end = (const int*)d_in[11];
    const int* q_et     = (const int*)d_in[12];
    const int* q_et_end = (const int*)d_in[13];

    // workspace layout (all segment sizes multiples of 16B)
    u16* partsB  = (u16*)d_ws;                             // SPLITK*MA*H u16
    float* proto = (float*)(partsB + (size_t)SPLITK * MA * H);  // NPROTO*H f32
    u16* Wh      = (u16*)(proto + (size_t)NPROTO * H);     // H*KP
    u16* A_bf    = Wh + (size_t)H * KP;                    // MA*KP
    u16* flatS   = A_bf + (size_t)MA * KP;                 // BS*KP

    pre_kernel<<<MTOT + H, 256, 0, stream>>>(
        all_support, all_query, support_emb, query_emb, fc_W,
        s_eh, s_eh_end, s_et, s_et_end, q_eh, q_eh_end, q_et, q_et_end,
        flatS, A_bf, Wh);

    avg_kernel<<<NPROTO, 256, 0, stream>>>(flatS, A_bf);

    gemm_mfma<<<240, 256, 0, stream>>>(A_bf, Wh, partsB);

    protofin_kernel<<<NPROTO, 256, 0, stream>>>(partsB, proto);

    dist_kernel<<<BQ, 256, 0, stream>>>(partsB, proto, (float*)d_out);
}

// Round 8
// 69.768 us; speedup vs baseline: 4.5812x; 1.0715x over previous
//
#include <hip/hip_runtime.h>

// Problem constants (fixed by setup_inputs in the reference)
#define H        768
#define LMAX     128
#define CONV_NUM 8
#define CONV_SIZE 96
#define T_CONV   673            // H - CONV_SIZE + 1
#define FC_IN    5384           // CONV_NUM * T_CONV
#define KP       5408           // K padded to multiple of 32 (169 steps)
#define KSTEPS   (KP / 32)      // 169
#define N_WAY    10
#define K_SHOT   5
#define TOTAL_Q  150
#define SPLITK   8
#define BS       400
#define BQ       1200
#define MTOT     1600           // BS + BQ
#define NPROTO   80             // BS / K_SHOT
#define MA       1280           // NPROTO + BQ  (GEMM rows; 5 tiles of 256)

using s16x8 = __attribute__((ext_vector_type(8))) short;   // 8 bf16 (4 VGPRs)
using f32x4 = __attribute__((ext_vector_type(4))) float;   // MFMA acc
typedef unsigned short u16;

__device__ __forceinline__ u16 f2bf(float x) {              // RNE float->bf16 bits
    unsigned u = __float_as_uint(x);
    u += 0x7FFFu + ((u >> 16) & 1u);
    return (u16)(u >> 16);
}
__device__ __forceinline__ float bf2f(u16 b) { return __uint_as_float(((unsigned)b) << 16); }

__device__ __forceinline__ void gl16(const u16* g, u16* l) { // global->LDS 16B async
    __builtin_amdgcn_global_load_lds(
        (const __attribute__((address_space(1))) unsigned int*)g,
        (__attribute__((address_space(3))) unsigned int*)l, 16, 0, 0);
}

// ---------------------------------------------------------------------------
// 1) fused: [blocks 0..MTOT): entity-gather + MFMA conv(96) + ReLU + concat +
//    avgpool(2) -> bf16 rows.  Support rows -> flatS, query rows -> A[80..).
//    [blocks MTOT..MTOT+H): fc_W row -> bf16 (float4/ushort4 vectorized).
//    Conv as per-sample GEMM: A = filt(16x96, hi/lo 2-term in regs),
//    B = Hankel(x) built via 8 shifted bf16 LDS copies -> 1 aligned
//    ds_read_b128 per B-fragment. D[combo][pos] accumulated fp32, 6 MFMA/tile.
// ---------------------------------------------------------------------------
#define HTS 678                 // ht bf16 stride
#define XCS 784                 // xcs stride (16B-aligned rows, <=4-way banks)
__global__ __launch_bounds__(256, 4) void pre_kernel(
    const float* __restrict__ all_support, const float* __restrict__ all_query,
    const float* __restrict__ support_emb, const float* __restrict__ query_emb,
    const float* __restrict__ fc_W,
    const int* __restrict__ s_eh, const int* __restrict__ s_eh_end,
    const int* __restrict__ s_et, const int* __restrict__ s_et_end,
    const int* __restrict__ q_eh, const int* __restrict__ q_eh_end,
    const int* __restrict__ q_et, const int* __restrict__ q_et_end,
    u16* __restrict__ flatS, u16* __restrict__ A_bf,
    u16* __restrict__ Wh)
{
    int bid = blockIdx.x;
    int tid = threadIdx.x;

    if (bid >= MTOT) {                      // ---- W-split path (vectorized) ----
        int r = bid - MTOT;
        const float* wr = fc_W + (size_t)r * FC_IN;
        u16* whr = Wh + (size_t)r * KP;
        for (int j4 = tid; j4 < KP / 4; j4 += 256) {   // 1352 groups of 4
            int j = j4 * 4;
            ushort4 o;
            if (j4 < FC_IN / 4) {                      // 1346 full float4s
                float4 v = *(const float4*)(wr + j);
                o.x = f2bf(v.x); o.y = f2bf(v.y); o.z = f2bf(v.z); o.w = f2bf(v.w);
            } else {
                o.x = 0; o.y = 0; o.z = 0; o.w = 0;    // K-pad
            }
            *(ushort4*)(whr + j) = o;
        }
        return;
    }

    // ---- conv path ----
    __shared__ u16 htb[16 * HTS];           // 21696 B
    __shared__ u16 filt_h[16 * 96];         // combo-major: 0..7 head, 8..15 tail
    __shared__ u16 filt_l[16 * 96];
    __shared__ u16 xcs[8][XCS];             // xcs[c][j] = bf16(x[j+c]), 16B rows

    int b = bid;
    const float* src;
    int sh, eh, st, et;
    if (b < BS) {
        src = all_support + (size_t)b * LMAX * H;
        sh = s_eh[b]; eh = s_eh_end[b]; st = s_et[b]; et = s_et_end[b];
    } else {
        int m = b - BS;
        src = all_query + (size_t)m * LMAX * H;
        sh = q_eh[m]; eh = q_eh_end[m]; st = q_et[m]; et = q_et_end[m];
    }
    if (eh < sh + 1) eh = sh + 1;
    if (et < st + 1) et = st + 1;

    {   // entity gather -> filt hi/lo; 2x-unrolled, 6 independent load chains
        float a0 = 0.f, a1 = 0.f, a2 = 0.f, b0 = 0.f, b1 = 0.f, b2 = 0.f;
        int r = sh;
        for (; r + 2 <= eh; r += 2) {
            const float* p0 = src + (size_t)r * H;
            const float* p1 = p0 + H;
            a0 += p0[tid]; a1 += p0[tid + 256]; a2 += p0[tid + 512];
            b0 += p1[tid]; b1 += p1[tid + 256]; b2 += p1[tid + 512];
        }
        if (r < eh) {
            const float* p0 = src + (size_t)r * H;
            a0 += p0[tid]; a1 += p0[tid + 256]; a2 += p0[tid + 512];
        }
        float rc = 1.0f / (float)(eh - sh);
        float m0 = (a0 + b0) * rc, m1 = (a1 + b1) * rc, m2 = (a2 + b2) * rc;
        u16 h0 = f2bf(m0), h1 = f2bf(m1), h2 = f2bf(m2);
        filt_h[tid] = h0;       filt_l[tid] = f2bf(m0 - bf2f(h0));
        filt_h[tid + 256] = h1; filt_l[tid + 256] = f2bf(m1 - bf2f(h1));
        filt_h[tid + 512] = h2; filt_l[tid + 512] = f2bf(m2 - bf2f(h2));
        a0 = a1 = a2 = b0 = b1 = b2 = 0.f;
        r = st;
        for (; r + 2 <= et; r += 2) {
            const float* p0 = src + (size_t)r * H;
            const float* p1 = p0 + H;
            a0 += p0[tid]; a1 += p0[tid + 256]; a2 += p0[tid + 512];
            b0 += p1[tid]; b1 += p1[tid + 256]; b2 += p1[tid + 512];
        }
        if (r < et) {
            const float* p0 = src + (size_t)r * H;
            a0 += p0[tid]; a1 += p0[tid + 256]; a2 += p0[tid + 512];
        }
        rc = 1.0f / (float)(et - st);
        m0 = (a0 + b0) * rc; m1 = (a1 + b1) * rc; m2 = (a2 + b2) * rc;
        h0 = f2bf(m0); h1 = f2bf(m1); h2 = f2bf(m2);
        filt_h[tid + 768] = h0;  filt_l[tid + 768] = f2bf(m0 - bf2f(h0));
        filt_h[tid + 1024] = h1; filt_l[tid + 1024] = f2bf(m1 - bf2f(h1));
        filt_h[tid + 1280] = h2; filt_l[tid + 1280] = f2bf(m2 - bf2f(h2));
    }

    // xcs direct build: global float4 -> cvt once -> 8 shifted LDS stores.
    // Zero region j in [768-c, XCS) is disjoint from data writes (j <= 767-c).
    {
        if (tid < 192) {                     // zero tails: row=tid/24, 24 idx each
            int row = tid / 24, idx = tid % 24;
            int j = 768 - row + idx;
            if (j < XCS) xcs[row][j] = 0;
        }
        const float* xsrc = (b < BS) ? (support_emb + (size_t)b * H)
                                     : (query_emb + (size_t)(b - BS) * H);
        if (tid < 192) {
            float4 v = *(const float4*)(xsrc + tid * 4);
            u16 h[4] = {f2bf(v.x), f2bf(v.y), f2bf(v.z), f2bf(v.w)};
            #pragma unroll
            for (int u = 0; u < 4; ++u) {
                int i = tid * 4 + u;
                #pragma unroll
                for (int c = 0; c < 8; ++c)
                    if (i >= c) xcs[c][i - c] = h[u];
            }
        }
    }
    __syncthreads();

    // ---- MFMA conv: D[combo(16)][pos(673)] = filt(16x96) @ HankelB(96x673)
    {
        int lane = tid & 63, wv = tid >> 6;
        int n = lane & 15, g = lane >> 4;
        int afo = n * 96 + g * 8;           // A-frag: combo = n, k = g*8+j
        s16x8 fh0 = *(const s16x8*)&filt_h[afo];
        s16x8 fh1 = *(const s16x8*)&filt_h[afo + 32];
        s16x8 fh2 = *(const s16x8*)&filt_h[afo + 64];
        s16x8 fl0 = *(const s16x8*)&filt_l[afo];
        s16x8 fl1 = *(const s16x8*)&filt_l[afo + 32];
        s16x8 fl2 = *(const s16x8*)&filt_l[afo + 64];
        // B-frag base: x[nt*16 + n + k], k = g*8+j ->
        // xcs[n&7][nt*16 + (n&8) + g*8 + j]  (16B-aligned)
        const u16* xrow = &xcs[n & 7][g * 8 + (n & 8)];
        #pragma unroll 1
        for (int nt = wv; nt < 43; nt += 4) {
            const u16* xp = xrow + nt * 16;
            s16x8 x0 = *(const s16x8*)(xp);
            s16x8 x1 = *(const s16x8*)(xp + 32);
            s16x8 x2 = *(const s16x8*)(xp + 64);
            f32x4 a = (f32x4){0.f, 0.f, 0.f, 0.f};
            a = __builtin_amdgcn_mfma_f32_16x16x32_bf16(fh0, x0, a, 0, 0, 0);
            a = __builtin_amdgcn_mfma_f32_16x16x32_bf16(fl0, x0, a, 0, 0, 0);
            a = __builtin_amdgcn_mfma_f32_16x16x32_bf16(fh1, x1, a, 0, 0, 0);
            a = __builtin_amdgcn_mfma_f32_16x16x32_bf16(fl1, x1, a, 0, 0, 0);
            a = __builtin_amdgcn_mfma_f32_16x16x32_bf16(fh2, x2, a, 0, 0, 0);
            a = __builtin_amdgcn_mfma_f32_16x16x32_bf16(fl2, x2, a, 0, 0, 0);
            int pcol = nt * 16 + n;         // D: col=lane&15 -> position
            if (pcol < T_CONV) {
                #pragma unroll
                for (int r = 0; r < 4; ++r) // D: row=(lane>>4)*4+r -> combo
                    htb[(g * 4 + r) * HTS + pcol] = f2bf(fmaxf(a[r], 0.f));
            }
        }
    }
    __syncthreads();

    // avgpool(2) over concat(h_f, t_f); straddles h/t boundary at j=336
    u16* oh = (b < BS) ? (flatS + (size_t)b * KP)
                       : (A_bf + (size_t)(NPROTO + b - BS) * KP);
    for (int f = 0; f < CONV_NUM; ++f) {
        for (int j = tid; j < T_CONV; j += 256) {
            int i0 = 2 * j, i1 = 2 * j + 1;
            float v0 = bf2f((i0 < T_CONV) ? htb[f * HTS + i0]
                                          : htb[(8 + f) * HTS + (i0 - T_CONV)]);
            float v1 = bf2f((i1 < T_CONV) ? htb[f * HTS + i1]
                                          : htb[(8 + f) * HTS + (i1 - T_CONV)]);
            oh[f * T_CONV + j] = f2bf(0.5f * (v0 + v1));
        }
    }
    for (int j = FC_IN + tid; j < KP; j += 256) oh[j] = 0;
}

// ---------------------------------------------------------------------------
// 2) support pre-average (fc linear => mean-before == mean-after), 16B vec.
// ---------------------------------------------------------------------------
__global__ __launch_bounds__(256) void avg_kernel(
    const u16* __restrict__ flatS, u16* __restrict__ A_bf)
{
    int i = blockIdx.x;                   // proto row 0..79
    size_t base = (size_t)i * K_SHOT * KP;
    for (int t = threadIdx.x; t < KP / 8; t += 256) {
        int j = t * 8;
        float s[8] = {0.f, 0.f, 0.f, 0.f, 0.f, 0.f, 0.f, 0.f};
        #pragma unroll
        for (int k = 0; k < K_SHOT; ++k) {
            s16x8 vh = *(const s16x8*)(flatS + base + (size_t)k * KP + j);
            #pragma unroll
            for (int u = 0; u < 8; ++u)
                s[u] += bf2f((u16)vh[u]);
        }
        s16x8 oh;
        #pragma unroll
        for (int u = 0; u < 8; ++u)
            oh[u] = (short)f2bf(s[u] * (1.0f / K_SHOT));
        *(s16x8*)(A_bf + (size_t)i * KP + j) = oh;
    }
}

// ---------------------------------------------------------------------------
// 3) bf16 MFMA GEMM: C = A * W^T  (fp32 acc, bf16 C-store; bias dropped —
//    it cancels in proto-query differences).
//    256x128 tile, BK=32, 256 thr / 4 waves x (64x128): 32 MFMA : 12 ds_read
//    per K-step. Frag-native LDS. 2-ahead counted vmcnt(6).
//    Grid 240 = 5m x 6n x 8sk, XCD-chunked bijective swizzle.
// ---------------------------------------------------------------------------
#define ASEG 8192   // 256*32 u16 (16KB)
#define BSEG 4096   // 128*32 u16 (8KB)
#define BUFU (ASEG + BSEG)   // 12288 u16 = 24KB per buffer

#define STAGE(ks, buf) do {                                     \
    int kb_ = (ks) * 32;                                        \
    u16* L_ = &lds[buf][0];                                     \
    gl16(Ah_g + aoff0 + kb_, L_ + cA0 * 8);                     \
    gl16(Ah_g + aoff1 + kb_, L_ + cA1 * 8);                     \
    gl16(Ah_g + aoff2 + kb_, L_ + cA2 * 8);                     \
    gl16(Ah_g + aoff3 + kb_, L_ + cA3 * 8);                     \
    gl16(Bh_g + boff0 + kb_, L_ + ASEG + cB0 * 8);              \
    gl16(Bh_g + boff1 + kb_, L_ + ASEG + cB1 * 8);              \
} while (0)

__global__ __launch_bounds__(256, 2) void gemm_mfma(
    const u16* __restrict__ Ah_g, const u16* __restrict__ Bh_g,
    u16* __restrict__ partsB)
{
    __shared__ u16 lds[2][BUFU];   // 48 KB

    int tid = threadIdx.x;
    // XCD-chunked bijective swizzle: 240 blocks = 8 XCDs x 30
    int wg = (blockIdx.x & 7) * 30 + (blockIdx.x >> 3);
    int sk = wg / 30;
    int rem = wg % 30;
    int n0 = (rem / 5) * 128;
    int m0 = (rem % 5) * 256;

    int ks0 = (KSTEPS * sk) / SPLITK;
    int nk = (KSTEPS * (sk + 1)) / SPLITK - ks0;   // 21 or 22

    // A chunks (1024 of 16B): c: frag=c>>6, kg=(c>>4)&3, row=c&15
    int cA0 = tid, cA1 = tid + 256, cA2 = tid + 512, cA3 = tid + 768;
    int cB0 = tid, cB1 = tid + 256;               // B chunks (512)
    size_t aoff0 = (size_t)(m0 + (cA0 >> 6) * 16 + (cA0 & 15)) * KP + ((cA0 >> 4) & 3) * 8;
    size_t aoff1 = (size_t)(m0 + (cA1 >> 6) * 16 + (cA1 & 15)) * KP + ((cA1 >> 4) & 3) * 8;
    size_t aoff2 = (size_t)(m0 + (cA2 >> 6) * 16 + (cA2 & 15)) * KP + ((cA2 >> 4) & 3) * 8;
    size_t aoff3 = (size_t)(m0 + (cA3 >> 6) * 16 + (cA3 & 15)) * KP + ((cA3 >> 4) & 3) * 8;
    size_t boff0 = (size_t)(n0 + (cB0 >> 6) * 16 + (cB0 & 15)) * KP + ((cB0 >> 4) & 3) * 8;
    size_t boff1 = (size_t)(n0 + (cB1 >> 6) * 16 + (cB1 & 15)) * KP + ((cB1 >> 4) & 3) * 8;

    int w = tid >> 6, lane = tid & 63;            // wave w owns rows w*64..w*64+63
    int lfr = ((lane >> 4) * 16 + (lane & 15)) * 8;

    f32x4 acc[4][8];
    #pragma unroll
    for (int i = 0; i < 4; ++i)
        #pragma unroll
        for (int j = 0; j < 8; ++j) acc[i][j] = (f32x4){0.f, 0.f, 0.f, 0.f};

    STAGE(ks0, 0);          // 6 loads/thread in flight
    STAGE(ks0 + 1, 1);      // 12 in flight (nk >= 21 always)

    int cur = 0;
    for (int k = 0; k < nk; ++k) {
        if (k + 1 < nk) asm volatile("s_waitcnt vmcnt(6)" ::: "memory");
        else            asm volatile("s_waitcnt vmcnt(0)" ::: "memory");
        __builtin_amdgcn_s_barrier();

        const u16* L = &lds[cur][0];
        s16x8 ah[4], bh[8];
        #pragma unroll
        for (int f = 0; f < 4; ++f)
            ah[f] = *(const s16x8*)(L + (w * 4 + f) * 512 + lfr);
        #pragma unroll
        for (int j = 0; j < 8; ++j)
            bh[j] = *(const s16x8*)(L + ASEG + j * 512 + lfr);
        asm volatile("s_waitcnt lgkmcnt(0)" ::: "memory");
        __builtin_amdgcn_s_barrier();       // all waves done reading buf(cur)

        if (k + 2 < nk) STAGE(ks0 + k + 2, cur);   // flies under MFMA

        #pragma unroll
        for (int i = 0; i < 4; ++i)
            #pragma unroll
            for (int j = 0; j < 8; ++j)
                acc[i][j] = __builtin_amdgcn_mfma_f32_16x16x32_bf16(ah[i], bh[j], acc[i][j], 0, 0, 0);
        cur ^= 1;
    }

    // epilogue: C/D layout col=lane&15, row=(lane>>4)*4+reg  [m91-verified]
    int rbase = m0 + w * 64 + (lane >> 4) * 4;
    int cbase = n0 + (lane & 15);
    #pragma unroll
    for (int i = 0; i < 4; ++i) {
        int row0 = rbase + i * 16;
        #pragma unroll
        for (int j = 0; j < 8; ++j) {
            int col = cbase + j * 16;
            u16* dst = partsB + ((size_t)sk * MA + row0) * H + col;
            #pragma unroll
            for (int r = 0; r < 4; ++r)
                dst[(size_t)r * H] = f2bf(acc[i][j][r]);
        }
    }
}

// ---------------------------------------------------------------------------
// 4) proto finalize: proto[i] = sum_split partsB[sp][i]   (i < 80)
// ---------------------------------------------------------------------------
__global__ __launch_bounds__(256) void protofin_kernel(
    const u16* __restrict__ partsB, float* __restrict__ proto)
{
    int i = blockIdx.x;
    int tid = threadIdx.x;
    #pragma unroll
    for (int q = 0; q < 3; ++q) {
        int d = tid + q * 256;
        float s = 0.f;
        #pragma unroll
        for (int sp = 0; sp < SPLITK; ++sp)
            s += bf2f(partsB[((size_t)sp * MA + i) * H + d]);
        proto[(size_t)i * H + d] = s;
    }
}

// ---------------------------------------------------------------------------
// 5) distances + logits + pred; grid = BQ blocks (one per query).
//    192 active threads x 4 contiguous dims: ushort4/float4 full-rate loads.
// ---------------------------------------------------------------------------
__global__ __launch_bounds__(256) void dist_kernel(
    const u16* __restrict__ partsB, const float* __restrict__ proto,
    float* __restrict__ outp)
{
    int bid = blockIdx.x;            // e*TOTAL_Q + q
    int e = bid / TOTAL_Q;
    int tid = threadIdx.x;
    int m = NPROTO + bid;            // GEMM row of this query
    int d0 = tid * 4;                // tid < 192 covers 768 dims

    float qv0 = 0.f, qv1 = 0.f, qv2 = 0.f, qv3 = 0.f;
    if (tid < 192) {
        #pragma unroll
        for (int sp = 0; sp < SPLITK; ++sp) {
            ushort4 v = *(const ushort4*)(partsB + ((size_t)sp * MA + m) * H + d0);
            qv0 += bf2f(v.x); qv1 += bf2f(v.y); qv2 += bf2f(v.z); qv3 += bf2f(v.w);
        }
    }

    __shared__ float red[N_WAY][4];
    __shared__ float lvals[N_WAY];
    int wave = tid >> 6, lane = tid & 63;
    for (int n = 0; n < N_WAY; ++n) {
        float p = 0.f;
        if (tid < 192) {
            const float* pr = proto + (size_t)(e * N_WAY + n) * H + d0;
            float4 pv = *(const float4*)pr;
            float df0 = pv.x - qv0, df1 = pv.y - qv1, df2 = pv.z - qv2, df3 = pv.w - qv3;
            p = df0 * df0;
            p = fmaf(df1, df1, p);
            p = fmaf(df2, df2, p);
            p = fmaf(df3, df3, p);
        }
        #pragma unroll
        for (int off = 32; off > 0; off >>= 1)
            p += __shfl_down(p, off);
        if (lane == 0) red[n][wave] = p;
    }
    __syncthreads();
    if (tid < N_WAY) {
        float v = red[tid][0] + red[tid][1] + red[tid][2] + red[tid][3];
        lvals[tid] = -v;
        outp[(size_t)bid * (N_WAY + 1) + tid] = -v;
    }
    __syncthreads();
    if (tid == 0) {
        float mn = lvals[0];
        #pragma unroll
        for (int n = 1; n < N_WAY; ++n) mn = fminf(mn, lvals[n]);
        float last = mn - 1.0f;
        outp[(size_t)bid * (N_WAY + 1) + N_WAY] = last;
        float best = lvals[0];
        int bi = 0;
        for (int n = 1; n < N_WAY; ++n)
            if (lvals[n] > best) { best = lvals[n]; bi = n; }
        if (last > best) bi = N_WAY;   // parity with reference; cannot trigger
        outp[(size_t)BQ * (N_WAY + 1) + bid] = (float)bi;
    }
}

// ---------------------------------------------------------------------------
extern "C" void kernel_launch(void* const* d_in, const int* in_sizes, int n_in,
                              void* d_out, int out_size, void* d_ws, size_t ws_size,
                              hipStream_t stream)
{
    const float* all_support = (const float*)d_in[0];
    const float* support_emb = (const float*)d_in[1];
    const float* all_query   = (const float*)d_in[2];
    const float* query_emb   = (const float*)d_in[3];
    const float* fc_W        = (const float*)d_in[4];
    const int* s_eh     = (const int*)d_in[6];
    const int* s_eh_end = (const int*)d_in[7];
    const int* s_et     = (const int*)d_in[8];
    const int* s_et_end = (const int*)d_in[9];
    const int* q_eh     = (const int*)d_in[10];
    const int* q_eh_end = (const int*)d_in[11];
    const int* q_et     = (const int*)d_in[12];
    const int* q_et_end = (const int*)d_in[13];

    // workspace layout (all segment sizes multiples of 16B)
    u16* partsB  = (u16*)d_ws;                             // SPLITK*MA*H u16
    float* proto = (float*)(partsB + (size_t)SPLITK * MA * H);  // NPROTO*H f32
    u16* Wh      = (u16*)(proto + (size_t)NPROTO * H);     // H*KP
    u16* A_bf    = Wh + (size_t)H * KP;                    // MA*KP
    u16* flatS   = A_bf + (size_t)MA * KP;                 // BS*KP

    pre_kernel<<<MTOT + H, 256, 0, stream>>>(
        all_support, all_query, support_emb, query_emb, fc_W,
        s_eh, s_eh_end, s_et, s_et_end, q_eh, q_eh_end, q_et, q_et_end,
        flatS, A_bf, Wh);

    avg_kernel<<<NPROTO, 256, 0, stream>>>(flatS, A_bf);

    gemm_mfma<<<240, 256, 0, stream>>>(A_bf, Wh, partsB);

    protofin_kernel<<<NPROTO, 256, 0, stream>>>(partsB, proto);

    dist_kernel<<<BQ, 256, 0, stream>>>(partsB, proto, (float*)d_out);
}

// Round 10
// 69.566 us; speedup vs baseline: 4.5946x; 1.0029x over previous
//
#include <hip/hip_runtime.h>

// Problem constants (fixed by setup_inputs in the reference)
#define H        768
#define LMAX     128
#define CONV_NUM 8
#define CONV_SIZE 96
#define T_CONV   673            // H - CONV_SIZE + 1
#define FC_IN    5384           // CONV_NUM * T_CONV
#define KP       5408           // K padded to multiple of 32 (169 steps)
#define KSTEPS   (KP / 32)      // 169
#define N_WAY    10
#define K_SHOT   5
#define TOTAL_Q  150
#define SPLITK   8
#define BS       400
#define BQ       1200
#define MTOT     1600           // BS + BQ
#define NPROTO   80             // BS / K_SHOT
#define MA       1280           // NPROTO + BQ  (GEMM rows; 5 tiles of 256)

using s16x8 = __attribute__((ext_vector_type(8))) short;   // 8 bf16 (4 VGPRs)
using f32x4 = __attribute__((ext_vector_type(4))) float;   // MFMA acc
typedef unsigned short u16;

__device__ __forceinline__ u16 f2bf(float x) {              // RNE float->bf16 bits
    unsigned u = __float_as_uint(x);
    u += 0x7FFFu + ((u >> 16) & 1u);
    return (u16)(u >> 16);
}
__device__ __forceinline__ float bf2f(u16 b) { return __uint_as_float(((unsigned)b) << 16); }

__device__ __forceinline__ void gl16(const u16* g, u16* l) { // global->LDS 16B async
    __builtin_amdgcn_global_load_lds(
        (const __attribute__((address_space(1))) unsigned int*)g,
        (__attribute__((address_space(3))) unsigned int*)l, 16, 0, 0);
}

// ---------------------------------------------------------------------------
// 1) fused: [blocks 0..MTOT): entity-gather + MFMA conv(96) + ReLU + concat +
//    avgpool(2) -> bf16 rows.  Support rows -> flatS, query rows -> A[80..).
//    [blocks MTOT..MTOT+H): fc_W row -> bf16 (float4/ushort4 vectorized).
//    Conv as per-sample GEMM: A = filt(16x96, hi/lo 2-term in regs),
//    B = Hankel(x) built via 8 shifted bf16 LDS copies -> 1 aligned
//    ds_read_b128 per B-fragment. D[combo][pos] accumulated fp32, 6 MFMA/tile.
// ---------------------------------------------------------------------------
#define HTS 678                 // ht bf16 stride
#define XCS 784                 // xcs stride (16B-aligned rows, <=4-way banks)
__global__ __launch_bounds__(256, 4) void pre_kernel(
    const float* __restrict__ all_support, const float* __restrict__ all_query,
    const float* __restrict__ support_emb, const float* __restrict__ query_emb,
    const float* __restrict__ fc_W,
    const int* __restrict__ s_eh, const int* __restrict__ s_eh_end,
    const int* __restrict__ s_et, const int* __restrict__ s_et_end,
    const int* __restrict__ q_eh, const int* __restrict__ q_eh_end,
    const int* __restrict__ q_et, const int* __restrict__ q_et_end,
    u16* __restrict__ flatS, u16* __restrict__ A_bf,
    u16* __restrict__ Wh)
{
    int bid = blockIdx.x;
    int tid = threadIdx.x;

    if (bid >= MTOT) {                      // ---- W-split path (vectorized) ----
        int r = bid - MTOT;
        const float* wr = fc_W + (size_t)r * FC_IN;
        u16* whr = Wh + (size_t)r * KP;
        for (int j4 = tid; j4 < KP / 4; j4 += 256) {   // 1352 groups of 4
            int j = j4 * 4;
            ushort4 o;
            if (j4 < FC_IN / 4) {                      // 1346 full float4s
                float4 v = *(const float4*)(wr + j);
                o.x = f2bf(v.x); o.y = f2bf(v.y); o.z = f2bf(v.z); o.w = f2bf(v.w);
            } else {
                o.x = 0; o.y = 0; o.z = 0; o.w = 0;    // K-pad
            }
            *(ushort4*)(whr + j) = o;
        }
        return;
    }

    // ---- conv path ----
    __shared__ u16 htb[16 * HTS];           // 21696 B
    __shared__ u16 filt_h[16 * 96];         // combo-major: 0..7 head, 8..15 tail
    __shared__ u16 filt_l[16 * 96];
    __shared__ u16 xcs[8][XCS];             // xcs[c][j] = bf16(x[j+c]), 16B rows

    int b = bid;
    const float* src;
    int sh, eh, st, et;
    if (b < BS) {
        src = all_support + (size_t)b * LMAX * H;
        sh = s_eh[b]; eh = s_eh_end[b]; st = s_et[b]; et = s_et_end[b];
    } else {
        int m = b - BS;
        src = all_query + (size_t)m * LMAX * H;
        sh = q_eh[m]; eh = q_eh_end[m]; st = q_et[m]; et = q_et_end[m];
    }
    if (eh < sh + 1) eh = sh + 1;
    if (et < st + 1) et = st + 1;

    {   // entity gather -> filt hi/lo; 4x-unrolled, 12 independent load chains
        float a0 = 0.f, a1 = 0.f, a2 = 0.f, b0 = 0.f, b1 = 0.f, b2 = 0.f;
        float c0 = 0.f, c1 = 0.f, c2 = 0.f, d0 = 0.f, d1 = 0.f, d2 = 0.f;
        int r = sh;
        for (; r + 4 <= eh; r += 4) {
            const float* p0 = src + (size_t)r * H;
            const float* p1 = p0 + H;
            const float* p2 = p0 + 2 * H;
            const float* p3 = p0 + 3 * H;
            a0 += p0[tid]; a1 += p0[tid + 256]; a2 += p0[tid + 512];
            b0 += p1[tid]; b1 += p1[tid + 256]; b2 += p1[tid + 512];
            c0 += p2[tid]; c1 += p2[tid + 256]; c2 += p2[tid + 512];
            d0 += p3[tid]; d1 += p3[tid + 256]; d2 += p3[tid + 512];
        }
        for (; r < eh; ++r) {
            const float* p0 = src + (size_t)r * H;
            a0 += p0[tid]; a1 += p0[tid + 256]; a2 += p0[tid + 512];
        }
        float rc = 1.0f / (float)(eh - sh);
        float m0 = ((a0 + b0) + (c0 + d0)) * rc;
        float m1 = ((a1 + b1) + (c1 + d1)) * rc;
        float m2 = ((a2 + b2) + (c2 + d2)) * rc;
        u16 h0 = f2bf(m0), h1 = f2bf(m1), h2 = f2bf(m2);
        filt_h[tid] = h0;       filt_l[tid] = f2bf(m0 - bf2f(h0));
        filt_h[tid + 256] = h1; filt_l[tid + 256] = f2bf(m1 - bf2f(h1));
        filt_h[tid + 512] = h2; filt_l[tid + 512] = f2bf(m2 - bf2f(h2));
        a0 = a1 = a2 = b0 = b1 = b2 = c0 = c1 = c2 = d0 = d1 = d2 = 0.f;
        r = st;
        for (; r + 4 <= et; r += 4) {
            const float* p0 = src + (size_t)r * H;
            const float* p1 = p0 + H;
            const float* p2 = p0 + 2 * H;
            const float* p3 = p0 + 3 * H;
            a0 += p0[tid]; a1 += p0[tid + 256]; a2 += p0[tid + 512];
            b0 += p1[tid]; b1 += p1[tid + 256]; b2 += p1[tid + 512];
            c0 += p2[tid]; c1 += p2[tid + 256]; c2 += p2[tid + 512];
            d0 += p3[tid]; d1 += p3[tid + 256]; d2 += p3[tid + 512];
        }
        for (; r < et; ++r) {
            const float* p0 = src + (size_t)r * H;
            a0 += p0[tid]; a1 += p0[tid + 256]; a2 += p0[tid + 512];
        }
        rc = 1.0f / (float)(et - st);
        m0 = ((a0 + b0) + (c0 + d0)) * rc;
        m1 = ((a1 + b1) + (c1 + d1)) * rc;
        m2 = ((a2 + b2) + (c2 + d2)) * rc;
        h0 = f2bf(m0); h1 = f2bf(m1); h2 = f2bf(m2);
        filt_h[tid + 768] = h0;  filt_l[tid + 768] = f2bf(m0 - bf2f(h0));
        filt_h[tid + 1024] = h1; filt_l[tid + 1024] = f2bf(m1 - bf2f(h1));
        filt_h[tid + 1280] = h2; filt_l[tid + 1280] = f2bf(m2 - bf2f(h2));
    }

    // xcs direct build: global float4 -> cvt once -> 8 shifted LDS stores.
    // Zero region j in [768-c, XCS) is disjoint from data writes (j <= 767-c).
    // Also zero htb pad columns (673..677 of each of 16 rows) defensively.
    {
        if (tid < 192) {                     // zero tails: row=tid/24, 24 idx each
            int row = tid / 24, idx = tid % 24;
            int j = 768 - row + idx;
            if (j < XCS) xcs[row][j] = 0;
        }
        if (tid >= 192 && tid < 192 + 80) {  // htb pad: 16 rows x 5 cols
            int t = tid - 192;
            htb[(t / 5) * HTS + 673 + (t % 5)] = 0;
        }
        const float* xsrc = (b < BS) ? (support_emb + (size_t)b * H)
                                     : (query_emb + (size_t)(b - BS) * H);
        if (tid < 192) {
            float4 v = *(const float4*)(xsrc + tid * 4);
            u16 h[4] = {f2bf(v.x), f2bf(v.y), f2bf(v.z), f2bf(v.w)};
            #pragma unroll
            for (int u = 0; u < 4; ++u) {
                int i = tid * 4 + u;
                #pragma unroll
                for (int c = 0; c < 8; ++c)
                    if (i >= c) xcs[c][i - c] = h[u];
            }
        }
    }
    __syncthreads();

    // ---- MFMA conv: D[combo(16)][pos(673)] = filt(16x96) @ HankelB(96x673)
    {
        int lane = tid & 63, wv = tid >> 6;
        int n = lane & 15, g = lane >> 4;
        int afo = n * 96 + g * 8;           // A-frag: combo = n, k = g*8+j
        s16x8 fh0 = *(const s16x8*)&filt_h[afo];
        s16x8 fh1 = *(const s16x8*)&filt_h[afo + 32];
        s16x8 fh2 = *(const s16x8*)&filt_h[afo + 64];
        s16x8 fl0 = *(const s16x8*)&filt_l[afo];
        s16x8 fl1 = *(const s16x8*)&filt_l[afo + 32];
        s16x8 fl2 = *(const s16x8*)&filt_l[afo + 64];
        // B-frag base: x[nt*16 + n + k], k = g*8+j ->
        // xcs[n&7][nt*16 + (n&8) + g*8 + j]  (16B-aligned)
        const u16* xrow = &xcs[n & 7][g * 8 + (n & 8)];
        #pragma unroll 1
        for (int nt = wv; nt < 43; nt += 4) {
            const u16* xp = xrow + nt * 16;
            s16x8 x0 = *(const s16x8*)(xp);
            s16x8 x1 = *(const s16x8*)(xp + 32);
            s16x8 x2 = *(const s16x8*)(xp + 64);
            f32x4 a = (f32x4){0.f, 0.f, 0.f, 0.f};
            a = __builtin_amdgcn_mfma_f32_16x16x32_bf16(fh0, x0, a, 0, 0, 0);
            a = __builtin_amdgcn_mfma_f32_16x16x32_bf16(fl0, x0, a, 0, 0, 0);
            a = __builtin_amdgcn_mfma_f32_16x16x32_bf16(fh1, x1, a, 0, 0, 0);
            a = __builtin_amdgcn_mfma_f32_16x16x32_bf16(fl1, x1, a, 0, 0, 0);
            a = __builtin_amdgcn_mfma_f32_16x16x32_bf16(fh2, x2, a, 0, 0, 0);
            a = __builtin_amdgcn_mfma_f32_16x16x32_bf16(fl2, x2, a, 0, 0, 0);
            int pcol = nt * 16 + n;         // D: col=lane&15 -> position
            if (pcol < T_CONV) {
                #pragma unroll
                for (int r = 0; r < 4; ++r) // D: row=(lane>>4)*4+r -> combo
                    htb[(g * 4 + r) * HTS + pcol] = f2bf(fmaxf(a[r], 0.f));
            }
        }
    }
    __syncthreads();

    // avgpool(2) over concat(h_f, t_f), flat-indexed: 8 outputs/thread ->
    // one aligned s16x8 store. i = f*673 + j; reads virtual concat idx 2j,2j+1.
    // Magic div: f = (i*24929)>>24 == i/673 exactly for 0 <= i < 2^18
    // (24929 = ceil(2^24/673); verified at i=672,673,1346,5383).
    u16* oh = (b < BS) ? (flatS + (size_t)b * KP)
                       : (A_bf + (size_t)(NPROTO + b - BS) * KP);
    for (int t = tid; t < KP / 8; t += 256) {   // 676 groups of 8
        int i0 = t * 8;
        s16x8 o;
        if (i0 < FC_IN) {
            #pragma unroll
            for (int u = 0; u < 8; ++u) {
                int i = i0 + u;                 // < 5384
                int f = (int)(((unsigned)i * 24929u) >> 24);   // i/673 exact
                int j = i - f * 673;
                int e0 = 2 * j, e1 = 2 * j + 1;
                float v0 = bf2f((e0 < T_CONV) ? htb[f * HTS + e0]
                                              : htb[(8 + f) * HTS + (e0 - T_CONV)]);
                float v1 = bf2f((e1 < T_CONV) ? htb[f * HTS + e1]
                                              : htb[(8 + f) * HTS + (e1 - T_CONV)]);
                o[u] = (short)f2bf(0.5f * (v0 + v1));
            }
        } else {
            #pragma unroll
            for (int u = 0; u < 8; ++u) o[u] = 0;   // K-pad
        }
        *(s16x8*)(oh + i0) = o;
    }
}

// ---------------------------------------------------------------------------
// 2) support pre-average (fc linear => mean-before == mean-after), 16B vec.
//    grid (80, 4): block.y owns a quarter of KP (169 groups of 8).
// ---------------------------------------------------------------------------
__global__ __launch_bounds__(256) void avg_kernel(
    const u16* __restrict__ flatS, u16* __restrict__ A_bf)
{
    int i = blockIdx.x;                   // proto row 0..79
    int q = blockIdx.y;                   // KP quarter
    size_t base = (size_t)i * K_SHOT * KP;
    int t = threadIdx.x;
    if (t >= 169) return;
    int j = (q * 169 + t) * 8;
    float s[8] = {0.f, 0.f, 0.f, 0.f, 0.f, 0.f, 0.f, 0.f};
    #pragma unroll
    for (int k = 0; k < K_SHOT; ++k) {
        s16x8 vh = *(const s16x8*)(flatS + base + (size_t)k * KP + j);
        #pragma unroll
        for (int u = 0; u < 8; ++u)
            s[u] += bf2f((u16)vh[u]);
    }
    s16x8 oh;
    #pragma unroll
    for (int u = 0; u < 8; ++u)
        oh[u] = (short)f2bf(s[u] * (1.0f / K_SHOT));
    *(s16x8*)(A_bf + (size_t)i * KP + j) = oh;
}

// ---------------------------------------------------------------------------
// 3) bf16 MFMA GEMM: C = A * W^T  (fp32 acc, bf16 C-store; bias dropped —
//    it cancels in proto-query differences).
//    256x128 tile, BK=32, 256 thr / 4 waves x (64x128): 32 MFMA : 12 ds_read
//    per K-step. Frag-native LDS. 2-ahead counted vmcnt(6).
//    Grid 240 = 5m x 6n x 8sk, XCD-chunked bijective swizzle.
// ---------------------------------------------------------------------------
#define ASEG 8192   // 256*32 u16 (16KB)
#define BSEG 4096   // 128*32 u16 (8KB)
#define BUFU (ASEG + BSEG)   // 12288 u16 = 24KB per buffer

#define STAGE(ks, buf) do {                                     \
    int kb_ = (ks) * 32;                                        \
    u16* L_ = &lds[buf][0];                                     \
    gl16(Ah_g + aoff0 + kb_, L_ + cA0 * 8);                     \
    gl16(Ah_g + aoff1 + kb_, L_ + cA1 * 8);                     \
    gl16(Ah_g + aoff2 + kb_, L_ + cA2 * 8);                     \
    gl16(Ah_g + aoff3 + kb_, L_ + cA3 * 8);                     \
    gl16(Bh_g + boff0 + kb_, L_ + ASEG + cB0 * 8);              \
    gl16(Bh_g + boff1 + kb_, L_ + ASEG + cB1 * 8);              \
} while (0)

__global__ __launch_bounds__(256, 2) void gemm_mfma(
    const u16* __restrict__ Ah_g, const u16* __restrict__ Bh_g,
    u16* __restrict__ partsB)
{
    __shared__ u16 lds[2][BUFU];   // 48 KB

    int tid = threadIdx.x;
    // XCD-chunked bijective swizzle: 240 blocks = 8 XCDs x 30
    int wg = (blockIdx.x & 7) * 30 + (blockIdx.x >> 3);
    int sk = wg / 30;
    int rem = wg % 30;
    int n0 = (rem / 5) * 128;
    int m0 = (rem % 5) * 256;

    int ks0 = (KSTEPS * sk) / SPLITK;
    int nk = (KSTEPS * (sk + 1)) / SPLITK - ks0;   // 21 or 22

    // A chunks (1024 of 16B): c: frag=c>>6, kg=(c>>4)&3, row=c&15
    int cA0 = tid, cA1 = tid + 256, cA2 = tid + 512, cA3 = tid + 768;
    int cB0 = tid, cB1 = tid + 256;               // B chunks (512)
    size_t aoff0 = (size_t)(m0 + (cA0 >> 6) * 16 + (cA0 & 15)) * KP + ((cA0 >> 4) & 3) * 8;
    size_t aoff1 = (size_t)(m0 + (cA1 >> 6) * 16 + (cA1 & 15)) * KP + ((cA1 >> 4) & 3) * 8;
    size_t aoff2 = (size_t)(m0 + (cA2 >> 6) * 16 + (cA2 & 15)) * KP + ((cA2 >> 4) & 3) * 8;
    size_t aoff3 = (size_t)(m0 + (cA3 >> 6) * 16 + (cA3 & 15)) * KP + ((cA3 >> 4) & 3) * 8;
    size_t boff0 = (size_t)(n0 + (cB0 >> 6) * 16 + (cB0 & 15)) * KP + ((cB0 >> 4) & 3) * 8;
    size_t boff1 = (size_t)(n0 + (cB1 >> 6) * 16 + (cB1 & 15)) * KP + ((cB1 >> 4) & 3) * 8;

    int w = tid >> 6, lane = tid & 63;            // wave w owns rows w*64..w*64+63
    int lfr = ((lane >> 4) * 16 + (lane & 15)) * 8;

    f32x4 acc[4][8];
    #pragma unroll
    for (int i = 0; i < 4; ++i)
        #pragma unroll
        for (int j = 0; j < 8; ++j) acc[i][j] = (f32x4){0.f, 0.f, 0.f, 0.f};

    STAGE(ks0, 0);          // 6 loads/thread in flight
    STAGE(ks0 + 1, 1);      // 12 in flight (nk >= 21 always)

    int cur = 0;
    for (int k = 0; k < nk; ++k) {
        if (k + 1 < nk) asm volatile("s_waitcnt vmcnt(6)" ::: "memory");
        else            asm volatile("s_waitcnt vmcnt(0)" ::: "memory");
        __builtin_amdgcn_s_barrier();

        const u16* L = &lds[cur][0];
        s16x8 ah[4], bh[8];
        #pragma unroll
        for (int f = 0; f < 4; ++f)
            ah[f] = *(const s16x8*)(L + (w * 4 + f) * 512 + lfr);
        #pragma unroll
        for (int j = 0; j < 8; ++j)
            bh[j] = *(const s16x8*)(L + ASEG + j * 512 + lfr);
        asm volatile("s_waitcnt lgkmcnt(0)" ::: "memory");
        __builtin_amdgcn_s_barrier();       // all waves done reading buf(cur)

        if (k + 2 < nk) STAGE(ks0 + k + 2, cur);   // flies under MFMA

        #pragma unroll
        for (int i = 0; i < 4; ++i)
            #pragma unroll
            for (int j = 0; j < 8; ++j)
                acc[i][j] = __builtin_amdgcn_mfma_f32_16x16x32_bf16(ah[i], bh[j], acc[i][j], 0, 0, 0);
        cur ^= 1;
    }

    // epilogue: C/D layout col=lane&15, row=(lane>>4)*4+reg  [m91-verified]
    int rbase = m0 + w * 64 + (lane >> 4) * 4;
    int cbase = n0 + (lane & 15);
    #pragma unroll
    for (int i = 0; i < 4; ++i) {
        int row0 = rbase + i * 16;
        #pragma unroll
        for (int j = 0; j < 8; ++j) {
            int col = cbase + j * 16;
            u16* dst = partsB + ((size_t)sk * MA + row0) * H + col;
            #pragma unroll
            for (int r = 0; r < 4; ++r)
                dst[(size_t)r * H] = f2bf(acc[i][j][r]);
        }
    }
}

// ---------------------------------------------------------------------------
// 4) proto finalize: proto[i] = sum_split partsB[sp][i]   (i < 80), ushort4.
// ---------------------------------------------------------------------------
__global__ __launch_bounds__(256) void protofin_kernel(
    const u16* __restrict__ partsB, float* __restrict__ proto)
{
    int i = blockIdx.x;
    int tid = threadIdx.x;
    if (tid >= 192) return;
    int d0 = tid * 4;
    float s0 = 0.f, s1 = 0.f, s2 = 0.f, s3 = 0.f;
    #pragma unroll
    for (int sp = 0; sp < SPLITK; ++sp) {
        ushort4 v = *(const ushort4*)(partsB + ((size_t)sp * MA + i) * H + d0);
        s0 += bf2f(v.x); s1 += bf2f(v.y); s2 += bf2f(v.z); s3 += bf2f(v.w);
    }
    *(float4*)(proto + (size_t)i * H + d0) = make_float4(s0, s1, s2, s3);
}

// ---------------------------------------------------------------------------
// 5) distances + logits + pred; grid = BQ blocks (one per query).
//    192 active threads x 4 contiguous dims: ushort4/float4 full-rate loads.
// ---------------------------------------------------------------------------
__global__ __launch_bounds__(256) void dist_kernel(
    const u16* __restrict__ partsB, const float* __restrict__ proto,
    float* __restrict__ outp)
{
    int bid = blockIdx.x;            // e*TOTAL_Q + q
    int e = bid / TOTAL_Q;
    int tid = threadIdx.x;
    int m = NPROTO + bid;            // GEMM row of this query
    int d0 = tid * 4;                // tid < 192 covers 768 dims

    float qv0 = 0.f, qv1 = 0.f, qv2 = 0.f, qv3 = 0.f;
    if (tid < 192) {
        #pragma unroll
        for (int sp = 0; sp < SPLITK; ++sp) {
            ushort4 v = *(const ushort4*)(partsB + ((size_t)sp * MA + m) * H + d0);
            qv0 += bf2f(v.x); qv1 += bf2f(v.y); qv2 += bf2f(v.z); qv3 += bf2f(v.w);
        }
    }

    __shared__ float red[N_WAY][4];
    __shared__ float lvals[N_WAY];
    int wave = tid >> 6, lane = tid & 63;
    for (int n = 0; n < N_WAY; ++n) {
        float p = 0.f;
        if (tid < 192) {
            const float* pr = proto + (size_t)(e * N_WAY + n) * H + d0;
            float4 pv = *(const float4*)pr;
            float df0 = pv.x - qv0, df1 = pv.y - qv1, df2 = pv.z - qv2, df3 = pv.w - qv3;
            p = df0 * df0;
            p = fmaf(df1, df1, p);
            p = fmaf(df2, df2, p);
            p = fmaf(df3, df3, p);
        }
        #pragma unroll
        for (int off = 32; off > 0; off >>= 1)
            p += __shfl_down(p, off);
        if (lane == 0) red[n][wave] = p;
    }
    __syncthreads();
    if (tid < N_WAY) {
        float v = red[tid][0] + red[tid][1] + red[tid][2] + red[tid][3];
        lvals[tid] = -v;
        outp[(size_t)bid * (N_WAY + 1) + tid] = -v;
    }
    __syncthreads();
    if (tid == 0) {
        float mn = lvals[0];
        #pragma unroll
        for (int n = 1; n < N_WAY; ++n) mn = fminf(mn, lvals[n]);
        float last = mn - 1.0f;
        outp[(size_t)bid * (N_WAY + 1) + N_WAY] = last;
        float best = lvals[0];
        int bi = 0;
        for (int n = 1; n < N_WAY; ++n)
            if (lvals[n] > best) { best = lvals[n]; bi = n; }
        if (last > best) bi = N_WAY;   // parity with reference; cannot trigger
        outp[(size_t)BQ * (N_WAY + 1) + bid] = (float)bi;
    }
}

// ---------------------------------------------------------------------------
extern "C" void kernel_launch(void* const* d_in, const int* in_sizes, int n_in,
                              void* d_out, int out_size, void* d_ws, size_t ws_size,
                              hipStream_t stream)
{
    const float* all_support = (const float*)d_in[0];
    const float* support_emb = (const float*)d_in[1];
    const float* all_query   = (const float*)d_in[2];
    const float* query_emb   = (const float*)d_in[3];
    const float* fc_W        = (const float*)d_in[4];
    const int* s_eh     = (const int*)d_in[6];
    const int* s_eh_end = (const int*)d_in[7];
    const int* s_et     = (const int*)d_in[8];
    const int* s_et_end = (const int*)d_in[9];
    const int* q_eh     = (const int*)d_in[10];
    const int* q_eh_end = (const int*)d_in[11];
    const int* q_et     = (const int*)d_in[12];
    const int* q_et_end = (const int*)d_in[13];

    // workspace layout (all segment sizes multiples of 16B)
    u16* partsB  = (u16*)d_ws;                             // SPLITK*MA*H u16
    float* proto = (float*)(partsB + (size_t)SPLITK * MA * H);  // NPROTO*H f32
    u16* Wh      = (u16*)(proto + (size_t)NPROTO * H);     // H*KP
    u16* A_bf    = Wh + (size_t)H * KP;                    // MA*KP
    u16* flatS   = A_bf + (size_t)MA * KP;                 // BS*KP

    pre_kernel<<<MTOT + H, 256, 0, stream>>>(
        all_support, all_query, support_emb, query_emb, fc_W,
        s_eh, s_eh_end, s_et, s_et_end, q_eh, q_eh_end, q_et, q_et_end,
        flatS, A_bf, Wh);

    avg_kernel<<<dim3(NPROTO, 4), 256, 0, stream>>>(flatS, A_bf);

    gemm_mfma<<<240, 256, 0, stream>>>(A_bf, Wh, partsB);

    protofin_kernel<<<NPROTO, 256, 0, stream>>>(partsB, proto);

    dist_kernel<<<BQ, 256, 0, stream>>>(partsB, proto, (float*)d_out);
}

// Round 11
// 68.742 us; speedup vs baseline: 4.6496x; 1.0120x over previous
//
#include <hip/hip_runtime.h>

// Problem constants (fixed by setup_inputs in the reference)
#define H        768
#define LMAX     128
#define CONV_NUM 8
#define CONV_SIZE 96
#define T_CONV   673            // H - CONV_SIZE + 1
#define FC_IN    5384           // CONV_NUM * T_CONV
#define KP       5408           // K padded to multiple of 32 (169 steps)
#define KSTEPS   (KP / 32)      // 169
#define N_WAY    10
#define K_SHOT   5
#define TOTAL_Q  150
#define SPLITK   8
#define BS       400
#define BQ       1200
#define MTOT     1600           // BS + BQ
#define NPROTO   80             // BS / K_SHOT
#define MA       1280           // NPROTO + BQ  (GEMM rows; 10 tiles of 128)

using s16x8 = __attribute__((ext_vector_type(8))) short;   // 8 bf16 (4 VGPRs)
using f32x4 = __attribute__((ext_vector_type(4))) float;   // MFMA acc
typedef unsigned short u16;

__device__ __forceinline__ u16 f2bf(float x) {              // RNE float->bf16 bits
    unsigned u = __float_as_uint(x);
    u += 0x7FFFu + ((u >> 16) & 1u);
    return (u16)(u >> 16);
}
__device__ __forceinline__ float bf2f(u16 b) { return __uint_as_float(((unsigned)b) << 16); }

__device__ __forceinline__ void gl16(const u16* g, u16* l) { // global->LDS 16B async
    __builtin_amdgcn_global_load_lds(
        (const __attribute__((address_space(1))) unsigned int*)g,
        (__attribute__((address_space(3))) unsigned int*)l, 16, 0, 0);
}

// ---------------------------------------------------------------------------
// 1) fused: [blocks 0..MTOT): entity-gather + MFMA conv(96) + ReLU + concat +
//    avgpool(2) -> bf16 rows.  Support rows -> flatS, query rows -> A[80..).
//    [blocks MTOT..MTOT+H): fc_W row -> bf16 (float4/ushort4 vectorized).
//    (unchanged from round 10 — verified)
// ---------------------------------------------------------------------------
#define HTS 678                 // ht bf16 stride
#define XCS 784                 // xcs stride (16B-aligned rows, <=4-way banks)
__global__ __launch_bounds__(256, 4) void pre_kernel(
    const float* __restrict__ all_support, const float* __restrict__ all_query,
    const float* __restrict__ support_emb, const float* __restrict__ query_emb,
    const float* __restrict__ fc_W,
    const int* __restrict__ s_eh, const int* __restrict__ s_eh_end,
    const int* __restrict__ s_et, const int* __restrict__ s_et_end,
    const int* __restrict__ q_eh, const int* __restrict__ q_eh_end,
    const int* __restrict__ q_et, const int* __restrict__ q_et_end,
    u16* __restrict__ flatS, u16* __restrict__ A_bf,
    u16* __restrict__ Wh)
{
    int bid = blockIdx.x;
    int tid = threadIdx.x;

    if (bid >= MTOT) {                      // ---- W-split path (vectorized) ----
        int r = bid - MTOT;
        const float* wr = fc_W + (size_t)r * FC_IN;
        u16* whr = Wh + (size_t)r * KP;
        for (int j4 = tid; j4 < KP / 4; j4 += 256) {   // 1352 groups of 4
            int j = j4 * 4;
            ushort4 o;
            if (j4 < FC_IN / 4) {                      // 1346 full float4s
                float4 v = *(const float4*)(wr + j);
                o.x = f2bf(v.x); o.y = f2bf(v.y); o.z = f2bf(v.z); o.w = f2bf(v.w);
            } else {
                o.x = 0; o.y = 0; o.z = 0; o.w = 0;    // K-pad
            }
            *(ushort4*)(whr + j) = o;
        }
        return;
    }

    // ---- conv path ----
    __shared__ u16 htb[16 * HTS];           // 21696 B
    __shared__ u16 filt_h[16 * 96];         // combo-major: 0..7 head, 8..15 tail
    __shared__ u16 filt_l[16 * 96];
    __shared__ u16 xcs[8][XCS];             // xcs[c][j] = bf16(x[j+c]), 16B rows

    int b = bid;
    const float* src;
    int sh, eh, st, et;
    if (b < BS) {
        src = all_support + (size_t)b * LMAX * H;
        sh = s_eh[b]; eh = s_eh_end[b]; st = s_et[b]; et = s_et_end[b];
    } else {
        int m = b - BS;
        src = all_query + (size_t)m * LMAX * H;
        sh = q_eh[m]; eh = q_eh_end[m]; st = q_et[m]; et = q_et_end[m];
    }
    if (eh < sh + 1) eh = sh + 1;
    if (et < st + 1) et = st + 1;

    {   // entity gather -> filt hi/lo; 4x-unrolled, 12 independent load chains
        float a0 = 0.f, a1 = 0.f, a2 = 0.f, b0 = 0.f, b1 = 0.f, b2 = 0.f;
        float c0 = 0.f, c1 = 0.f, c2 = 0.f, d0 = 0.f, d1 = 0.f, d2 = 0.f;
        int r = sh;
        for (; r + 4 <= eh; r += 4) {
            const float* p0 = src + (size_t)r * H;
            const float* p1 = p0 + H;
            const float* p2 = p0 + 2 * H;
            const float* p3 = p0 + 3 * H;
            a0 += p0[tid]; a1 += p0[tid + 256]; a2 += p0[tid + 512];
            b0 += p1[tid]; b1 += p1[tid + 256]; b2 += p1[tid + 512];
            c0 += p2[tid]; c1 += p2[tid + 256]; c2 += p2[tid + 512];
            d0 += p3[tid]; d1 += p3[tid + 256]; d2 += p3[tid + 512];
        }
        for (; r < eh; ++r) {
            const float* p0 = src + (size_t)r * H;
            a0 += p0[tid]; a1 += p0[tid + 256]; a2 += p0[tid + 512];
        }
        float rc = 1.0f / (float)(eh - sh);
        float m0 = ((a0 + b0) + (c0 + d0)) * rc;
        float m1 = ((a1 + b1) + (c1 + d1)) * rc;
        float m2 = ((a2 + b2) + (c2 + d2)) * rc;
        u16 h0 = f2bf(m0), h1 = f2bf(m1), h2 = f2bf(m2);
        filt_h[tid] = h0;       filt_l[tid] = f2bf(m0 - bf2f(h0));
        filt_h[tid + 256] = h1; filt_l[tid + 256] = f2bf(m1 - bf2f(h1));
        filt_h[tid + 512] = h2; filt_l[tid + 512] = f2bf(m2 - bf2f(h2));
        a0 = a1 = a2 = b0 = b1 = b2 = c0 = c1 = c2 = d0 = d1 = d2 = 0.f;
        r = st;
        for (; r + 4 <= et; r += 4) {
            const float* p0 = src + (size_t)r * H;
            const float* p1 = p0 + H;
            const float* p2 = p0 + 2 * H;
            const float* p3 = p0 + 3 * H;
            a0 += p0[tid]; a1 += p0[tid + 256]; a2 += p0[tid + 512];
            b0 += p1[tid]; b1 += p1[tid + 256]; b2 += p1[tid + 512];
            c0 += p2[tid]; c1 += p2[tid + 256]; c2 += p2[tid + 512];
            d0 += p3[tid]; d1 += p3[tid + 256]; d2 += p3[tid + 512];
        }
        for (; r < et; ++r) {
            const float* p0 = src + (size_t)r * H;
            a0 += p0[tid]; a1 += p0[tid + 256]; a2 += p0[tid + 512];
        }
        rc = 1.0f / (float)(et - st);
        m0 = ((a0 + b0) + (c0 + d0)) * rc;
        m1 = ((a1 + b1) + (c1 + d1)) * rc;
        m2 = ((a2 + b2) + (c2 + d2)) * rc;
        h0 = f2bf(m0); h1 = f2bf(m1); h2 = f2bf(m2);
        filt_h[tid + 768] = h0;  filt_l[tid + 768] = f2bf(m0 - bf2f(h0));
        filt_h[tid + 1024] = h1; filt_l[tid + 1024] = f2bf(m1 - bf2f(h1));
        filt_h[tid + 1280] = h2; filt_l[tid + 1280] = f2bf(m2 - bf2f(h2));
    }

    // xcs direct build: global float4 -> cvt once -> 8 shifted LDS stores.
    {
        if (tid < 192) {                     // zero tails: row=tid/24, 24 idx each
            int row = tid / 24, idx = tid % 24;
            int j = 768 - row + idx;
            if (j < XCS) xcs[row][j] = 0;
        }
        if (tid >= 192 && tid < 192 + 80) {  // htb pad: 16 rows x 5 cols
            int t = tid - 192;
            htb[(t / 5) * HTS + 673 + (t % 5)] = 0;
        }
        const float* xsrc = (b < BS) ? (support_emb + (size_t)b * H)
                                     : (query_emb + (size_t)(b - BS) * H);
        if (tid < 192) {
            float4 v = *(const float4*)(xsrc + tid * 4);
            u16 h[4] = {f2bf(v.x), f2bf(v.y), f2bf(v.z), f2bf(v.w)};
            #pragma unroll
            for (int u = 0; u < 4; ++u) {
                int i = tid * 4 + u;
                #pragma unroll
                for (int c = 0; c < 8; ++c)
                    if (i >= c) xcs[c][i - c] = h[u];
            }
        }
    }
    __syncthreads();

    // ---- MFMA conv: D[combo(16)][pos(673)] = filt(16x96) @ HankelB(96x673)
    {
        int lane = tid & 63, wv = tid >> 6;
        int n = lane & 15, g = lane >> 4;
        int afo = n * 96 + g * 8;           // A-frag: combo = n, k = g*8+j
        s16x8 fh0 = *(const s16x8*)&filt_h[afo];
        s16x8 fh1 = *(const s16x8*)&filt_h[afo + 32];
        s16x8 fh2 = *(const s16x8*)&filt_h[afo + 64];
        s16x8 fl0 = *(const s16x8*)&filt_l[afo];
        s16x8 fl1 = *(const s16x8*)&filt_l[afo + 32];
        s16x8 fl2 = *(const s16x8*)&filt_l[afo + 64];
        const u16* xrow = &xcs[n & 7][g * 8 + (n & 8)];
        #pragma unroll 1
        for (int nt = wv; nt < 43; nt += 4) {
            const u16* xp = xrow + nt * 16;
            s16x8 x0 = *(const s16x8*)(xp);
            s16x8 x1 = *(const s16x8*)(xp + 32);
            s16x8 x2 = *(const s16x8*)(xp + 64);
            f32x4 a = (f32x4){0.f, 0.f, 0.f, 0.f};
            a = __builtin_amdgcn_mfma_f32_16x16x32_bf16(fh0, x0, a, 0, 0, 0);
            a = __builtin_amdgcn_mfma_f32_16x16x32_bf16(fl0, x0, a, 0, 0, 0);
            a = __builtin_amdgcn_mfma_f32_16x16x32_bf16(fh1, x1, a, 0, 0, 0);
            a = __builtin_amdgcn_mfma_f32_16x16x32_bf16(fl1, x1, a, 0, 0, 0);
            a = __builtin_amdgcn_mfma_f32_16x16x32_bf16(fh2, x2, a, 0, 0, 0);
            a = __builtin_amdgcn_mfma_f32_16x16x32_bf16(fl2, x2, a, 0, 0, 0);
            int pcol = nt * 16 + n;         // D: col=lane&15 -> position
            if (pcol < T_CONV) {
                #pragma unroll
                for (int r = 0; r < 4; ++r) // D: row=(lane>>4)*4+r -> combo
                    htb[(g * 4 + r) * HTS + pcol] = f2bf(fmaxf(a[r], 0.f));
            }
        }
    }
    __syncthreads();

    // avgpool(2) over concat(h_f, t_f), flat-indexed; magic div by 673
    // (24929 = ceil(2^24/673), exact for i < 2^18).
    u16* oh = (b < BS) ? (flatS + (size_t)b * KP)
                       : (A_bf + (size_t)(NPROTO + b - BS) * KP);
    for (int t = tid; t < KP / 8; t += 256) {   // 676 groups of 8
        int i0 = t * 8;
        s16x8 o;
        if (i0 < FC_IN) {
            #pragma unroll
            for (int u = 0; u < 8; ++u) {
                int i = i0 + u;                 // < 5384
                int f = (int)(((unsigned)i * 24929u) >> 24);   // i/673 exact
                int j = i - f * 673;
                int e0 = 2 * j, e1 = 2 * j + 1;
                float v0 = bf2f((e0 < T_CONV) ? htb[f * HTS + e0]
                                              : htb[(8 + f) * HTS + (e0 - T_CONV)]);
                float v1 = bf2f((e1 < T_CONV) ? htb[f * HTS + e1]
                                              : htb[(8 + f) * HTS + (e1 - T_CONV)]);
                o[u] = (short)f2bf(0.5f * (v0 + v1));
            }
        } else {
            #pragma unroll
            for (int u = 0; u < 8; ++u) o[u] = 0;   // K-pad
        }
        *(s16x8*)(oh + i0) = o;
    }
}

// ---------------------------------------------------------------------------
// 2) support pre-average (fc linear => mean-before == mean-after), 16B vec.
//    grid (80, 3): t = by*256+tid covers all 676 groups of 8.
// ---------------------------------------------------------------------------
__global__ __launch_bounds__(256) void avg_kernel(
    const u16* __restrict__ flatS, u16* __restrict__ A_bf)
{
    int i = blockIdx.x;                   // proto row 0..79
    int t = blockIdx.y * 256 + threadIdx.x;
    if (t >= KP / 8) return;
    size_t base = (size_t)i * K_SHOT * KP;
    int j = t * 8;
    float s[8] = {0.f, 0.f, 0.f, 0.f, 0.f, 0.f, 0.f, 0.f};
    #pragma unroll
    for (int k = 0; k < K_SHOT; ++k) {
        s16x8 vh = *(const s16x8*)(flatS + base + (size_t)k * KP + j);
        #pragma unroll
        for (int u = 0; u < 8; ++u)
            s[u] += bf2f((u16)vh[u]);
    }
    s16x8 oh;
    #pragma unroll
    for (int u = 0; u < 8; ++u)
        oh[u] = (short)f2bf(s[u] * (1.0f / K_SHOT));
    *(s16x8*)(A_bf + (size_t)i * KP + j) = oh;
}

// ---------------------------------------------------------------------------
// 3) bf16 MFMA GEMM: C = A * W^T  (fp32 acc, bf16 C-store; bias dropped).
//    m97-proven geometry: 128x128 tile, BK=32, 256 thr / 4 waves x (64x64),
//    16 MFMA : 8 ds_read per K-step. Frag-native LDS (2x16KB dbuf).
//    2-ahead counted vmcnt(4). Grid 480 = 10m x 6n x 8sk — ALL co-resident
//    at 3 blocks/CU (launch_bounds(256,3)), zero tail, barrier drains hidden
//    by co-resident blocks. XCD swizzle 480 = 8 x 60: each XCD owns one full
//    split-K slice (A+B slice ~2.8 MB -> L2-resident).
// ---------------------------------------------------------------------------
#define ASEG 4096   // 128*32 u16 (8KB)
#define BSEG 4096   // 128*32 u16 (8KB)
#define BUFU (ASEG + BSEG)   // 8192 u16 = 16KB per buffer

#define STAGE(ks, buf) do {                                     \
    int kb_ = (ks) * 32;                                        \
    u16* L_ = &lds[buf][0];                                     \
    gl16(Ah_g + aoff0 + kb_, L_ + cA0 * 8);                     \
    gl16(Ah_g + aoff1 + kb_, L_ + cA1 * 8);                     \
    gl16(Bh_g + boff0 + kb_, L_ + ASEG + cA0 * 8);              \
    gl16(Bh_g + boff1 + kb_, L_ + ASEG + cA1 * 8);              \
} while (0)

__global__ __launch_bounds__(256, 3) void gemm_mfma(
    const u16* __restrict__ Ah_g, const u16* __restrict__ Bh_g,
    u16* __restrict__ partsB)
{
    __shared__ u16 lds[2][BUFU];   // 32 KB

    int tid = threadIdx.x;
    // XCD-chunked bijective swizzle: 480 blocks = 8 XCDs x 60
    int wg = (blockIdx.x & 7) * 60 + (blockIdx.x >> 3);
    int sk = wg / 60;
    int rem = wg % 60;
    int n0 = (rem / 10) * 128;
    int m0 = (rem % 10) * 128;

    int ks0 = (KSTEPS * sk) / SPLITK;
    int nk = (KSTEPS * (sk + 1)) / SPLITK - ks0;   // 21 or 22

    // chunks (512 of 16B per seg): c: frag=c>>6, kg=(c>>4)&3, row=c&15
    int cA0 = tid, cA1 = tid + 256;
    size_t aoff0 = (size_t)(m0 + (cA0 >> 6) * 16 + (cA0 & 15)) * KP + ((cA0 >> 4) & 3) * 8;
    size_t aoff1 = (size_t)(m0 + (cA1 >> 6) * 16 + (cA1 & 15)) * KP + ((cA1 >> 4) & 3) * 8;
    size_t boff0 = (size_t)(n0 + (cA0 >> 6) * 16 + (cA0 & 15)) * KP + ((cA0 >> 4) & 3) * 8;
    size_t boff1 = (size_t)(n0 + (cA1 >> 6) * 16 + (cA1 & 15)) * KP + ((cA1 >> 4) & 3) * 8;

    int w = tid >> 6, lane = tid & 63;
    int wm = w >> 1, wn = w & 1;                  // 2x2 waves of 64x64
    int lfr = ((lane >> 4) * 16 + (lane & 15)) * 8;

    f32x4 acc[4][4];
    #pragma unroll
    for (int i = 0; i < 4; ++i)
        #pragma unroll
        for (int j = 0; j < 4; ++j) acc[i][j] = (f32x4){0.f, 0.f, 0.f, 0.f};

    STAGE(ks0, 0);          // 4 loads/thread in flight
    STAGE(ks0 + 1, 1);      // 8 in flight (nk >= 21 always)

    int cur = 0;
    for (int k = 0; k < nk; ++k) {
        if (k + 1 < nk) asm volatile("s_waitcnt vmcnt(4)" ::: "memory");
        else            asm volatile("s_waitcnt vmcnt(0)" ::: "memory");
        __builtin_amdgcn_s_barrier();

        const u16* L = &lds[cur][0];
        s16x8 ah[4], bh[4];
        #pragma unroll
        for (int f = 0; f < 4; ++f) {
            ah[f] = *(const s16x8*)(L + (wm * 4 + f) * 512 + lfr);
            bh[f] = *(const s16x8*)(L + ASEG + (wn * 4 + f) * 512 + lfr);
        }
        asm volatile("s_waitcnt lgkmcnt(0)" ::: "memory");
        __builtin_amdgcn_s_barrier();       // all waves done reading buf(cur)

        if (k + 2 < nk) STAGE(ks0 + k + 2, cur);   // flies under MFMA

        #pragma unroll
        for (int i = 0; i < 4; ++i)
            #pragma unroll
            for (int j = 0; j < 4; ++j)
                acc[i][j] = __builtin_amdgcn_mfma_f32_16x16x32_bf16(ah[i], bh[j], acc[i][j], 0, 0, 0);
        cur ^= 1;
    }

    // epilogue: C/D layout col=lane&15, row=(lane>>4)*4+reg  [m91-verified]
    int rbase = m0 + wm * 64 + (lane >> 4) * 4;
    int cbase = n0 + wn * 64 + (lane & 15);
    #pragma unroll
    for (int i = 0; i < 4; ++i) {
        int row0 = rbase + i * 16;
        #pragma unroll
        for (int j = 0; j < 4; ++j) {
            int col = cbase + j * 16;
            u16* dst = partsB + ((size_t)sk * MA + row0) * H + col;
            #pragma unroll
            for (int r = 0; r < 4; ++r)
                dst[(size_t)r * H] = f2bf(acc[i][j][r]);
        }
    }
}

// ---------------------------------------------------------------------------
// 4) proto finalize: proto[i] = sum_split partsB[sp][i]  (i < 80), ushort4.
//    block = 192 threads (3 waves, all active).
// ---------------------------------------------------------------------------
__global__ __launch_bounds__(192) void protofin_kernel(
    const u16* __restrict__ partsB, float* __restrict__ proto)
{
    int i = blockIdx.x;
    int d0 = threadIdx.x * 4;
    float s0 = 0.f, s1 = 0.f, s2 = 0.f, s3 = 0.f;
    #pragma unroll
    for (int sp = 0; sp < SPLITK; ++sp) {
        ushort4 v = *(const ushort4*)(partsB + ((size_t)sp * MA + i) * H + d0);
        s0 += bf2f(v.x); s1 += bf2f(v.y); s2 += bf2f(v.z); s3 += bf2f(v.w);
    }
    *(float4*)(proto + (size_t)i * H + d0) = make_float4(s0, s1, s2, s3);
}

// ---------------------------------------------------------------------------
// 5) distances + logits + pred; grid = BQ blocks of 192 (3 waves, all active).
// ---------------------------------------------------------------------------
__global__ __launch_bounds__(192) void dist_kernel(
    const u16* __restrict__ partsB, const float* __restrict__ proto,
    float* __restrict__ outp)
{
    int bid = blockIdx.x;            // e*TOTAL_Q + q
    int e = bid / TOTAL_Q;
    int tid = threadIdx.x;
    int m = NPROTO + bid;            // GEMM row of this query
    int d0 = tid * 4;                // 192 threads cover 768 dims

    float qv0 = 0.f, qv1 = 0.f, qv2 = 0.f, qv3 = 0.f;
    #pragma unroll
    for (int sp = 0; sp < SPLITK; ++sp) {
        ushort4 v = *(const ushort4*)(partsB + ((size_t)sp * MA + m) * H + d0);
        qv0 += bf2f(v.x); qv1 += bf2f(v.y); qv2 += bf2f(v.z); qv3 += bf2f(v.w);
    }

    __shared__ float red[N_WAY][3];
    __shared__ float lvals[N_WAY];
    int wave = tid >> 6, lane = tid & 63;
    for (int n = 0; n < N_WAY; ++n) {
        const float* pr = proto + (size_t)(e * N_WAY + n) * H + d0;
        float4 pv = *(const float4*)pr;
        float df0 = pv.x - qv0, df1 = pv.y - qv1, df2 = pv.z - qv2, df3 = pv.w - qv3;
        float p = df0 * df0;
        p = fmaf(df1, df1, p);
        p = fmaf(df2, df2, p);
        p = fmaf(df3, df3, p);
        #pragma unroll
        for (int off = 32; off > 0; off >>= 1)
            p += __shfl_down(p, off);
        if (lane == 0) red[n][wave] = p;
    }
    __syncthreads();
    if (tid < N_WAY) {
        float v = red[tid][0] + red[tid][1] + red[tid][2];
        lvals[tid] = -v;
        outp[(size_t)bid * (N_WAY + 1) + tid] = -v;
    }
    __syncthreads();
    if (tid == 0) {
        float mn = lvals[0];
        #pragma unroll
        for (int n = 1; n < N_WAY; ++n) mn = fminf(mn, lvals[n]);
        float last = mn - 1.0f;
        outp[(size_t)bid * (N_WAY + 1) + N_WAY] = last;
        float best = lvals[0];
        int bi = 0;
        for (int n = 1; n < N_WAY; ++n)
            if (lvals[n] > best) { best = lvals[n]; bi = n; }
        if (last > best) bi = N_WAY;   // parity with reference; cannot trigger
        outp[(size_t)BQ * (N_WAY + 1) + bid] = (float)bi;
    }
}

// ---------------------------------------------------------------------------
extern "C" void kernel_launch(void* const* d_in, const int* in_sizes, int n_in,
                              void* d_out, int out_size, void* d_ws, size_t ws_size,
                              hipStream_t stream)
{
    const float* all_support = (const float*)d_in[0];
    const float* support_emb = (const float*)d_in[1];
    const float* all_query   = (const float*)d_in[2];
    const float* query_emb   = (const float*)d_in[3];
    const float* fc_W        = (const float*)d_in[4];
    const int* s_eh     = (const int*)d_in[6];
    const int* s_eh_end = (const int*)d_in[7];
    const int* s_et     = (const int*)d_in[8];
    const int* s_et_end = (const int*)d_in[9];
    const int* q_eh     = (const int*)d_in[10];
    const int* q_eh_end = (const int*)d_in[11];
    const int* q_et     = (const int*)d_in[12];
    const int* q_et_end = (const int*)d_in[13];

    // workspace layout (all segment sizes multiples of 16B)
    u16* partsB  = (u16*)d_ws;                             // SPLITK*MA*H u16
    float* proto = (float*)(partsB + (size_t)SPLITK * MA * H);  // NPROTO*H f32
    u16* Wh      = (u16*)(proto + (size_t)NPROTO * H);     // H*KP
    u16* A_bf    = Wh + (size_t)H * KP;                    // MA*KP
    u16* flatS   = A_bf + (size_t)MA * KP;                 // BS*KP

    pre_kernel<<<MTOT + H, 256, 0, stream>>>(
        all_support, all_query, support_emb, query_emb, fc_W,
        s_eh, s_eh_end, s_et, s_et_end, q_eh, q_eh_end, q_et, q_et_end,
        flatS, A_bf, Wh);

    avg_kernel<<<dim3(NPROTO, 3), 256, 0, stream>>>(flatS, A_bf);

    gemm_mfma<<<480, 256, 0, stream>>>(A_bf, Wh, partsB);

    protofin_kernel<<<NPROTO, 192, 0, stream>>>(partsB, proto);

    dist_kernel<<<BQ, 192, 0, stream>>>(partsB, proto, (float*)d_out);
}